// Round 7
// baseline (1131.175 us; speedup 1.0000x reference)
//
#include <hip/hip_runtime.h>

#define N_NODES 50000
#define N_EDGES 800000
#define LRELU_SLOPE 0.2f
#define BN_EPS 1e-5f

__device__ __forceinline__ float lrelu(float x){ return fmaxf(x,0.f) + LRELU_SLOPE*fminf(x,0.f); }
__device__ __forceinline__ float wsum(float v){
  #pragma unroll
  for(int m=32;m>=1;m>>=1) v += __shfl_xor(v, m, 64);
  return v;
}

// ---------------- CSR build ----------------
__global__ __launch_bounds__(256) void k_init(int* __restrict__ cnt, int* __restrict__ fill,
                                              int* __restrict__ gstart, int* __restrict__ gend){
  int i = blockIdx.x*256 + threadIdx.x;
  if(i < N_NODES){ cnt[i] = 0; fill[i] = 0; }
  if(i < 64){ gstart[i] = N_NODES; gend[i] = 0; }
}

__global__ __launch_bounds__(256) void k_hist(const int* __restrict__ eidx, int* __restrict__ cnt){
  int e = blockIdx.x*256 + threadIdx.x;
  if(e < N_EDGES) atomicAdd(&cnt[eidx[N_EDGES + e]], 1);
}

__global__ __launch_bounds__(1024) void k_scan(const int* __restrict__ cnt, int* __restrict__ rowptr){
  __shared__ int part[1024];
  int t = threadIdx.x;
  const int per = (N_NODES + 1023)/1024; // 49
  int beg = t*per, end = beg+per; if(end > N_NODES) end = N_NODES;
  int s = 0;
  for(int i=beg;i<end;i++) s += cnt[i];
  part[t] = s;
  __syncthreads();
  for(int off=1; off<1024; off<<=1){
    int v = (t>=off) ? part[t-off] : 0;
    __syncthreads();
    part[t] += v;
    __syncthreads();
  }
  int run = (t==0) ? 0 : part[t-1];
  for(int i=beg;i<end;i++){ rowptr[i] = run; run += cnt[i]; }
  if(t==1023) rowptr[N_NODES] = run;
}

__global__ __launch_bounds__(256) void k_scatter(const int* __restrict__ eidx, const float* __restrict__ pw,
                                                 const int* __restrict__ rowptr, int* __restrict__ fill,
                                                 int* __restrict__ s_src, float* __restrict__ s_w){
  int e = blockIdx.x*256 + threadIdx.x;
  if(e < N_EDGES){
    int d = eidx[N_EDGES + e];
    int pos = rowptr[d] + atomicAdd(&fill[d], 1);
    s_src[pos] = eidx[e];
    s_w[pos]   = pw[e];
  }
}

// ---------------- GCN ----------------
__global__ __launch_bounds__(256) void k_deg(const int* __restrict__ rowptr, const float* __restrict__ s_w,
                                             float* __restrict__ dinv){
  int n = blockIdx.x*256 + threadIdx.x;
  if(n >= N_NODES) return;
  int rb = rowptr[n], re = rowptr[n+1];
  float d = 1.f; // self-loop weight
  for(int j=rb;j<re;j++) d += s_w[j];
  dinv[n] = 1.f / sqrtf(d);
}

__global__ __launch_bounds__(256) void k_enorm(const int* __restrict__ s_src, const float* __restrict__ s_w,
                                               const float* __restrict__ dinv, float* __restrict__ g_e){
  int j = blockIdx.x*256 + threadIdx.x;
  if(j < N_EDGES) g_e[j] = dinv[s_src[j]] * s_w[j];
}

__global__ __launch_bounds__(256) void k_h(const float* __restrict__ px, const float* __restrict__ gw,
                                           float* __restrict__ h){
  int n = blockIdx.x*256 + threadIdx.x;
  if(n >= N_NODES) return;
  float x[33];
  #pragma unroll
  for(int k=0;k<33;k++) x[k] = px[n*33+k];
  for(int c=0;c<33;c++){
    float a = 0.f;
    #pragma unroll
    for(int k=0;k<33;k++) a = fmaf(x[k], gw[c*33+k], a);
    h[n*33+c] = a;
  }
}

// xp1 padded to stride 36, fused: agg + gcn_b + relu + BN(eval)
__global__ __launch_bounds__(256) void k_gcn(const float* __restrict__ h, const int* __restrict__ rowptr,
                                             const int* __restrict__ s_src, const float* __restrict__ g_e,
                                             const float* __restrict__ dinv,
                                             const float* __restrict__ gcnb, const float* __restrict__ bnm,
                                             const float* __restrict__ bnv, const float* __restrict__ bnw,
                                             const float* __restrict__ bnb, float* __restrict__ xp1){
  int t = threadIdx.x;
  int nl = t/33, c = t - nl*33;
  int n = blockIdx.x*7 + nl;
  if(nl < 7 && n < N_NODES){
    float acc = 0.f;
    int rb = rowptr[n], re = rowptr[n+1];
    for(int j=rb;j<re;j++) acc = fmaf(g_e[j], h[s_src[j]*33 + c], acc);
    float dn = dinv[n];
    acc += dn * h[n*33 + c];
    float val = fmaxf(dn*acc + gcnb[c], 0.f);
    float inv = bnw[c] / sqrtf(bnv[c] + BN_EPS);
    val = val*inv + (bnb[c] - bnm[c]*inv);
    xp1[n*36 + c] = val;
  }
  int p = t - 231;
  if(p >= 0 && p < 21){
    int np = blockIdx.x*7 + p/3;
    if(np < N_NODES) xp1[np*36 + 33 + (p%3)] = 0.f;
  }
}

// ---------------- GATv2 ----------------
// Tiled: 64 nodes/block, x-tile + both weight matrices in LDS, coalesced flat writes.
__global__ __launch_bounds__(256) void k_gatlin(const float* __restrict__ xp1, const float* __restrict__ wl,
                                                const float* __restrict__ wr, float* __restrict__ xl,
                                                float* __restrict__ xr){
  __shared__ float sx[64*36];    // 9 KB
  __shared__ float swl[132*33];  // 17.4 KB
  __shared__ float swr[132*33];  // 17.4 KB
  int t = threadIdx.x;
  int n0 = blockIdx.x*64;
  int nn = N_NODES - n0; if(nn > 64) nn = 64;
  for(int i=t;i<4356;i+=256){ swl[i] = wl[i]; swr[i] = wr[i]; }
  int xcnt = nn*36;
  for(int i=t;i<xcnt;i+=256) sx[i] = xp1[(size_t)n0*36 + i];
  __syncthreads();
  int total = nn*132;
  for(int flat=t; flat<total; flat+=256){
    int n = flat/132, j = flat - n*132;
    const float* xv = sx + n*36;
    const float* wlv = swl + j*33;
    const float* wrv = swr + j*33;
    float al = 0.f, ar = 0.f;
    #pragma unroll
    for(int k=0;k<33;k++){
      float x = xv[k];
      al = fmaf(x, wlv[k], al);
      ar = fmaf(x, wrv[k], ar);
    }
    size_t gidx = (size_t)n0*132 + flat;
    xl[gidx] = al;
    xr[gidx] = ar;
  }
}

// one block per node; wave 0 = head 0, wave 1 = head 1; lane = channel.
// 4-way edge unroll: 4 independent gathers + 4 interleaved butterfly reduces per iter.
__global__ __launch_bounds__(128) void k_gat(const int* __restrict__ rowptr, const int* __restrict__ s_src,
                                             const float* __restrict__ xl, const float* __restrict__ xr,
                                             const float* __restrict__ att, const float* __restrict__ gatb,
                                             float* __restrict__ xp2){
  int n = blockIdx.x;
  int h = threadIdx.x >> 6;
  int lane = threadIdx.x & 63;
  int base = h*66;
  bool ex = (lane < 2);
  float att0 = att[base + lane];
  float att1 = ex ? att[base + 64 + lane] : 0.f;
  size_t nrow = (size_t)n*132;
  float xr0 = xr[nrow + base + lane];
  float xr1 = ex ? xr[nrow + base + 64 + lane] : 0.f;
  float xs0 = xl[nrow + base + lane];
  float xs1 = ex ? xl[nrow + base + 64 + lane] : 0.f;
  float e_self = wsum(lrelu(xs0+xr0)*att0 + lrelu(xs1+xr1)*att1);
  float acc0 = xs0, acc1 = xs1, asum = 1.f; // a_self = exp(0) = 1
  int rb = rowptr[n], re = rowptr[n+1];
  int j = rb;
  for(; j+4 <= re; j += 4){
    int sA = s_src[j], sB = s_src[j+1], sC = s_src[j+2], sD = s_src[j+3];
    const float* rA = xl + (size_t)sA*132 + base;
    const float* rB = xl + (size_t)sB*132 + base;
    const float* rC = xl + (size_t)sC*132 + base;
    const float* rD = xl + (size_t)sD*132 + base;
    float vA0 = rA[lane], vB0 = rB[lane], vC0 = rC[lane], vD0 = rD[lane];
    float vA1 = ex ? rA[64+lane] : 0.f;
    float vB1 = ex ? rB[64+lane] : 0.f;
    float vC1 = ex ? rC[64+lane] : 0.f;
    float vD1 = ex ? rD[64+lane] : 0.f;
    float t0 = lrelu(vA0+xr0)*att0 + lrelu(vA1+xr1)*att1;
    float t1 = lrelu(vB0+xr0)*att0 + lrelu(vB1+xr1)*att1;
    float t2 = lrelu(vC0+xr0)*att0 + lrelu(vC1+xr1)*att1;
    float t3 = lrelu(vD0+xr0)*att0 + lrelu(vD1+xr1)*att1;
    #pragma unroll
    for(int m=32;m>=1;m>>=1){
      t0 += __shfl_xor(t0, m, 64);
      t1 += __shfl_xor(t1, m, 64);
      t2 += __shfl_xor(t2, m, 64);
      t3 += __shfl_xor(t3, m, 64);
    }
    float a0 = __expf(t0 - e_self);
    float a1 = __expf(t1 - e_self);
    float a2 = __expf(t2 - e_self);
    float a3 = __expf(t3 - e_self);
    acc0 = fmaf(a0, vA0, fmaf(a1, vB0, fmaf(a2, vC0, fmaf(a3, vD0, acc0))));
    acc1 = fmaf(a0, vA1, fmaf(a1, vB1, fmaf(a2, vC1, fmaf(a3, vD1, acc1))));
    asum += (a0 + a1) + (a2 + a3);
  }
  for(; j<re; j++){
    int s = s_src[j];
    size_t srow = (size_t)s*132;
    float v0 = xl[srow + base + lane];
    float v1 = ex ? xl[srow + base + 64 + lane] : 0.f;
    float e = wsum(lrelu(v0+xr0)*att0 + lrelu(v1+xr1)*att1);
    float a = __expf(e - e_self);
    acc0 = fmaf(a, v0, acc0);
    acc1 = fmaf(a, v1, acc1);
    asum += a;
  }
  float inv = 1.f/asum;
  float o0 = fmaxf(acc0*inv + gatb[base + lane], 0.f);
  xp2[nrow + base + lane] = o0;
  if(ex){
    float o1 = fmaxf(acc1*inv + gatb[base + 64 + lane], 0.f);
    xp2[nrow + base + 64 + lane] = o1;
  }
}

// ---------------- pooling + MLP head ----------------
// pro_batch is SORTED -> boundary detection, zero atomics
__global__ __launch_bounds__(256) void k_bounds(const int* __restrict__ batch, int* __restrict__ gstart,
                                                int* __restrict__ gend){
  int n = blockIdx.x*256 + threadIdx.x;
  if(n >= N_NODES) return;
  int b = batch[n];
  if(n == 0) gstart[b] = 0;
  else {
    int p = batch[n-1];
    if(p != b){ gstart[b] = n; gend[p] = n; }
  }
  if(n == N_NODES-1) gend[b] = N_NODES;
}

// stage 1: 16 segments per graph -> partial sums (1024 blocks)
__global__ __launch_bounds__(128) void k_poolp(const float* __restrict__ xp2, const int* __restrict__ gstart,
                                               const int* __restrict__ gend, float* __restrict__ pp){
  int g = blockIdx.x, seg = blockIdx.y, t = threadIdx.x;
  int s = gstart[g], e = gend[g];
  int len = e - s; if(len < 0) len = 0;
  int ns = s + (int)(((long long)len*seg)>>4);
  int ne = s + (int)(((long long)len*(seg+1))>>4);
  float a0 = 0.f, a1 = 0.f;
  for(int n=ns;n<ne;n++){
    a0 += xp2[(size_t)n*132 + t];
    if(t < 4) a1 += xp2[(size_t)n*132 + 128 + t];
  }
  float* o = pp + (size_t)(g*16 + seg)*132;
  o[t] = a0;
  if(t < 4) o[128 + t] = a1;
}

// stage 2: reduce 16 partials, divide by count
__global__ __launch_bounds__(256) void k_poolr(const float* __restrict__ pp, const int* __restrict__ gstart,
                                               const int* __restrict__ gend, float* __restrict__ pooledT){
  int g = blockIdx.x, t = threadIdx.x;
  if(t >= 132) return;
  float s = 0.f;
  #pragma unroll
  for(int k=0;k<16;k++) s += pp[(size_t)(g*16 + k)*132 + t];
  int c = gend[g] - gstart[g]; if(c < 1) c = 1;
  pooledT[t*64 + g] = s/(float)c;
}

__global__ __launch_bounds__(256) void k_fc1(const float* __restrict__ pooledT, const float* __restrict__ w,
                                             const float* __restrict__ b, float* __restrict__ h1T){
  int gid = blockIdx.x*256 + threadIdx.x;
  int o = gid >> 6, g = gid & 63;
  float acc = b[o];
  const float* wr = w + o*132;
  for(int k=0;k<132;k++) acc = fmaf(pooledT[k*64+g], wr[k], acc);
  h1T[o*64+g] = fmaxf(acc, 0.f);
}

__global__ __launch_bounds__(256) void k_fc2(const float* __restrict__ h1T, const float* __restrict__ w,
                                             const float* __restrict__ b, float* __restrict__ out){
  int gid = blockIdx.x*256 + threadIdx.x;
  int o = gid >> 6, g = gid & 63;
  float acc = b[o];
  const float* wr = w + o*1024;
  for(int k=0;k<1024;k++) acc = fmaf(h1T[k*64+g], wr[k], acc);
  out[8192 + g*128 + o] = acc;
}

// ---------------- RNA branches ----------------
// Fire-and-forget LDS float atomics (ds_add_f32, no result -> no lgkm wait in the chain),
// single shared copy, 256 threads/block for full occupancy.
__global__ __launch_bounds__(256) void k_s1(const int* __restrict__ g, const float* __restrict__ w,
                                            float* __restrict__ S1){
  __shared__ float S[40];   // [v=5][k=8]
  int b = blockIdx.x, co = blockIdx.y, t = threadIdx.x;
  if(t < 40) S[t] = 0.f;
  __syncthreads();
  const float* wrow = w + co*24000;
  const int*   grow = g + b*3000;
  for(int it=0; it<94; ++it){
    int idx = it*256 + t;
    if(idx < 24000){
      float wv = wrow[idx];          // coalesced stream
      int v = grow[idx>>3];          // octet-broadcast, L1-hot
      unsafeAtomicAdd(&S[v*8 + (idx&7)], wv);  // ds_add_f32
    }
  }
  __syncthreads();
  if(t < 40) S1[b*1280 + co*40 + t] = S[t];
}

__global__ __launch_bounds__(256) void k_s2(const int* __restrict__ g, const float* __restrict__ w,
                                            float* __restrict__ S2){
  __shared__ float S[520];  // [v=65][k=8] = 2 KB
  int b = blockIdx.x, co = blockIdx.y, t = threadIdx.x;
  for(int i=t;i<520;i+=256) S[i] = 0.f;
  __syncthreads();
  const float* wrow = w + co*23984;
  const int*   grow = g + b*2998;
  for(int it=0; it<94; ++it){
    int idx = it*256 + t;
    if(idx < 23984){
      float wv = wrow[idx];
      int v = grow[idx>>3];
      unsafeAtomicAdd(&S[v*8 + (idx&7)], wv);
    }
  }
  __syncthreads();
  for(int i=t;i<520;i+=256) S2[(size_t)b*16640 + co*520 + i] = S[i];
}

// ysum[b][co*121+l] = 0.5*(conv1+bias1)   (k_y1 writes, k_y2 adds)
__global__ __launch_bounds__(128) void k_y1(const float* __restrict__ S1, const float* __restrict__ emb1,
                                            const float* __restrict__ c1b, float* __restrict__ ysum){
  int b = blockIdx.x, co = blockIdx.y, t = threadIdx.x;
  __shared__ float em[640];
  for(int i=t;i<640;i+=128) em[i] = emb1[i];
  __syncthreads();
  if(t < 121){
    const float* S = S1 + b*1280 + co*40;
    float acc = c1b[co];
    #pragma unroll
    for(int v=0;v<5;v++)
      #pragma unroll
      for(int k=0;k<8;k++) acc = fmaf(S[v*8+k], em[v*128 + t + k], acc);
    ysum[b*3872 + co*121 + t] = 0.5f*acc;
  }
}

__global__ __launch_bounds__(128) void k_y2(const float* __restrict__ S2, const float* __restrict__ emb2,
                                            const float* __restrict__ c2b, float* __restrict__ ysum){
  int b = blockIdx.x, co = blockIdx.y, t = threadIdx.x;
  __shared__ float em[8320];
  for(int i=t;i<8320;i+=128) em[i] = emb2[i];
  __syncthreads();
  if(t < 121){
    const float* S = S2 + (size_t)b*16640 + co*520;
    float acc = c2b[co];
    for(int v=0;v<65;v++){
      #pragma unroll
      for(int k=0;k<8;k++) acc = fmaf(S[v*8+k], em[v*128 + t + k], acc);
    }
    ysum[b*3872 + co*121 + t] += 0.5f*acc;
  }
}

// out[b][o] = sum_j ysum[b][j]*fcw[o][j] + fcb[o]
// grid (64 graphs, 4 output-quarters); 8-way k-split per output, LDS reduce.
__global__ __launch_bounds__(256) void k_fcxr(const float* __restrict__ ysum, const float* __restrict__ fcw,
                                              const float* __restrict__ fcb, float* __restrict__ out){
  __shared__ float part[256];
  int b = blockIdx.x, q = blockIdx.y, t = threadIdx.x;
  int ol = t >> 3;          // 0..31
  int o  = q*32 + ol;
  int slice = t & 7;        // 0..7, each covers 121 float4 = 484 floats
  const float4* ys = (const float4*)(ysum + b*3872) + slice*121;
  const float4* wr = (const float4*)(fcw + (size_t)o*3872) + slice*121;
  float acc = 0.f;
  for(int k=0;k<121;k++){
    float4 y = ys[k], w4 = wr[k];
    acc += y.x*w4.x + y.y*w4.y + y.z*w4.z + y.w*w4.w;
  }
  part[t] = acc;
  __syncthreads();
  if(slice == 0){
    float s = fcb[o];
    #pragma unroll
    for(int i=0;i<8;i++) s += part[ol*8 + i];
    out[b*128 + o] = s;
  }
}

extern "C" void kernel_launch(void* const* d_in, const int* in_sizes, int n_in,
                              void* d_out, int out_size, void* d_ws, size_t ws_size,
                              hipStream_t stream){
  const int*   g_rna = (const int*)  d_in[0];
  const int*   l_rna = (const int*)  d_in[1];
  const float* pro_x = (const float*)d_in[2];
  const int*   eidx  = (const int*)  d_in[3];
  const float* pro_w = (const float*)d_in[4];
  const int*   batch = (const int*)  d_in[5];
  const float* emb1  = (const float*)d_in[6];
  const float* emb2  = (const float*)d_in[7];
  const float* c1w   = (const float*)d_in[8];
  const float* c1b   = (const float*)d_in[9];
  const float* c2w   = (const float*)d_in[10];
  const float* c2b   = (const float*)d_in[11];
  const float* fcxw  = (const float*)d_in[12];
  const float* fcxb  = (const float*)d_in[13];
  const float* gcnw  = (const float*)d_in[14];
  const float* gcnb  = (const float*)d_in[15];
  const float* bnm   = (const float*)d_in[16];
  const float* bnv   = (const float*)d_in[17];
  const float* bnw   = (const float*)d_in[18];
  const float* bnb   = (const float*)d_in[19];
  const float* gwl   = (const float*)d_in[20];
  const float* gwr   = (const float*)d_in[21];
  const float* gatt  = (const float*)d_in[22];
  const float* gatb  = (const float*)d_in[23];
  const float* f1w   = (const float*)d_in[24];
  const float* f1b   = (const float*)d_in[25];
  const float* f2w   = (const float*)d_in[26];
  const float* f2b_  = (const float*)d_in[27];
  float* out = (float*)d_out;

  char* ws = (char*)d_ws;
  size_t off = 0;
  auto A = [&](size_t n)->char*{ char* p = ws + off; off = (off + n + 255) & ~(size_t)255; return p; };
  int*   cnt    = (int*)  A((size_t)N_NODES*4);
  int*   rowptr = (int*)  A((size_t)(N_NODES+1)*4);
  int*   fill   = (int*)  A((size_t)N_NODES*4);
  int*   s_src  = (int*)  A((size_t)N_EDGES*4);
  float* s_w    = (float*)A((size_t)N_EDGES*4);
  float* g_e    = (float*)A((size_t)N_EDGES*4);
  float* dinv   = (float*)A((size_t)N_NODES*4);
  float* hbuf   = (float*)A((size_t)N_NODES*33*4);
  float* xp1    = (float*)A((size_t)N_NODES*36*4);
  float* xl     = (float*)A((size_t)N_NODES*132*4);
  float* xr     = (float*)A((size_t)N_NODES*132*4);
  float* xp2    = (float*)A((size_t)N_NODES*132*4);
  int*   gstart = (int*)  A(64*4);
  int*   gend   = (int*)  A(64*4);
  float* pooledT= (float*)A(132*64*4);
  float* pp     = (float*)A((size_t)64*16*132*4);
  float* h1T    = (float*)A(1024*64*4);
  float* S1     = (float*)A((size_t)64*1280*4);
  float* S2     = (float*)A((size_t)64*16640*4);
  float* ysum   = (float*)A((size_t)64*3872*4);
  (void)ws_size; (void)in_sizes; (void)n_in; (void)out_size;

  // protein GNN pipeline
  k_init   <<<196, 256, 0, stream>>>(cnt, fill, gstart, gend);
  k_hist   <<<3125, 256, 0, stream>>>(eidx, cnt);
  k_scan   <<<1, 1024, 0, stream>>>(cnt, rowptr);
  k_scatter<<<3125, 256, 0, stream>>>(eidx, pro_w, rowptr, fill, s_src, s_w);
  k_deg    <<<196, 256, 0, stream>>>(rowptr, s_w, dinv);
  k_enorm  <<<3125, 256, 0, stream>>>(s_src, s_w, dinv, g_e);
  k_h      <<<196, 256, 0, stream>>>(pro_x, gcnw, hbuf);
  k_gcn    <<<7143, 256, 0, stream>>>(hbuf, rowptr, s_src, g_e, dinv, gcnb, bnm, bnv, bnw, bnb, xp1);
  k_gatlin <<<782, 256, 0, stream>>>(xp1, gwl, gwr, xl, xr);
  k_gat    <<<N_NODES, 128, 0, stream>>>(rowptr, s_src, xl, xr, gatt, gatb, xp2);
  k_bounds <<<196, 256, 0, stream>>>(batch, gstart, gend);
  k_poolp  <<<dim3(64,16), 128, 0, stream>>>(xp2, gstart, gend, pp);
  k_poolr  <<<64, 256, 0, stream>>>(pp, gstart, gend, pooledT);
  k_fc1    <<<256, 256, 0, stream>>>(pooledT, f1w, f1b, h1T);
  k_fc2    <<<32, 256, 0, stream>>>(h1T, f2w, f2b_, out);

  // RNA branches
  k_s1  <<<dim3(64,32), 256, 0, stream>>>(g_rna, c1w, S1);
  k_s2  <<<dim3(64,32), 256, 0, stream>>>(l_rna, c2w, S2);
  k_y1  <<<dim3(64,32), 128, 0, stream>>>(S1, emb1, c1b, ysum);
  k_y2  <<<dim3(64,32), 128, 0, stream>>>(S2, emb2, c2b, ysum);
  k_fcxr<<<dim3(64,4), 256, 0, stream>>>(ysum, fcxw, fcxb, out);
}

// Round 8
// 720.468 us; speedup vs baseline: 1.5701x; 1.5701x over previous
//
#include <hip/hip_runtime.h>

#define N_NODES 50000
#define N_EDGES 800000
#define LRELU_SLOPE 0.2f
#define BN_EPS 1e-5f

__device__ __forceinline__ float lrelu(float x){ return fmaxf(x,0.f) + LRELU_SLOPE*fminf(x,0.f); }
__device__ __forceinline__ float wsum(float v){
  #pragma unroll
  for(int m=32;m>=1;m>>=1) v += __shfl_xor(v, m, 64);
  return v;
}

// ---------------- CSR build ----------------
__global__ __launch_bounds__(256) void k_init(int* __restrict__ cnt, int* __restrict__ fill,
                                              int* __restrict__ gstart, int* __restrict__ gend){
  int i = blockIdx.x*256 + threadIdx.x;
  if(i < N_NODES){ cnt[i] = 0; fill[i] = 0; }
  if(i < 64){ gstart[i] = N_NODES; gend[i] = 0; }
}

__global__ __launch_bounds__(256) void k_hist(const int* __restrict__ eidx, int* __restrict__ cnt){
  int e = blockIdx.x*256 + threadIdx.x;
  if(e < N_EDGES) atomicAdd(&cnt[eidx[N_EDGES + e]], 1);
}

__global__ __launch_bounds__(1024) void k_scan(const int* __restrict__ cnt, int* __restrict__ rowptr){
  __shared__ int part[1024];
  int t = threadIdx.x;
  const int per = (N_NODES + 1023)/1024; // 49
  int beg = t*per, end = beg+per; if(end > N_NODES) end = N_NODES;
  int s = 0;
  for(int i=beg;i<end;i++) s += cnt[i];
  part[t] = s;
  __syncthreads();
  for(int off=1; off<1024; off<<=1){
    int v = (t>=off) ? part[t-off] : 0;
    __syncthreads();
    part[t] += v;
    __syncthreads();
  }
  int run = (t==0) ? 0 : part[t-1];
  for(int i=beg;i<end;i++){ rowptr[i] = run; run += cnt[i]; }
  if(t==1023) rowptr[N_NODES] = run;
}

__global__ __launch_bounds__(256) void k_scatter(const int* __restrict__ eidx, const float* __restrict__ pw,
                                                 const int* __restrict__ rowptr, int* __restrict__ fill,
                                                 int* __restrict__ s_src, float* __restrict__ s_w){
  int e = blockIdx.x*256 + threadIdx.x;
  if(e < N_EDGES){
    int d = eidx[N_EDGES + e];
    int pos = rowptr[d] + atomicAdd(&fill[d], 1);
    s_src[pos] = eidx[e];
    s_w[pos]   = pw[e];
  }
}

// ---------------- GCN ----------------
__global__ __launch_bounds__(256) void k_deg(const int* __restrict__ rowptr, const float* __restrict__ s_w,
                                             float* __restrict__ dinv){
  int n = blockIdx.x*256 + threadIdx.x;
  if(n >= N_NODES) return;
  int rb = rowptr[n], re = rowptr[n+1];
  float d = 1.f; // self-loop weight
  for(int j=rb;j<re;j++) d += s_w[j];
  dinv[n] = 1.f / sqrtf(d);
}

__global__ __launch_bounds__(256) void k_enorm(const int* __restrict__ s_src, const float* __restrict__ s_w,
                                               const float* __restrict__ dinv, float* __restrict__ g_e){
  int j = blockIdx.x*256 + threadIdx.x;
  if(j < N_EDGES) g_e[j] = dinv[s_src[j]] * s_w[j];
}

__global__ __launch_bounds__(256) void k_h(const float* __restrict__ px, const float* __restrict__ gw,
                                           float* __restrict__ h){
  int n = blockIdx.x*256 + threadIdx.x;
  if(n >= N_NODES) return;
  float x[33];
  #pragma unroll
  for(int k=0;k<33;k++) x[k] = px[n*33+k];
  for(int c=0;c<33;c++){
    float a = 0.f;
    #pragma unroll
    for(int k=0;k<33;k++) a = fmaf(x[k], gw[c*33+k], a);
    h[n*33+c] = a;
  }
}

// xp1 padded to stride 36, fused: agg + gcn_b + relu + BN(eval)
__global__ __launch_bounds__(256) void k_gcn(const float* __restrict__ h, const int* __restrict__ rowptr,
                                             const int* __restrict__ s_src, const float* __restrict__ g_e,
                                             const float* __restrict__ dinv,
                                             const float* __restrict__ gcnb, const float* __restrict__ bnm,
                                             const float* __restrict__ bnv, const float* __restrict__ bnw,
                                             const float* __restrict__ bnb, float* __restrict__ xp1){
  int t = threadIdx.x;
  int nl = t/33, c = t - nl*33;
  int n = blockIdx.x*7 + nl;
  if(nl < 7 && n < N_NODES){
    float acc = 0.f;
    int rb = rowptr[n], re = rowptr[n+1];
    for(int j=rb;j<re;j++) acc = fmaf(g_e[j], h[s_src[j]*33 + c], acc);
    float dn = dinv[n];
    acc += dn * h[n*33 + c];
    float val = fmaxf(dn*acc + gcnb[c], 0.f);
    float inv = bnw[c] / sqrtf(bnv[c] + BN_EPS);
    val = val*inv + (bnb[c] - bnm[c]*inv);
    xp1[n*36 + c] = val;
  }
  int p = t - 231;
  if(p >= 0 && p < 21){
    int np = blockIdx.x*7 + p/3;
    if(np < N_NODES) xp1[np*36 + 33 + (p%3)] = 0.f;
  }
}

// ---------------- GATv2 ----------------
// Tiled: 64 nodes/block, x-tile + both weight matrices in LDS, coalesced flat writes.
__global__ __launch_bounds__(256) void k_gatlin(const float* __restrict__ xp1, const float* __restrict__ wl,
                                                const float* __restrict__ wr, float* __restrict__ xl,
                                                float* __restrict__ xr){
  __shared__ float sx[64*36];    // 9 KB
  __shared__ float swl[132*33];  // 17.4 KB
  __shared__ float swr[132*33];  // 17.4 KB
  int t = threadIdx.x;
  int n0 = blockIdx.x*64;
  int nn = N_NODES - n0; if(nn > 64) nn = 64;
  for(int i=t;i<4356;i+=256){ swl[i] = wl[i]; swr[i] = wr[i]; }
  int xcnt = nn*36;
  for(int i=t;i<xcnt;i+=256) sx[i] = xp1[(size_t)n0*36 + i];
  __syncthreads();
  int total = nn*132;
  for(int flat=t; flat<total; flat+=256){
    int n = flat/132, j = flat - n*132;
    const float* xv = sx + n*36;
    const float* wlv = swl + j*33;
    const float* wrv = swr + j*33;
    float al = 0.f, ar = 0.f;
    #pragma unroll
    for(int k=0;k<33;k++){
      float x = xv[k];
      al = fmaf(x, wlv[k], al);
      ar = fmaf(x, wrv[k], ar);
    }
    size_t gidx = (size_t)n0*132 + flat;
    xl[gidx] = al;
    xr[gidx] = ar;
  }
}

// one block per node; wave 0 = head 0, wave 1 = head 1; lane = channel.
// 4-way edge unroll: 4 independent gathers + 4 interleaved butterfly reduces per iter.
__global__ __launch_bounds__(128) void k_gat(const int* __restrict__ rowptr, const int* __restrict__ s_src,
                                             const float* __restrict__ xl, const float* __restrict__ xr,
                                             const float* __restrict__ att, const float* __restrict__ gatb,
                                             float* __restrict__ xp2){
  int n = blockIdx.x;
  int h = threadIdx.x >> 6;
  int lane = threadIdx.x & 63;
  int base = h*66;
  bool ex = (lane < 2);
  float att0 = att[base + lane];
  float att1 = ex ? att[base + 64 + lane] : 0.f;
  size_t nrow = (size_t)n*132;
  float xr0 = xr[nrow + base + lane];
  float xr1 = ex ? xr[nrow + base + 64 + lane] : 0.f;
  float xs0 = xl[nrow + base + lane];
  float xs1 = ex ? xl[nrow + base + 64 + lane] : 0.f;
  float e_self = wsum(lrelu(xs0+xr0)*att0 + lrelu(xs1+xr1)*att1);
  float acc0 = xs0, acc1 = xs1, asum = 1.f; // a_self = exp(0) = 1
  int rb = rowptr[n], re = rowptr[n+1];
  int j = rb;
  for(; j+4 <= re; j += 4){
    int sA = s_src[j], sB = s_src[j+1], sC = s_src[j+2], sD = s_src[j+3];
    const float* rA = xl + (size_t)sA*132 + base;
    const float* rB = xl + (size_t)sB*132 + base;
    const float* rC = xl + (size_t)sC*132 + base;
    const float* rD = xl + (size_t)sD*132 + base;
    float vA0 = rA[lane], vB0 = rB[lane], vC0 = rC[lane], vD0 = rD[lane];
    float vA1 = ex ? rA[64+lane] : 0.f;
    float vB1 = ex ? rB[64+lane] : 0.f;
    float vC1 = ex ? rC[64+lane] : 0.f;
    float vD1 = ex ? rD[64+lane] : 0.f;
    float t0 = lrelu(vA0+xr0)*att0 + lrelu(vA1+xr1)*att1;
    float t1 = lrelu(vB0+xr0)*att0 + lrelu(vB1+xr1)*att1;
    float t2 = lrelu(vC0+xr0)*att0 + lrelu(vC1+xr1)*att1;
    float t3 = lrelu(vD0+xr0)*att0 + lrelu(vD1+xr1)*att1;
    #pragma unroll
    for(int m=32;m>=1;m>>=1){
      t0 += __shfl_xor(t0, m, 64);
      t1 += __shfl_xor(t1, m, 64);
      t2 += __shfl_xor(t2, m, 64);
      t3 += __shfl_xor(t3, m, 64);
    }
    float a0 = __expf(t0 - e_self);
    float a1 = __expf(t1 - e_self);
    float a2 = __expf(t2 - e_self);
    float a3 = __expf(t3 - e_self);
    acc0 = fmaf(a0, vA0, fmaf(a1, vB0, fmaf(a2, vC0, fmaf(a3, vD0, acc0))));
    acc1 = fmaf(a0, vA1, fmaf(a1, vB1, fmaf(a2, vC1, fmaf(a3, vD1, acc1))));
    asum += (a0 + a1) + (a2 + a3);
  }
  for(; j<re; j++){
    int s = s_src[j];
    size_t srow = (size_t)s*132;
    float v0 = xl[srow + base + lane];
    float v1 = ex ? xl[srow + base + 64 + lane] : 0.f;
    float e = wsum(lrelu(v0+xr0)*att0 + lrelu(v1+xr1)*att1);
    float a = __expf(e - e_self);
    acc0 = fmaf(a, v0, acc0);
    acc1 = fmaf(a, v1, acc1);
    asum += a;
  }
  float inv = 1.f/asum;
  float o0 = fmaxf(acc0*inv + gatb[base + lane], 0.f);
  xp2[nrow + base + lane] = o0;
  if(ex){
    float o1 = fmaxf(acc1*inv + gatb[base + 64 + lane], 0.f);
    xp2[nrow + base + 64 + lane] = o1;
  }
}

// ---------------- pooling + MLP head ----------------
// pro_batch is SORTED -> boundary detection, zero atomics
__global__ __launch_bounds__(256) void k_bounds(const int* __restrict__ batch, int* __restrict__ gstart,
                                                int* __restrict__ gend){
  int n = blockIdx.x*256 + threadIdx.x;
  if(n >= N_NODES) return;
  int b = batch[n];
  if(n == 0) gstart[b] = 0;
  else {
    int p = batch[n-1];
    if(p != b){ gstart[b] = n; gend[p] = n; }
  }
  if(n == N_NODES-1) gend[b] = N_NODES;
}

// stage 1: 16 segments per graph -> partial sums (1024 blocks)
__global__ __launch_bounds__(128) void k_poolp(const float* __restrict__ xp2, const int* __restrict__ gstart,
                                               const int* __restrict__ gend, float* __restrict__ pp){
  int g = blockIdx.x, seg = blockIdx.y, t = threadIdx.x;
  int s = gstart[g], e = gend[g];
  int len = e - s; if(len < 0) len = 0;
  int ns = s + (int)(((long long)len*seg)>>4);
  int ne = s + (int)(((long long)len*(seg+1))>>4);
  float a0 = 0.f, a1 = 0.f;
  for(int n=ns;n<ne;n++){
    a0 += xp2[(size_t)n*132 + t];
    if(t < 4) a1 += xp2[(size_t)n*132 + 128 + t];
  }
  float* o = pp + (size_t)(g*16 + seg)*132;
  o[t] = a0;
  if(t < 4) o[128 + t] = a1;
}

// stage 2: reduce 16 partials, divide by count
__global__ __launch_bounds__(256) void k_poolr(const float* __restrict__ pp, const int* __restrict__ gstart,
                                               const int* __restrict__ gend, float* __restrict__ pooledT){
  int g = blockIdx.x, t = threadIdx.x;
  if(t >= 132) return;
  float s = 0.f;
  #pragma unroll
  for(int k=0;k<16;k++) s += pp[(size_t)(g*16 + k)*132 + t];
  int c = gend[g] - gstart[g]; if(c < 1) c = 1;
  pooledT[t*64 + g] = s/(float)c;
}

__global__ __launch_bounds__(256) void k_fc1(const float* __restrict__ pooledT, const float* __restrict__ w,
                                             const float* __restrict__ b, float* __restrict__ h1T){
  int gid = blockIdx.x*256 + threadIdx.x;
  int o = gid >> 6, g = gid & 63;
  float acc = b[o];
  const float* wr = w + o*132;
  for(int k=0;k<132;k++) acc = fmaf(pooledT[k*64+g], wr[k], acc);
  h1T[o*64+g] = fmaxf(acc, 0.f);
}

__global__ __launch_bounds__(256) void k_fc2(const float* __restrict__ h1T, const float* __restrict__ w,
                                             const float* __restrict__ b, float* __restrict__ out){
  int gid = blockIdx.x*256 + threadIdx.x;
  int o = gid >> 6, g = gid & 63;
  float acc = b[o];
  const float* wr = w + o*1024;
  for(int k=0;k<1024;k++) acc = fmaf(h1T[k*64+g], wr[k], acc);
  out[8192 + g*128 + o] = acc;
}

// ---------------- RNA branches ----------------
// Bucket-sort the embedding indices once per (b), then gather-sum weights with
// register accumulators: zero atomics / zero LDS RMW in the hot loop.
// sci stores ci*8 (pre-scaled float offset); off has V+1 bucket offsets per b.
__global__ __launch_bounds__(256) void k_bucket(const int* __restrict__ g, int L, int V,
                                                int* __restrict__ sci, int* __restrict__ off){
  __shared__ int gl[3000];
  __shared__ int hist[65];
  __shared__ int base[66];
  int b = blockIdx.x, t = threadIdx.x;
  if(t < V) hist[t] = 0;
  for(int i=t;i<L;i+=256) gl[i] = g[b*L + i];
  __syncthreads();
  for(int i=t;i<L;i+=256) atomicAdd(&hist[gl[i]], 1);
  __syncthreads();
  if(t == 0){
    int run = 0;
    for(int v=0;v<V;v++){ base[v] = run; run += hist[v]; }
    base[V] = run;
  }
  __syncthreads();
  if(t <= V) off[b*(V+1) + t] = base[t];
  if(t < V) hist[t] = 0;
  __syncthreads();
  for(int i=t;i<L;i+=256){
    int v = gl[i];
    int p = base[v] + atomicAdd(&hist[v], 1);
    sci[b*3000 + p] = i*8;   // pre-scaled
  }
}

// thread = (co = t>>3, kk = t&7); block = (b, v-range). Registers only in the hot loop.
__global__ __launch_bounds__(256) void k_sgather(const int* __restrict__ sci, const int* __restrict__ off,
                                                 const float* __restrict__ w, int V, int wstride,
                                                 int sstride, float* __restrict__ S){
  __shared__ int loff[66];
  __shared__ int lci[3000];
  int b = blockIdx.x, q = blockIdx.y, t = threadIdx.x;
  int nsplit = gridDim.y;
  if(t <= V) loff[t] = off[b*(V+1) + t];
  __syncthreads();
  int vs = (V*q)/nsplit, ve = (V*(q+1))/nsplit;
  int p0 = loff[vs], p1 = loff[ve];
  for(int i=p0+t;i<p1;i+=256) lci[i-p0] = sci[b*3000 + i];
  __syncthreads();
  int co = t >> 3, kk = t & 7;
  const float* wrow = w + co*wstride + kk;
  float* Srow = S + (size_t)b*32*sstride + co*sstride + kk;
  for(int v=vs;v<ve;v++){
    int j = loff[v] - p0, je = loff[v+1] - p0;
    float a0=0.f,a1=0.f,a2=0.f,a3=0.f,a4=0.f,a5=0.f,a6=0.f,a7=0.f;
    for(; j+8 <= je; j += 8){
      a0 += wrow[lci[j]];
      a1 += wrow[lci[j+1]];
      a2 += wrow[lci[j+2]];
      a3 += wrow[lci[j+3]];
      a4 += wrow[lci[j+4]];
      a5 += wrow[lci[j+5]];
      a6 += wrow[lci[j+6]];
      a7 += wrow[lci[j+7]];
    }
    for(; j<je; j++) a0 += wrow[lci[j]];
    Srow[v*8] = ((a0+a1)+(a2+a3)) + ((a4+a5)+(a6+a7));
  }
}

// ysum[b][co*121+l] = 0.5*(conv1+bias1)   (k_y1 writes, k_y2 adds)
__global__ __launch_bounds__(128) void k_y1(const float* __restrict__ S1, const float* __restrict__ emb1,
                                            const float* __restrict__ c1b, float* __restrict__ ysum){
  int b = blockIdx.x, co = blockIdx.y, t = threadIdx.x;
  __shared__ float em[640];
  for(int i=t;i<640;i+=128) em[i] = emb1[i];
  __syncthreads();
  if(t < 121){
    const float* S = S1 + b*1280 + co*40;
    float acc = c1b[co];
    #pragma unroll
    for(int v=0;v<5;v++)
      #pragma unroll
      for(int k=0;k<8;k++) acc = fmaf(S[v*8+k], em[v*128 + t + k], acc);
    ysum[b*3872 + co*121 + t] = 0.5f*acc;
  }
}

__global__ __launch_bounds__(128) void k_y2(const float* __restrict__ S2, const float* __restrict__ emb2,
                                            const float* __restrict__ c2b, float* __restrict__ ysum){
  int b = blockIdx.x, co = blockIdx.y, t = threadIdx.x;
  __shared__ float em[8320];
  for(int i=t;i<8320;i+=128) em[i] = emb2[i];
  __syncthreads();
  if(t < 121){
    const float* S = S2 + (size_t)b*16640 + co*520;
    float acc = c2b[co];
    for(int v=0;v<65;v++){
      #pragma unroll
      for(int k=0;k<8;k++) acc = fmaf(S[v*8+k], em[v*128 + t + k], acc);
    }
    ysum[b*3872 + co*121 + t] += 0.5f*acc;
  }
}

// out[b][o] = sum_j ysum[b][j]*fcw[o][j] + fcb[o]
// grid (64 graphs, 4 output-quarters); 8-way k-split per output, LDS reduce.
__global__ __launch_bounds__(256) void k_fcxr(const float* __restrict__ ysum, const float* __restrict__ fcw,
                                              const float* __restrict__ fcb, float* __restrict__ out){
  __shared__ float part[256];
  int b = blockIdx.x, q = blockIdx.y, t = threadIdx.x;
  int ol = t >> 3;          // 0..31
  int o  = q*32 + ol;
  int slice = t & 7;        // 0..7, each covers 121 float4 = 484 floats
  const float4* ys = (const float4*)(ysum + b*3872) + slice*121;
  const float4* wr = (const float4*)(fcw + (size_t)o*3872) + slice*121;
  float acc = 0.f;
  for(int k=0;k<121;k++){
    float4 y = ys[k], w4 = wr[k];
    acc += y.x*w4.x + y.y*w4.y + y.z*w4.z + y.w*w4.w;
  }
  part[t] = acc;
  __syncthreads();
  if(slice == 0){
    float s = fcb[o];
    #pragma unroll
    for(int i=0;i<8;i++) s += part[ol*8 + i];
    out[b*128 + o] = s;
  }
}

extern "C" void kernel_launch(void* const* d_in, const int* in_sizes, int n_in,
                              void* d_out, int out_size, void* d_ws, size_t ws_size,
                              hipStream_t stream){
  const int*   g_rna = (const int*)  d_in[0];
  const int*   l_rna = (const int*)  d_in[1];
  const float* pro_x = (const float*)d_in[2];
  const int*   eidx  = (const int*)  d_in[3];
  const float* pro_w = (const float*)d_in[4];
  const int*   batch = (const int*)  d_in[5];
  const float* emb1  = (const float*)d_in[6];
  const float* emb2  = (const float*)d_in[7];
  const float* c1w   = (const float*)d_in[8];
  const float* c1b   = (const float*)d_in[9];
  const float* c2w   = (const float*)d_in[10];
  const float* c2b   = (const float*)d_in[11];
  const float* fcxw  = (const float*)d_in[12];
  const float* fcxb  = (const float*)d_in[13];
  const float* gcnw  = (const float*)d_in[14];
  const float* gcnb  = (const float*)d_in[15];
  const float* bnm   = (const float*)d_in[16];
  const float* bnv   = (const float*)d_in[17];
  const float* bnw   = (const float*)d_in[18];
  const float* bnb   = (const float*)d_in[19];
  const float* gwl   = (const float*)d_in[20];
  const float* gwr   = (const float*)d_in[21];
  const float* gatt  = (const float*)d_in[22];
  const float* gatb  = (const float*)d_in[23];
  const float* f1w   = (const float*)d_in[24];
  const float* f1b   = (const float*)d_in[25];
  const float* f2w   = (const float*)d_in[26];
  const float* f2b_  = (const float*)d_in[27];
  float* out = (float*)d_out;

  char* ws = (char*)d_ws;
  size_t off = 0;
  auto A = [&](size_t n)->char*{ char* p = ws + off; off = (off + n + 255) & ~(size_t)255; return p; };
  int*   cnt    = (int*)  A((size_t)N_NODES*4);
  int*   rowptr = (int*)  A((size_t)(N_NODES+1)*4);
  int*   fill   = (int*)  A((size_t)N_NODES*4);
  int*   s_src  = (int*)  A((size_t)N_EDGES*4);
  float* s_w    = (float*)A((size_t)N_EDGES*4);
  float* g_e    = (float*)A((size_t)N_EDGES*4);
  float* dinv   = (float*)A((size_t)N_NODES*4);
  float* hbuf   = (float*)A((size_t)N_NODES*33*4);
  float* xp1    = (float*)A((size_t)N_NODES*36*4);
  float* xl     = (float*)A((size_t)N_NODES*132*4);
  float* xr     = (float*)A((size_t)N_NODES*132*4);
  float* xp2    = (float*)A((size_t)N_NODES*132*4);
  int*   gstart = (int*)  A(64*4);
  int*   gend   = (int*)  A(64*4);
  float* pooledT= (float*)A(132*64*4);
  float* pp     = (float*)A((size_t)64*16*132*4);
  float* h1T    = (float*)A(1024*64*4);
  float* S1     = (float*)A((size_t)64*1280*4);
  float* S2     = (float*)A((size_t)64*16640*4);
  float* ysum   = (float*)A((size_t)64*3872*4);
  int*   sci1   = (int*)  A((size_t)64*3000*4);
  int*   off1   = (int*)  A((size_t)64*8*4);
  int*   sci2   = (int*)  A((size_t)64*3000*4);
  int*   off2   = (int*)  A((size_t)64*66*4);
  (void)ws_size; (void)in_sizes; (void)n_in; (void)out_size;

  // protein GNN pipeline
  k_init   <<<196, 256, 0, stream>>>(cnt, fill, gstart, gend);
  k_hist   <<<3125, 256, 0, stream>>>(eidx, cnt);
  k_scan   <<<1, 1024, 0, stream>>>(cnt, rowptr);
  k_scatter<<<3125, 256, 0, stream>>>(eidx, pro_w, rowptr, fill, s_src, s_w);
  k_deg    <<<196, 256, 0, stream>>>(rowptr, s_w, dinv);
  k_enorm  <<<3125, 256, 0, stream>>>(s_src, s_w, dinv, g_e);
  k_h      <<<196, 256, 0, stream>>>(pro_x, gcnw, hbuf);
  k_gcn    <<<7143, 256, 0, stream>>>(hbuf, rowptr, s_src, g_e, dinv, gcnb, bnm, bnv, bnw, bnb, xp1);
  k_gatlin <<<782, 256, 0, stream>>>(xp1, gwl, gwr, xl, xr);
  k_gat    <<<N_NODES, 128, 0, stream>>>(rowptr, s_src, xl, xr, gatt, gatb, xp2);
  k_bounds <<<196, 256, 0, stream>>>(batch, gstart, gend);
  k_poolp  <<<dim3(64,16), 128, 0, stream>>>(xp2, gstart, gend, pp);
  k_poolr  <<<64, 256, 0, stream>>>(pp, gstart, gend, pooledT);
  k_fc1    <<<256, 256, 0, stream>>>(pooledT, f1w, f1b, h1T);
  k_fc2    <<<32, 256, 0, stream>>>(h1T, f2w, f2b_, out);

  // RNA branches: bucket-sort + register gather
  k_bucket <<<64, 256, 0, stream>>>(g_rna, 3000, 5, sci1, off1);
  k_bucket <<<64, 256, 0, stream>>>(l_rna, 2998, 65, sci2, off2);
  k_sgather<<<dim3(64,5), 256, 0, stream>>>(sci1, off1, c1w, 5, 24000, 40, S1);
  k_sgather<<<dim3(64,8), 256, 0, stream>>>(sci2, off2, c2w, 65, 23984, 520, S2);
  k_y1  <<<dim3(64,32), 128, 0, stream>>>(S1, emb1, c1b, ysum);
  k_y2  <<<dim3(64,32), 128, 0, stream>>>(S2, emb2, c2b, ysum);
  k_fcxr<<<dim3(64,4), 256, 0, stream>>>(ysum, fcxw, fcxb, out);
}

// Round 9
// 704.499 us; speedup vs baseline: 1.6056x; 1.0227x over previous
//
#include <hip/hip_runtime.h>

#define N_NODES 50000
#define N_EDGES 800000
#define LRELU_SLOPE 0.2f
#define BN_EPS 1e-5f

typedef unsigned int u32;

__device__ __forceinline__ float lrelu(float x){ return fmaxf(x,0.f) + LRELU_SLOPE*fminf(x,0.f); }
__device__ __forceinline__ float wsum(float v){
  #pragma unroll
  for(int m=32;m>=1;m>>=1) v += __shfl_xor(v, m, 64);
  return v;
}
__device__ __forceinline__ float bflo(u32 u){ return __uint_as_float(u<<16); }
__device__ __forceinline__ float bfhi(u32 u){ return __uint_as_float(u & 0xffff0000u); }
__device__ __forceinline__ u32 packbf(float a, float b){
  u32 ua = __float_as_uint(a); ua = (ua + 0x7fffu + ((ua>>16)&1u)) >> 16;
  u32 ub = __float_as_uint(b); ub = (ub + 0x7fffu + ((ub>>16)&1u)) >> 16;
  return ua | (ub<<16);
}

// ---------------- CSR build ----------------
__global__ __launch_bounds__(256) void k_init(int* __restrict__ cnt, int* __restrict__ fill,
                                              int* __restrict__ gstart, int* __restrict__ gend){
  int i = blockIdx.x*256 + threadIdx.x;
  if(i < N_NODES){ cnt[i] = 0; fill[i] = 0; }
  if(i < 64){ gstart[i] = N_NODES; gend[i] = 0; }
}

__global__ __launch_bounds__(256) void k_hist(const int* __restrict__ eidx, int* __restrict__ cnt){
  int e = blockIdx.x*256 + threadIdx.x;
  if(e < N_EDGES) atomicAdd(&cnt[eidx[N_EDGES + e]], 1);
}

__global__ __launch_bounds__(1024) void k_scan(const int* __restrict__ cnt, int* __restrict__ rowptr){
  __shared__ int part[1024];
  int t = threadIdx.x;
  const int per = (N_NODES + 1023)/1024; // 49
  int beg = t*per, end = beg+per; if(end > N_NODES) end = N_NODES;
  int s = 0;
  for(int i=beg;i<end;i++) s += cnt[i];
  part[t] = s;
  __syncthreads();
  for(int off=1; off<1024; off<<=1){
    int v = (t>=off) ? part[t-off] : 0;
    __syncthreads();
    part[t] += v;
    __syncthreads();
  }
  int run = (t==0) ? 0 : part[t-1];
  for(int i=beg;i<end;i++){ rowptr[i] = run; run += cnt[i]; }
  if(t==1023) rowptr[N_NODES] = run;
}

__global__ __launch_bounds__(256) void k_scatter(const int* __restrict__ eidx, const float* __restrict__ pw,
                                                 const int* __restrict__ rowptr, int* __restrict__ fill,
                                                 int* __restrict__ s_src, float* __restrict__ s_w){
  int e = blockIdx.x*256 + threadIdx.x;
  if(e < N_EDGES){
    int d = eidx[N_EDGES + e];
    int pos = rowptr[d] + atomicAdd(&fill[d], 1);
    s_src[pos] = eidx[e];
    s_w[pos]   = pw[e];
  }
}

// ---------------- GCN ----------------
__global__ __launch_bounds__(256) void k_deg(const int* __restrict__ rowptr, const float* __restrict__ s_w,
                                             float* __restrict__ dinv){
  int n = blockIdx.x*256 + threadIdx.x;
  if(n >= N_NODES) return;
  int rb = rowptr[n], re = rowptr[n+1];
  float d = 1.f; // self-loop weight
  for(int j=rb;j<re;j++) d += s_w[j];
  dinv[n] = 1.f / sqrtf(d);
}

__global__ __launch_bounds__(256) void k_enorm(const int* __restrict__ s_src, const float* __restrict__ s_w,
                                               const float* __restrict__ dinv, float* __restrict__ g_e){
  int j = blockIdx.x*256 + threadIdx.x;
  if(j < N_EDGES) g_e[j] = dinv[s_src[j]] * s_w[j];
}

__global__ __launch_bounds__(256) void k_h(const float* __restrict__ px, const float* __restrict__ gw,
                                           float* __restrict__ h){
  int n = blockIdx.x*256 + threadIdx.x;
  if(n >= N_NODES) return;
  float x[33];
  #pragma unroll
  for(int k=0;k<33;k++) x[k] = px[n*33+k];
  for(int c=0;c<33;c++){
    float a = 0.f;
    #pragma unroll
    for(int k=0;k<33;k++) a = fmaf(x[k], gw[c*33+k], a);
    h[n*33+c] = a;
  }
}

// xp1 padded to stride 36, fused: agg + gcn_b + relu + BN(eval)
__global__ __launch_bounds__(256) void k_gcn(const float* __restrict__ h, const int* __restrict__ rowptr,
                                             const int* __restrict__ s_src, const float* __restrict__ g_e,
                                             const float* __restrict__ dinv,
                                             const float* __restrict__ gcnb, const float* __restrict__ bnm,
                                             const float* __restrict__ bnv, const float* __restrict__ bnw,
                                             const float* __restrict__ bnb, float* __restrict__ xp1){
  int t = threadIdx.x;
  int nl = t/33, c = t - nl*33;
  int n = blockIdx.x*7 + nl;
  if(nl < 7 && n < N_NODES){
    float acc = 0.f;
    int rb = rowptr[n], re = rowptr[n+1];
    for(int j=rb;j<re;j++) acc = fmaf(g_e[j], h[s_src[j]*33 + c], acc);
    float dn = dinv[n];
    acc += dn * h[n*33 + c];
    float val = fmaxf(dn*acc + gcnb[c], 0.f);
    float inv = bnw[c] / sqrtf(bnv[c] + BN_EPS);
    val = val*inv + (bnb[c] - bnm[c]*inv);
    xp1[n*36 + c] = val;
  }
  int p = t - 231;
  if(p >= 0 && p < 21){
    int np = blockIdx.x*7 + p/3;
    if(np < N_NODES) xp1[np*36 + 33 + (p%3)] = 0.f;
  }
}

// ---------------- GATv2 ----------------
// 64 nodes/block; emits xr (fp32) + xlb (bf16x2-packed dwords, node stride 66;
// dword d = channels 2d,2d+1; head h owns dwords [33h, 33h+33)).
__global__ __launch_bounds__(256) void k_gatlin(const float* __restrict__ xp1, const float* __restrict__ wl,
                                                const float* __restrict__ wr, u32* __restrict__ xlb,
                                                float* __restrict__ xr){
  __shared__ float sx[64*36];    // 9 KB
  __shared__ float swl[132*33];  // 17.4 KB
  __shared__ float swr[132*33];  // 17.4 KB
  int t = threadIdx.x;
  int n0 = blockIdx.x*64;
  int nn = N_NODES - n0; if(nn > 64) nn = 64;
  for(int i=t;i<4356;i+=256){ swl[i] = wl[i]; swr[i] = wr[i]; }
  int xcnt = nn*36;
  for(int i=t;i<xcnt;i+=256) sx[i] = xp1[(size_t)n0*36 + i];
  __syncthreads();
  int total = nn*66;   // (node, dword-pair) items
  for(int p=t; p<total; p+=256){
    int n = p/66, d = p - n*66;
    int j0 = 2*d;
    const float* xv  = sx + n*36;
    const float* wl0 = swl + j0*33;
    const float* wl1 = wl0 + 33;
    const float* wr0 = swr + j0*33;
    const float* wr1 = wr0 + 33;
    float al0=0.f, al1=0.f, ar0=0.f, ar1=0.f;
    #pragma unroll
    for(int k=0;k<33;k++){
      float x = xv[k];
      al0 = fmaf(x, wl0[k], al0);
      al1 = fmaf(x, wl1[k], al1);
      ar0 = fmaf(x, wr0[k], ar0);
      ar1 = fmaf(x, wr1[k], ar1);
    }
    size_t nidx = (size_t)(n0 + n);
    xlb[nidx*66 + d] = packbf(al0, al1);
    float2 xv2; xv2.x = ar0; xv2.y = ar1;
    ((float2*)xr)[nidx*66 + d] = xv2;
  }
}

// one block per node, 2 waves (one per head); each wave = 2×32-lane edge groups.
// Group g handles edge j+g; lane l holds channels 2l,2l+1 (bf16-packed dword);
// lane l==0 also handles tail channels 64,65 (dword 32).
__global__ __launch_bounds__(128) void k_gat(const int* __restrict__ rowptr, const int* __restrict__ s_src,
                                             const u32* __restrict__ xlb, const float* __restrict__ xr,
                                             const float* __restrict__ att, const float* __restrict__ gatb,
                                             float* __restrict__ xp2){
  int n = blockIdx.x;
  int h = threadIdx.x >> 6;
  int lane = threadIdx.x & 63;
  int l = lane & 31, g = lane >> 5;
  int base = h*66, dbase = h*33;
  bool t0 = (l == 0);
  size_t nrow = (size_t)n*132;
  float2 xrv  = ((const float2*)(xr + nrow + base))[l];
  float2 xrt  = t0 ? ((const float2*)(xr + nrow + base))[32] : make_float2(0.f,0.f);
  float2 attv = ((const float2*)(att + base))[l];
  float2 attt = ((const float2*)(att + base))[32];
  // self row
  const u32* srow = xlb + (size_t)n*66 + dbase;
  u32 us  = srow[l];
  u32 ust = t0 ? srow[32] : 0u;
  float s_lo = bflo(us), s_hi = bfhi(us);
  float st_lo = bflo(ust), st_hi = bfhi(ust);
  float p = lrelu(s_lo+xrv.x)*attv.x + lrelu(s_hi+xrv.y)*attv.y
          + lrelu(st_lo+xrt.x)*attt.x + lrelu(st_hi+xrt.y)*attt.y;
  #pragma unroll
  for(int m=1;m<=16;m<<=1) p += __shfl_xor(p, m, 64);
  float e_self = p;   // identical in both groups
  float acc_lo = g==0 ? s_lo : 0.f;
  float acc_hi = g==0 ? s_hi : 0.f;
  float act_lo = g==0 ? st_lo : 0.f;
  float act_hi = g==0 ? st_hi : 0.f;
  float asum   = g==0 ? 1.f : 0.f;   // self alpha = exp(0)
  int rb = rowptr[n], re = rowptr[n+1];
  int j = rb;
  // 2 pairs (4 edges) per iteration
  for(; j+4 <= re; j += 4){
    int sA = s_src[j + g];
    int sB = s_src[j + 2 + g];
    const u32* rA = xlb + (size_t)sA*66 + dbase;
    const u32* rB = xlb + (size_t)sB*66 + dbase;
    u32 uA = rA[l], uB = rB[l];
    u32 uAt = t0 ? rA[32] : 0u;
    u32 uBt = t0 ? rB[32] : 0u;
    float vA0 = bflo(uA), vA1 = bfhi(uA), vB0 = bflo(uB), vB1 = bfhi(uB);
    float wA0 = bflo(uAt), wA1 = bfhi(uAt), wB0 = bflo(uBt), wB1 = bfhi(uBt);
    float pA = lrelu(vA0+xrv.x)*attv.x + lrelu(vA1+xrv.y)*attv.y
             + lrelu(wA0+xrt.x)*attt.x + lrelu(wA1+xrt.y)*attt.y;
    float pB = lrelu(vB0+xrv.x)*attv.x + lrelu(vB1+xrv.y)*attv.y
             + lrelu(wB0+xrt.x)*attt.x + lrelu(wB1+xrt.y)*attt.y;
    #pragma unroll
    for(int m=1;m<=16;m<<=1){
      pA += __shfl_xor(pA, m, 64);
      pB += __shfl_xor(pB, m, 64);
    }
    float aA = __expf(pA - e_self);
    float aB = __expf(pB - e_self);
    acc_lo = fmaf(aA, vA0, fmaf(aB, vB0, acc_lo));
    acc_hi = fmaf(aA, vA1, fmaf(aB, vB1, acc_hi));
    act_lo = fmaf(aA, wA0, fmaf(aB, wB0, act_lo));
    act_hi = fmaf(aA, wA1, fmaf(aB, wB1, act_hi));
    asum += aA + aB;
  }
  if(j+2 <= re){
    int s = s_src[j + g];
    const u32* r = xlb + (size_t)s*66 + dbase;
    u32 u = r[l];
    u32 ut = t0 ? r[32] : 0u;
    float v0 = bflo(u), v1 = bfhi(u), w0 = bflo(ut), w1 = bfhi(ut);
    float pp = lrelu(v0+xrv.x)*attv.x + lrelu(v1+xrv.y)*attv.y
             + lrelu(w0+xrt.x)*attt.x + lrelu(w1+xrt.y)*attt.y;
    #pragma unroll
    for(int m=1;m<=16;m<<=1) pp += __shfl_xor(pp, m, 64);
    float a = __expf(pp - e_self);
    acc_lo = fmaf(a, v0, acc_lo); acc_hi = fmaf(a, v1, acc_hi);
    act_lo = fmaf(a, w0, act_lo); act_hi = fmaf(a, w1, act_hi);
    asum += a;
    j += 2;
  }
  if(j < re){
    bool val = (g == 0);
    int s = val ? s_src[j] : n;
    const u32* r = xlb + (size_t)s*66 + dbase;
    u32 u = r[l];
    u32 ut = t0 ? r[32] : 0u;
    float v0 = bflo(u), v1 = bfhi(u), w0 = bflo(ut), w1 = bfhi(ut);
    float pp = lrelu(v0+xrv.x)*attv.x + lrelu(v1+xrv.y)*attv.y
             + lrelu(w0+xrt.x)*attt.x + lrelu(w1+xrt.y)*attt.y;
    #pragma unroll
    for(int m=1;m<=16;m<<=1) pp += __shfl_xor(pp, m, 64);
    float a = val ? __expf(pp - e_self) : 0.f;
    acc_lo = fmaf(a, v0, acc_lo); acc_hi = fmaf(a, v1, acc_hi);
    act_lo = fmaf(a, w0, act_lo); act_hi = fmaf(a, w1, act_hi);
    asum += a;
  }
  // combine the two edge-groups
  acc_lo += __shfl_xor(acc_lo, 32, 64);
  acc_hi += __shfl_xor(acc_hi, 32, 64);
  act_lo += __shfl_xor(act_lo, 32, 64);
  act_hi += __shfl_xor(act_hi, 32, 64);
  asum   += __shfl_xor(asum,   32, 64);
  float inv = 1.f/asum;
  float2 gb  = ((const float2*)(gatb + base))[l];
  if(g == 0){
    float2 o;
    o.x = fmaxf(acc_lo*inv + gb.x, 0.f);
    o.y = fmaxf(acc_hi*inv + gb.y, 0.f);
    ((float2*)(xp2 + nrow + base))[l] = o;
    if(t0){
      float2 gbt = ((const float2*)(gatb + base))[32];
      float2 ot;
      ot.x = fmaxf(act_lo*inv + gbt.x, 0.f);
      ot.y = fmaxf(act_hi*inv + gbt.y, 0.f);
      ((float2*)(xp2 + nrow + base))[32] = ot;
    }
  }
}

// ---------------- pooling + MLP head ----------------
// pro_batch is SORTED -> boundary detection, zero atomics
__global__ __launch_bounds__(256) void k_bounds(const int* __restrict__ batch, int* __restrict__ gstart,
                                                int* __restrict__ gend){
  int n = blockIdx.x*256 + threadIdx.x;
  if(n >= N_NODES) return;
  int b = batch[n];
  if(n == 0) gstart[b] = 0;
  else {
    int p = batch[n-1];
    if(p != b){ gstart[b] = n; gend[p] = n; }
  }
  if(n == N_NODES-1) gend[b] = N_NODES;
}

// stage 1: 16 segments per graph -> partial sums (1024 blocks)
__global__ __launch_bounds__(128) void k_poolp(const float* __restrict__ xp2, const int* __restrict__ gstart,
                                               const int* __restrict__ gend, float* __restrict__ pp){
  int g = blockIdx.x, seg = blockIdx.y, t = threadIdx.x;
  int s = gstart[g], e = gend[g];
  int len = e - s; if(len < 0) len = 0;
  int ns = s + (int)(((long long)len*seg)>>4);
  int ne = s + (int)(((long long)len*(seg+1))>>4);
  float a0 = 0.f, a1 = 0.f;
  for(int n=ns;n<ne;n++){
    a0 += xp2[(size_t)n*132 + t];
    if(t < 4) a1 += xp2[(size_t)n*132 + 128 + t];
  }
  float* o = pp + (size_t)(g*16 + seg)*132;
  o[t] = a0;
  if(t < 4) o[128 + t] = a1;
}

// stage 2: reduce 16 partials, divide by count
__global__ __launch_bounds__(256) void k_poolr(const float* __restrict__ pp, const int* __restrict__ gstart,
                                               const int* __restrict__ gend, float* __restrict__ pooledT){
  int g = blockIdx.x, t = threadIdx.x;
  if(t >= 132) return;
  float s = 0.f;
  #pragma unroll
  for(int k=0;k<16;k++) s += pp[(size_t)(g*16 + k)*132 + t];
  int c = gend[g] - gstart[g]; if(c < 1) c = 1;
  pooledT[t*64 + g] = s/(float)c;
}

__global__ __launch_bounds__(256) void k_fc1(const float* __restrict__ pooledT, const float* __restrict__ w,
                                             const float* __restrict__ b, float* __restrict__ h1T){
  int gid = blockIdx.x*256 + threadIdx.x;
  int o = gid >> 6, g = gid & 63;
  float acc = b[o];
  const float* wr = w + o*132;
  for(int k=0;k<132;k++) acc = fmaf(pooledT[k*64+g], wr[k], acc);
  h1T[o*64+g] = fmaxf(acc, 0.f);
}

__global__ __launch_bounds__(256) void k_fc2(const float* __restrict__ h1T, const float* __restrict__ w,
                                             const float* __restrict__ b, float* __restrict__ out){
  int gid = blockIdx.x*256 + threadIdx.x;
  int o = gid >> 6, g = gid & 63;
  float acc = b[o];
  const float* wr = w + o*1024;
  for(int k=0;k<1024;k++) acc = fmaf(h1T[k*64+g], wr[k], acc);
  out[8192 + g*128 + o] = acc;
}

// ---------------- RNA branches ----------------
// Bucket-sort the embedding indices once per (b), then gather-sum weights with
// register accumulators: zero atomics / zero LDS RMW in the hot loop.
__global__ __launch_bounds__(256) void k_bucket(const int* __restrict__ g, int L, int V,
                                                int* __restrict__ sci, int* __restrict__ off){
  __shared__ int gl[3000];
  __shared__ int hist[65];
  __shared__ int base[66];
  int b = blockIdx.x, t = threadIdx.x;
  if(t < V) hist[t] = 0;
  for(int i=t;i<L;i+=256) gl[i] = g[b*L + i];
  __syncthreads();
  for(int i=t;i<L;i+=256) atomicAdd(&hist[gl[i]], 1);
  __syncthreads();
  if(t == 0){
    int run = 0;
    for(int v=0;v<V;v++){ base[v] = run; run += hist[v]; }
    base[V] = run;
  }
  __syncthreads();
  if(t <= V) off[b*(V+1) + t] = base[t];
  if(t < V) hist[t] = 0;
  __syncthreads();
  for(int i=t;i<L;i+=256){
    int v = gl[i];
    int p = base[v] + atomicAdd(&hist[v], 1);
    sci[b*3000 + p] = i*8;   // pre-scaled
  }
}

// thread = (co = t>>3, kk = t&7); block = (b, v-range). Registers only in the hot loop.
__global__ __launch_bounds__(256) void k_sgather(const int* __restrict__ sci, const int* __restrict__ off,
                                                 const float* __restrict__ w, int V, int wstride,
                                                 int sstride, float* __restrict__ S){
  __shared__ int loff[66];
  __shared__ int lci[3000];
  int b = blockIdx.x, q = blockIdx.y, t = threadIdx.x;
  int nsplit = gridDim.y;
  if(t <= V) loff[t] = off[b*(V+1) + t];
  __syncthreads();
  int vs = (V*q)/nsplit, ve = (V*(q+1))/nsplit;
  int p0 = loff[vs], p1 = loff[ve];
  for(int i=p0+t;i<p1;i+=256) lci[i-p0] = sci[b*3000 + i];
  __syncthreads();
  int co = t >> 3, kk = t & 7;
  const float* wrow = w + co*wstride + kk;
  float* Srow = S + (size_t)b*32*sstride + co*sstride + kk;
  for(int v=vs;v<ve;v++){
    int j = loff[v] - p0, je = loff[v+1] - p0;
    float a0=0.f,a1=0.f,a2=0.f,a3=0.f,a4=0.f,a5=0.f,a6=0.f,a7=0.f;
    for(; j+8 <= je; j += 8){
      a0 += wrow[lci[j]];
      a1 += wrow[lci[j+1]];
      a2 += wrow[lci[j+2]];
      a3 += wrow[lci[j+3]];
      a4 += wrow[lci[j+4]];
      a5 += wrow[lci[j+5]];
      a6 += wrow[lci[j+6]];
      a7 += wrow[lci[j+7]];
    }
    for(; j<je; j++) a0 += wrow[lci[j]];
    Srow[v*8] = ((a0+a1)+(a2+a3)) + ((a4+a5)+(a6+a7));
  }
}

// ysum[b][co*121+l] = 0.5*(conv1+bias1)   (k_y1 writes, k_y2 adds)
__global__ __launch_bounds__(128) void k_y1(const float* __restrict__ S1, const float* __restrict__ emb1,
                                            const float* __restrict__ c1b, float* __restrict__ ysum){
  int b = blockIdx.x, co = blockIdx.y, t = threadIdx.x;
  __shared__ float em[640];
  for(int i=t;i<640;i+=128) em[i] = emb1[i];
  __syncthreads();
  if(t < 121){
    const float* S = S1 + b*1280 + co*40;
    float acc = c1b[co];
    #pragma unroll
    for(int v=0;v<5;v++)
      #pragma unroll
      for(int k=0;k<8;k++) acc = fmaf(S[v*8+k], em[v*128 + t + k], acc);
    ysum[b*3872 + co*121 + t] = 0.5f*acc;
  }
}

__global__ __launch_bounds__(128) void k_y2(const float* __restrict__ S2, const float* __restrict__ emb2,
                                            const float* __restrict__ c2b, float* __restrict__ ysum){
  int b = blockIdx.x, co = blockIdx.y, t = threadIdx.x;
  __shared__ float em[8320];
  for(int i=t;i<8320;i+=128) em[i] = emb2[i];
  __syncthreads();
  if(t < 121){
    const float* S = S2 + (size_t)b*16640 + co*520;
    float acc = c2b[co];
    for(int v=0;v<65;v++){
      #pragma unroll
      for(int k=0;k<8;k++) acc = fmaf(S[v*8+k], em[v*128 + t + k], acc);
    }
    ysum[b*3872 + co*121 + t] += 0.5f*acc;
  }
}

// out[b][o] = sum_j ysum[b][j]*fcw[o][j] + fcb[o]
// grid (64 graphs, 4 output-quarters); 8-way k-split per output, LDS reduce.
__global__ __launch_bounds__(256) void k_fcxr(const float* __restrict__ ysum, const float* __restrict__ fcw,
                                              const float* __restrict__ fcb, float* __restrict__ out){
  __shared__ float part[256];
  int b = blockIdx.x, q = blockIdx.y, t = threadIdx.x;
  int ol = t >> 3;          // 0..31
  int o  = q*32 + ol;
  int slice = t & 7;        // 0..7, each covers 121 float4 = 484 floats
  const float4* ys = (const float4*)(ysum + b*3872) + slice*121;
  const float4* wr = (const float4*)(fcw + (size_t)o*3872) + slice*121;
  float acc = 0.f;
  for(int k=0;k<121;k++){
    float4 y = ys[k], w4 = wr[k];
    acc += y.x*w4.x + y.y*w4.y + y.z*w4.z + y.w*w4.w;
  }
  part[t] = acc;
  __syncthreads();
  if(slice == 0){
    float s = fcb[o];
    #pragma unroll
    for(int i=0;i<8;i++) s += part[ol*8 + i];
    out[b*128 + o] = s;
  }
}

extern "C" void kernel_launch(void* const* d_in, const int* in_sizes, int n_in,
                              void* d_out, int out_size, void* d_ws, size_t ws_size,
                              hipStream_t stream){
  const int*   g_rna = (const int*)  d_in[0];
  const int*   l_rna = (const int*)  d_in[1];
  const float* pro_x = (const float*)d_in[2];
  const int*   eidx  = (const int*)  d_in[3];
  const float* pro_w = (const float*)d_in[4];
  const int*   batch = (const int*)  d_in[5];
  const float* emb1  = (const float*)d_in[6];
  const float* emb2  = (const float*)d_in[7];
  const float* c1w   = (const float*)d_in[8];
  const float* c1b   = (const float*)d_in[9];
  const float* c2w   = (const float*)d_in[10];
  const float* c2b   = (const float*)d_in[11];
  const float* fcxw  = (const float*)d_in[12];
  const float* fcxb  = (const float*)d_in[13];
  const float* gcnw  = (const float*)d_in[14];
  const float* gcnb  = (const float*)d_in[15];
  const float* bnm   = (const float*)d_in[16];
  const float* bnv   = (const float*)d_in[17];
  const float* bnw   = (const float*)d_in[18];
  const float* bnb   = (const float*)d_in[19];
  const float* gwl   = (const float*)d_in[20];
  const float* gwr   = (const float*)d_in[21];
  const float* gatt  = (const float*)d_in[22];
  const float* gatb  = (const float*)d_in[23];
  const float* f1w   = (const float*)d_in[24];
  const float* f1b   = (const float*)d_in[25];
  const float* f2w   = (const float*)d_in[26];
  const float* f2b_  = (const float*)d_in[27];
  float* out = (float*)d_out;

  char* ws = (char*)d_ws;
  size_t off = 0;
  auto A = [&](size_t n)->char*{ char* p = ws + off; off = (off + n + 255) & ~(size_t)255; return p; };
  int*   cnt    = (int*)  A((size_t)N_NODES*4);
  int*   rowptr = (int*)  A((size_t)(N_NODES+1)*4);
  int*   fill   = (int*)  A((size_t)N_NODES*4);
  int*   s_src  = (int*)  A((size_t)N_EDGES*4);
  float* s_w    = (float*)A((size_t)N_EDGES*4);
  float* g_e    = (float*)A((size_t)N_EDGES*4);
  float* dinv   = (float*)A((size_t)N_NODES*4);
  float* hbuf   = (float*)A((size_t)N_NODES*33*4);
  float* xp1    = (float*)A((size_t)N_NODES*36*4);
  u32*   xlb    = (u32*)  A((size_t)N_NODES*66*4);
  float* xr     = (float*)A((size_t)N_NODES*132*4);
  float* xp2    = (float*)A((size_t)N_NODES*132*4);
  int*   gstart = (int*)  A(64*4);
  int*   gend   = (int*)  A(64*4);
  float* pooledT= (float*)A(132*64*4);
  float* pp     = (float*)A((size_t)64*16*132*4);
  float* h1T    = (float*)A(1024*64*4);
  float* S1     = (float*)A((size_t)64*1280*4);
  float* S2     = (float*)A((size_t)64*16640*4);
  float* ysum   = (float*)A((size_t)64*3872*4);
  int*   sci1   = (int*)  A((size_t)64*3000*4);
  int*   off1   = (int*)  A((size_t)64*8*4);
  int*   sci2   = (int*)  A((size_t)64*3000*4);
  int*   off2   = (int*)  A((size_t)64*66*4);
  (void)ws_size; (void)in_sizes; (void)n_in; (void)out_size;

  // protein GNN pipeline
  k_init   <<<196, 256, 0, stream>>>(cnt, fill, gstart, gend);
  k_hist   <<<3125, 256, 0, stream>>>(eidx, cnt);
  k_scan   <<<1, 1024, 0, stream>>>(cnt, rowptr);
  k_scatter<<<3125, 256, 0, stream>>>(eidx, pro_w, rowptr, fill, s_src, s_w);
  k_deg    <<<196, 256, 0, stream>>>(rowptr, s_w, dinv);
  k_enorm  <<<3125, 256, 0, stream>>>(s_src, s_w, dinv, g_e);
  k_h      <<<196, 256, 0, stream>>>(pro_x, gcnw, hbuf);
  k_gcn    <<<7143, 256, 0, stream>>>(hbuf, rowptr, s_src, g_e, dinv, gcnb, bnm, bnv, bnw, bnb, xp1);
  k_gatlin <<<782, 256, 0, stream>>>(xp1, gwl, gwr, xlb, xr);
  k_gat    <<<N_NODES, 128, 0, stream>>>(rowptr, s_src, xlb, xr, gatt, gatb, xp2);
  k_bounds <<<196, 256, 0, stream>>>(batch, gstart, gend);
  k_poolp  <<<dim3(64,16), 128, 0, stream>>>(xp2, gstart, gend, pp);
  k_poolr  <<<64, 256, 0, stream>>>(pp, gstart, gend, pooledT);
  k_fc1    <<<256, 256, 0, stream>>>(pooledT, f1w, f1b, h1T);
  k_fc2    <<<32, 256, 0, stream>>>(h1T, f2w, f2b_, out);

  // RNA branches: bucket-sort + register gather
  k_bucket <<<64, 256, 0, stream>>>(g_rna, 3000, 5, sci1, off1);
  k_bucket <<<64, 256, 0, stream>>>(l_rna, 2998, 65, sci2, off2);
  k_sgather<<<dim3(64,5), 256, 0, stream>>>(sci1, off1, c1w, 5, 24000, 40, S1);
  k_sgather<<<dim3(64,8), 256, 0, stream>>>(sci2, off2, c2w, 65, 23984, 520, S2);
  k_y1  <<<dim3(64,32), 128, 0, stream>>>(S1, emb1, c1b, ysum);
  k_y2  <<<dim3(64,32), 128, 0, stream>>>(S2, emb2, c2b, ysum);
  k_fcxr<<<dim3(64,4), 256, 0, stream>>>(ysum, fcxw, fcxb, out);
}

// Round 10
// 661.110 us; speedup vs baseline: 1.7110x; 1.0656x over previous
//
#include <hip/hip_runtime.h>

#define N_NODES 50000
#define N_EDGES 800000
#define LRELU_SLOPE 0.2f
#define BN_EPS 1e-5f

typedef unsigned int u32;

__device__ __forceinline__ float lrelu(float x){ return fmaxf(x,0.f) + LRELU_SLOPE*fminf(x,0.f); }
__device__ __forceinline__ float bflo(u32 u){ return __uint_as_float(u<<16); }
__device__ __forceinline__ float bfhi(u32 u){ return __uint_as_float(u & 0xffff0000u); }
__device__ __forceinline__ u32 packbf(float a, float b){
  u32 ua = __float_as_uint(a); ua = (ua + 0x7fffu + ((ua>>16)&1u)) >> 16;
  u32 ub = __float_as_uint(b); ub = (ub + 0x7fffu + ((ub>>16)&1u)) >> 16;
  return ua | (ub<<16);
}

// ---------------- CSR build ----------------
__global__ __launch_bounds__(256) void k_init(int* __restrict__ cnt, int* __restrict__ fill,
                                              int* __restrict__ gstart, int* __restrict__ gend){
  int i = blockIdx.x*256 + threadIdx.x;
  if(i < N_NODES){ cnt[i] = 0; fill[i] = 0; }
  if(i < 64){ gstart[i] = N_NODES; gend[i] = 0; }
}

__global__ __launch_bounds__(256) void k_hist(const int* __restrict__ eidx, int* __restrict__ cnt){
  int e = blockIdx.x*256 + threadIdx.x;
  if(e < N_EDGES) atomicAdd(&cnt[eidx[N_EDGES + e]], 1);
}

__global__ __launch_bounds__(1024) void k_scan(const int* __restrict__ cnt, int* __restrict__ rowptr){
  __shared__ int part[1024];
  int t = threadIdx.x;
  const int per = (N_NODES + 1023)/1024; // 49
  int beg = t*per, end = beg+per; if(end > N_NODES) end = N_NODES;
  int s = 0;
  for(int i=beg;i<end;i++) s += cnt[i];
  part[t] = s;
  __syncthreads();
  for(int off=1; off<1024; off<<=1){
    int v = (t>=off) ? part[t-off] : 0;
    __syncthreads();
    part[t] += v;
    __syncthreads();
  }
  int run = (t==0) ? 0 : part[t-1];
  for(int i=beg;i<end;i++){ rowptr[i] = run; run += cnt[i]; }
  if(t==1023) rowptr[N_NODES] = run;
}

__global__ __launch_bounds__(256) void k_scatter(const int* __restrict__ eidx, const float* __restrict__ pw,
                                                 const int* __restrict__ rowptr, int* __restrict__ fill,
                                                 int* __restrict__ s_src, float* __restrict__ s_w){
  int e = blockIdx.x*256 + threadIdx.x;
  if(e < N_EDGES){
    int d = eidx[N_EDGES + e];
    int pos = rowptr[d] + atomicAdd(&fill[d], 1);
    s_src[pos] = eidx[e];
    s_w[pos]   = pw[e];
  }
}

// ---------------- GCN ----------------
__global__ __launch_bounds__(256) void k_deg(const int* __restrict__ rowptr, const float* __restrict__ s_w,
                                             float* __restrict__ dinv){
  int n = blockIdx.x*256 + threadIdx.x;
  if(n >= N_NODES) return;
  int rb = rowptr[n], re = rowptr[n+1];
  float d = 1.f; // self-loop weight
  for(int j=rb;j<re;j++) d += s_w[j];
  dinv[n] = 1.f / sqrtf(d);
}

__global__ __launch_bounds__(256) void k_enorm(const int* __restrict__ s_src, const float* __restrict__ s_w,
                                               const float* __restrict__ dinv, float* __restrict__ g_e){
  int j = blockIdx.x*256 + threadIdx.x;
  if(j < N_EDGES) g_e[j] = dinv[s_src[j]] * s_w[j];
}

// h = pro_x @ gcn_w.T, packed to bf16 pairs: 17 dwords/node (dword d = ch 2d,2d+1; dword16 = ch32,pad)
__global__ __launch_bounds__(256) void k_h(const float* __restrict__ px, const float* __restrict__ gw,
                                           u32* __restrict__ hb){
  int n = blockIdx.x*256 + threadIdx.x;
  if(n >= N_NODES) return;
  float x[33];
  #pragma unroll
  for(int k=0;k<33;k++) x[k] = px[n*33+k];
  float a[33];
  for(int c=0;c<33;c++){
    float s = 0.f;
    #pragma unroll
    for(int k=0;k<33;k++) s = fmaf(x[k], gw[c*33+k], s);
    a[c] = s;
  }
  #pragma unroll
  for(int d=0;d<16;d++) hb[(size_t)n*17 + d] = packbf(a[2*d], a[2*d+1]);
  hb[(size_t)n*17 + 16] = packbf(a[32], 0.f);
}

// wave per node, 4 groups x 16 lanes, 4 edges/iter; bf16 h gather; fused bias+relu+BN.
__global__ __launch_bounds__(256) void k_gcn(const u32* __restrict__ hb, const int* __restrict__ rowptr,
                                             const int* __restrict__ s_src, const float* __restrict__ g_e,
                                             const float* __restrict__ dinv,
                                             const float* __restrict__ gcnb, const float* __restrict__ bnm,
                                             const float* __restrict__ bnv, const float* __restrict__ bnw,
                                             const float* __restrict__ bnb, float* __restrict__ xp1){
  int wave = threadIdx.x >> 6;
  int lane = threadIdx.x & 63;
  int n = blockIdx.x*4 + wave;
  if(n >= N_NODES) return;
  int l = lane & 15, g = lane >> 4;
  bool t0 = (l == 0);
  float dn = dinv[n];
  const u32* srow = hb + (size_t)n*17;
  u32 us  = srow[l];
  u32 ust = t0 ? srow[16] : 0u;
  float acc0, acc1, acct;
  if(g == 0){ acc0 = dn*bflo(us); acc1 = dn*bfhi(us); acct = dn*bflo(ust); }
  else      { acc0 = 0.f; acc1 = 0.f; acct = 0.f; }
  int rb = rowptr[n], re = rowptr[n+1];
  int j = rb;
  for(; j+4 <= re; j += 4){
    int e = j + g;
    float ge = g_e[e];
    int s = s_src[e];
    const u32* r = hb + (size_t)s*17;
    u32 u  = r[l];
    u32 ut = t0 ? r[16] : 0u;
    acc0 = fmaf(ge, bflo(u),  acc0);
    acc1 = fmaf(ge, bfhi(u),  acc1);
    acct = fmaf(ge, bflo(ut), acct);
  }
  int rem = re - j;
  if(rem > 0){
    bool val = (g < rem);
    int e = val ? (j + g) : j;
    float ge = val ? g_e[e] : 0.f;
    int s = s_src[e];
    const u32* r = hb + (size_t)s*17;
    u32 u  = r[l];
    u32 ut = t0 ? r[16] : 0u;
    acc0 = fmaf(ge, bflo(u),  acc0);
    acc1 = fmaf(ge, bfhi(u),  acc1);
    acct = fmaf(ge, bflo(ut), acct);
  }
  #pragma unroll
  for(int m=16;m<=32;m<<=1){
    acc0 += __shfl_xor(acc0, m, 64);
    acc1 += __shfl_xor(acc1, m, 64);
    acct += __shfl_xor(acct, m, 64);
  }
  if(g == 0){
    int c0 = 2*l, c1 = 2*l+1;
    float v0 = fmaxf(dn*acc0 + gcnb[c0], 0.f);
    float v1 = fmaxf(dn*acc1 + gcnb[c1], 0.f);
    float i0 = bnw[c0] / sqrtf(bnv[c0] + BN_EPS);
    float i1 = bnw[c1] / sqrtf(bnv[c1] + BN_EPS);
    float2 o;
    o.x = v0*i0 + (bnb[c0] - bnm[c0]*i0);
    o.y = v1*i1 + (bnb[c1] - bnm[c1]*i1);
    ((float2*)(xp1 + (size_t)n*36))[l] = o;
    if(t0){
      float vt = fmaxf(dn*acct + gcnb[32], 0.f);
      float it = bnw[32] / sqrtf(bnv[32] + BN_EPS);
      float2 ot; ot.x = vt*it + (bnb[32] - bnm[32]*it); ot.y = 0.f;
      ((float2*)(xp1 + (size_t)n*36))[16] = ot;
      float2 z; z.x = 0.f; z.y = 0.f;
      ((float2*)(xp1 + (size_t)n*36))[17] = z;
    }
  }
}

// ---------------- GATv2 ----------------
// 64 nodes/block; emits xr (fp32) + xlb (bf16x2 dwords, node stride 68, head h at dwords [34h,34h+33)).
__global__ __launch_bounds__(256) void k_gatlin(const float* __restrict__ xp1, const float* __restrict__ wl,
                                                const float* __restrict__ wr, u32* __restrict__ xlb,
                                                float* __restrict__ xr){
  __shared__ float sx[64*36];    // 9 KB
  __shared__ float swl[132*33];  // 17.4 KB
  __shared__ float swr[132*33];  // 17.4 KB
  int t = threadIdx.x;
  int n0 = blockIdx.x*64;
  int nn = N_NODES - n0; if(nn > 64) nn = 64;
  for(int i=t;i<4356;i+=256){ swl[i] = wl[i]; swr[i] = wr[i]; }
  int xcnt = nn*36;
  for(int i=t;i<xcnt;i+=256) sx[i] = xp1[(size_t)n0*36 + i];
  __syncthreads();
  int total = nn*66;   // (node, dword-pair) items
  for(int p=t; p<total; p+=256){
    int n = p/66, d = p - n*66;
    int j0 = 2*d;
    const float* xv  = sx + n*36;
    const float* wl0 = swl + j0*33;
    const float* wl1 = wl0 + 33;
    const float* wr0 = swr + j0*33;
    const float* wr1 = wr0 + 33;
    float al0=0.f, al1=0.f, ar0=0.f, ar1=0.f;
    #pragma unroll
    for(int k=0;k<33;k++){
      float x = xv[k];
      al0 = fmaf(x, wl0[k], al0);
      al1 = fmaf(x, wl1[k], al1);
      ar0 = fmaf(x, wr0[k], ar0);
      ar1 = fmaf(x, wr1[k], ar1);
    }
    size_t nidx = (size_t)(n0 + n);
    int head = (d >= 33) ? 1 : 0;
    int dd = d - 33*head;
    xlb[nidx*68 + head*34 + dd] = packbf(al0, al1);
    float2 xv2; xv2.x = ar0; xv2.y = ar1;
    ((float2*)xr)[nidx*66 + d] = xv2;
  }
}

// one block per node, 2 waves (head each); wave = 4 x 16-lane groups, 4 edges/iter.
// Lane l holds channels 4l..4l+3 (uint2 of bf16 pairs); lane0 of each group holds tail ch 64,65.
__global__ __launch_bounds__(128) void k_gat(const int* __restrict__ rowptr, const int* __restrict__ s_src,
                                             const u32* __restrict__ xlb, const float* __restrict__ xr,
                                             const float* __restrict__ att, const float* __restrict__ gatb,
                                             float* __restrict__ xp2){
  int n = blockIdx.x;
  int h = threadIdx.x >> 6;
  int lane = threadIdx.x & 63;
  int l = lane & 15, g = lane >> 4;
  int base = h*66, dbase = h*34;
  bool t0 = (l == 0);
  size_t nrow = (size_t)n*132;
  const float2* xr2 = (const float2*)(xr + nrow + base);
  float2 xra = xr2[2*l], xrb = xr2[2*l+1];
  float2 xrt = t0 ? xr2[32] : make_float2(0.f,0.f);
  const float2* att2 = (const float2*)(att + base);
  float2 ata = att2[2*l], atb = att2[2*l+1];
  float2 att_t = att2[32];
  // self row
  const u32* srow = xlb + (size_t)n*68 + dbase;
  uint2 su = ((const uint2*)srow)[l];
  u32 ust = t0 ? srow[32] : 0u;
  float s0 = bflo(su.x), s1 = bfhi(su.x), s2 = bflo(su.y), s3 = bfhi(su.y);
  float st0 = bflo(ust), st1 = bfhi(ust);
  float p = lrelu(s0+xra.x)*ata.x + lrelu(s1+xra.y)*ata.y
          + lrelu(s2+xrb.x)*atb.x + lrelu(s3+xrb.y)*atb.y
          + lrelu(st0+xrt.x)*att_t.x + lrelu(st1+xrt.y)*att_t.y;
  #pragma unroll
  for(int m=1;m<=8;m<<=1) p += __shfl_xor(p, m, 64);
  float e_self = p;
  float a0_, a1_, a2_, a3_, at0, at1, asum;
  if(g == 0){ a0_=s0; a1_=s1; a2_=s2; a3_=s3; at0=st0; at1=st1; asum=1.f; }
  else      { a0_=0.f; a1_=0.f; a2_=0.f; a3_=0.f; at0=0.f; at1=0.f; asum=0.f; }
  int rb = rowptr[n], re = rowptr[n+1];
  int j = rb;
  for(; j+4 <= re; j += 4){
    int s = s_src[j + g];
    const u32* r = xlb + (size_t)s*68 + dbase;
    uint2 uu = ((const uint2*)r)[l];
    u32 ut = t0 ? r[32] : 0u;
    float v0=bflo(uu.x), v1=bfhi(uu.x), v2=bflo(uu.y), v3=bfhi(uu.y);
    float w0=bflo(ut), w1=bfhi(ut);
    float pp = lrelu(v0+xra.x)*ata.x + lrelu(v1+xra.y)*ata.y
             + lrelu(v2+xrb.x)*atb.x + lrelu(v3+xrb.y)*atb.y
             + lrelu(w0+xrt.x)*att_t.x + lrelu(w1+xrt.y)*att_t.y;
    #pragma unroll
    for(int m=1;m<=8;m<<=1) pp += __shfl_xor(pp, m, 64);
    float a = __expf(pp - e_self);
    a0_ = fmaf(a, v0, a0_); a1_ = fmaf(a, v1, a1_);
    a2_ = fmaf(a, v2, a2_); a3_ = fmaf(a, v3, a3_);
    at0 = fmaf(a, w0, at0); at1 = fmaf(a, w1, at1);
    asum += a;
  }
  int rem = re - j;
  if(rem > 0){
    bool val = (g < rem);
    int s = val ? s_src[j + g] : n;
    const u32* r = xlb + (size_t)s*68 + dbase;
    uint2 uu = ((const uint2*)r)[l];
    u32 ut = t0 ? r[32] : 0u;
    float v0=bflo(uu.x), v1=bfhi(uu.x), v2=bflo(uu.y), v3=bfhi(uu.y);
    float w0=bflo(ut), w1=bfhi(ut);
    float pp = lrelu(v0+xra.x)*ata.x + lrelu(v1+xra.y)*ata.y
             + lrelu(v2+xrb.x)*atb.x + lrelu(v3+xrb.y)*atb.y
             + lrelu(w0+xrt.x)*att_t.x + lrelu(w1+xrt.y)*att_t.y;
    #pragma unroll
    for(int m=1;m<=8;m<<=1) pp += __shfl_xor(pp, m, 64);
    float a = val ? __expf(pp - e_self) : 0.f;
    a0_ = fmaf(a, v0, a0_); a1_ = fmaf(a, v1, a1_);
    a2_ = fmaf(a, v2, a2_); a3_ = fmaf(a, v3, a3_);
    at0 = fmaf(a, w0, at0); at1 = fmaf(a, w1, at1);
    asum += a;
  }
  #pragma unroll
  for(int m=16;m<=32;m<<=1){
    a0_ += __shfl_xor(a0_, m, 64);
    a1_ += __shfl_xor(a1_, m, 64);
    a2_ += __shfl_xor(a2_, m, 64);
    a3_ += __shfl_xor(a3_, m, 64);
    at0 += __shfl_xor(at0, m, 64);
    at1 += __shfl_xor(at1, m, 64);
    asum += __shfl_xor(asum, m, 64);
  }
  float inv = 1.f/asum;
  if(g == 0){
    const float2* gb2 = (const float2*)(gatb + base);
    float2 ga = gb2[2*l], gb = gb2[2*l+1];
    float2* o2 = (float2*)(xp2 + nrow + base);
    float2 oa, ob;
    oa.x = fmaxf(a0_*inv + ga.x, 0.f); oa.y = fmaxf(a1_*inv + ga.y, 0.f);
    ob.x = fmaxf(a2_*inv + gb.x, 0.f); ob.y = fmaxf(a3_*inv + gb.y, 0.f);
    o2[2*l] = oa; o2[2*l+1] = ob;
    if(t0){
      float2 gt = gb2[32];
      float2 ot;
      ot.x = fmaxf(at0*inv + gt.x, 0.f); ot.y = fmaxf(at1*inv + gt.y, 0.f);
      o2[32] = ot;
    }
  }
}

// ---------------- pooling + MLP head ----------------
__global__ __launch_bounds__(256) void k_bounds(const int* __restrict__ batch, int* __restrict__ gstart,
                                                int* __restrict__ gend){
  int n = blockIdx.x*256 + threadIdx.x;
  if(n >= N_NODES) return;
  int b = batch[n];
  if(n == 0) gstart[b] = 0;
  else {
    int p = batch[n-1];
    if(p != b){ gstart[b] = n; gend[p] = n; }
  }
  if(n == N_NODES-1) gend[b] = N_NODES;
}

__global__ __launch_bounds__(128) void k_poolp(const float* __restrict__ xp2, const int* __restrict__ gstart,
                                               const int* __restrict__ gend, float* __restrict__ pp){
  int g = blockIdx.x, seg = blockIdx.y, t = threadIdx.x;
  int s = gstart[g], e = gend[g];
  int len = e - s; if(len < 0) len = 0;
  int ns = s + (int)(((long long)len*seg)>>4);
  int ne = s + (int)(((long long)len*(seg+1))>>4);
  float a0 = 0.f, a1 = 0.f;
  for(int n=ns;n<ne;n++){
    a0 += xp2[(size_t)n*132 + t];
    if(t < 4) a1 += xp2[(size_t)n*132 + 128 + t];
  }
  float* o = pp + (size_t)(g*16 + seg)*132;
  o[t] = a0;
  if(t < 4) o[128 + t] = a1;
}

__global__ __launch_bounds__(256) void k_poolr(const float* __restrict__ pp, const int* __restrict__ gstart,
                                               const int* __restrict__ gend, float* __restrict__ pooledT){
  int g = blockIdx.x, t = threadIdx.x;
  if(t >= 132) return;
  float s = 0.f;
  #pragma unroll
  for(int k=0;k<16;k++) s += pp[(size_t)(g*16 + k)*132 + t];
  int c = gend[g] - gstart[g]; if(c < 1) c = 1;
  pooledT[t*64 + g] = s/(float)c;
}

__global__ __launch_bounds__(256) void k_fc1(const float* __restrict__ pooledT, const float* __restrict__ w,
                                             const float* __restrict__ b, float* __restrict__ h1T){
  int gid = blockIdx.x*256 + threadIdx.x;
  int o = gid >> 6, g = gid & 63;
  float acc = b[o];
  const float* wr = w + o*132;
  for(int k=0;k<132;k++) acc = fmaf(pooledT[k*64+g], wr[k], acc);
  h1T[o*64+g] = fmaxf(acc, 0.f);
}

// block per output o (128 blocks); 256 threads = 4 k-slices x 64 graphs; LDS reduce.
__global__ __launch_bounds__(256) void k_fc2(const float* __restrict__ h1T, const float* __restrict__ w,
                                             const float* __restrict__ b, float* __restrict__ out){
  __shared__ float part[256];
  int o = blockIdx.x, t = threadIdx.x;
  int s = t >> 6, g = t & 63;
  const float* wr = w + o*1024 + s*256;
  const float* hp = h1T + (size_t)(s*256)*64 + g;
  float acc = 0.f;
  for(int k=0;k<256;k++) acc = fmaf(hp[k*64], wr[k], acc);
  part[t] = acc;
  __syncthreads();
  if(s == 0){
    float r = b[o] + part[g] + part[64+g] + part[128+g] + part[192+g];
    out[8192 + g*128 + o] = r;
  }
}

// ---------------- RNA branches ----------------
__global__ __launch_bounds__(256) void k_bucket(const int* __restrict__ g, int L, int V,
                                                int* __restrict__ sci, int* __restrict__ off){
  __shared__ int gl[3000];
  __shared__ int hist[65];
  __shared__ int base[66];
  int b = blockIdx.x, t = threadIdx.x;
  if(t < V) hist[t] = 0;
  for(int i=t;i<L;i+=256) gl[i] = g[b*L + i];
  __syncthreads();
  for(int i=t;i<L;i+=256) atomicAdd(&hist[gl[i]], 1);
  __syncthreads();
  if(t == 0){
    int run = 0;
    for(int v=0;v<V;v++){ base[v] = run; run += hist[v]; }
    base[V] = run;
  }
  __syncthreads();
  if(t <= V) off[b*(V+1) + t] = base[t];
  if(t < V) hist[t] = 0;
  __syncthreads();
  for(int i=t;i<L;i+=256){
    int v = gl[i];
    int p = base[v] + atomicAdd(&hist[v], 1);
    sci[b*3000 + p] = i*8;   // pre-scaled
  }
}

__global__ __launch_bounds__(256) void k_sgather(const int* __restrict__ sci, const int* __restrict__ off,
                                                 const float* __restrict__ w, int V, int wstride,
                                                 int sstride, float* __restrict__ S){
  __shared__ int loff[66];
  __shared__ int lci[3000];
  int b = blockIdx.x, q = blockIdx.y, t = threadIdx.x;
  int nsplit = gridDim.y;
  if(t <= V) loff[t] = off[b*(V+1) + t];
  __syncthreads();
  int vs = (V*q)/nsplit, ve = (V*(q+1))/nsplit;
  int p0 = loff[vs], p1 = loff[ve];
  for(int i=p0+t;i<p1;i+=256) lci[i-p0] = sci[b*3000 + i];
  __syncthreads();
  int co = t >> 3, kk = t & 7;
  const float* wrow = w + co*wstride + kk;
  float* Srow = S + (size_t)b*32*sstride + co*sstride + kk;
  for(int v=vs;v<ve;v++){
    int j = loff[v] - p0, je = loff[v+1] - p0;
    float a0=0.f,a1=0.f,a2=0.f,a3=0.f,a4=0.f,a5=0.f,a6=0.f,a7=0.f;
    for(; j+8 <= je; j += 8){
      a0 += wrow[lci[j]];
      a1 += wrow[lci[j+1]];
      a2 += wrow[lci[j+2]];
      a3 += wrow[lci[j+3]];
      a4 += wrow[lci[j+4]];
      a5 += wrow[lci[j+5]];
      a6 += wrow[lci[j+6]];
      a7 += wrow[lci[j+7]];
    }
    for(; j<je; j++) a0 += wrow[lci[j]];
    Srow[v*8] = ((a0+a1)+(a2+a3)) + ((a4+a5)+(a6+a7));
  }
}

// ysum[b][co*121+l] = 0.5*(conv1+bias1)   (k_y1 writes, k_y2 adds)
__global__ __launch_bounds__(128) void k_y1(const float* __restrict__ S1, const float* __restrict__ emb1,
                                            const float* __restrict__ c1b, float* __restrict__ ysum){
  int b = blockIdx.x, co = blockIdx.y, t = threadIdx.x;
  __shared__ float em[640];
  for(int i=t;i<640;i+=128) em[i] = emb1[i];
  __syncthreads();
  if(t < 121){
    const float* S = S1 + b*1280 + co*40;
    float acc = c1b[co];
    #pragma unroll
    for(int v=0;v<5;v++)
      #pragma unroll
      for(int k=0;k<8;k++) acc = fmaf(S[v*8+k], em[v*128 + t + k], acc);
    ysum[b*3872 + co*121 + t] = 0.5f*acc;
  }
}

__global__ __launch_bounds__(128) void k_y2(const float* __restrict__ S2, const float* __restrict__ emb2,
                                            const float* __restrict__ c2b, float* __restrict__ ysum){
  int b = blockIdx.x, co = blockIdx.y, t = threadIdx.x;
  __shared__ float em[8320];
  for(int i=t;i<8320;i+=128) em[i] = emb2[i];
  __syncthreads();
  if(t < 121){
    const float* S = S2 + (size_t)b*16640 + co*520;
    float acc = c2b[co];
    for(int v=0;v<65;v++){
      #pragma unroll
      for(int k=0;k<8;k++) acc = fmaf(S[v*8+k], em[v*128 + t + k], acc);
    }
    ysum[b*3872 + co*121 + t] += 0.5f*acc;
  }
}

// out[b][o] = sum_j ysum[b][j]*fcw[o][j] + fcb[o]
__global__ __launch_bounds__(256) void k_fcxr(const float* __restrict__ ysum, const float* __restrict__ fcw,
                                              const float* __restrict__ fcb, float* __restrict__ out){
  __shared__ float part[256];
  int b = blockIdx.x, q = blockIdx.y, t = threadIdx.x;
  int ol = t >> 3;
  int o  = q*32 + ol;
  int slice = t & 7;
  const float4* ys = (const float4*)(ysum + b*3872) + slice*121;
  const float4* wr = (const float4*)(fcw + (size_t)o*3872) + slice*121;
  float acc = 0.f;
  for(int k=0;k<121;k++){
    float4 y = ys[k], w4 = wr[k];
    acc += y.x*w4.x + y.y*w4.y + y.z*w4.z + y.w*w4.w;
  }
  part[t] = acc;
  __syncthreads();
  if(slice == 0){
    float s = fcb[o];
    #pragma unroll
    for(int i=0;i<8;i++) s += part[ol*8 + i];
    out[b*128 + o] = s;
  }
}

extern "C" void kernel_launch(void* const* d_in, const int* in_sizes, int n_in,
                              void* d_out, int out_size, void* d_ws, size_t ws_size,
                              hipStream_t stream){
  const int*   g_rna = (const int*)  d_in[0];
  const int*   l_rna = (const int*)  d_in[1];
  const float* pro_x = (const float*)d_in[2];
  const int*   eidx  = (const int*)  d_in[3];
  const float* pro_w = (const float*)d_in[4];
  const int*   batch = (const int*)  d_in[5];
  const float* emb1  = (const float*)d_in[6];
  const float* emb2  = (const float*)d_in[7];
  const float* c1w   = (const float*)d_in[8];
  const float* c1b   = (const float*)d_in[9];
  const float* c2w   = (const float*)d_in[10];
  const float* c2b   = (const float*)d_in[11];
  const float* fcxw  = (const float*)d_in[12];
  const float* fcxb  = (const float*)d_in[13];
  const float* gcnw  = (const float*)d_in[14];
  const float* gcnb  = (const float*)d_in[15];
  const float* bnm   = (const float*)d_in[16];
  const float* bnv   = (const float*)d_in[17];
  const float* bnw   = (const float*)d_in[18];
  const float* bnb   = (const float*)d_in[19];
  const float* gwl   = (const float*)d_in[20];
  const float* gwr   = (const float*)d_in[21];
  const float* gatt  = (const float*)d_in[22];
  const float* gatb  = (const float*)d_in[23];
  const float* f1w   = (const float*)d_in[24];
  const float* f1b   = (const float*)d_in[25];
  const float* f2w   = (const float*)d_in[26];
  const float* f2b_  = (const float*)d_in[27];
  float* out = (float*)d_out;

  char* ws = (char*)d_ws;
  size_t off = 0;
  auto A = [&](size_t n)->char*{ char* p = ws + off; off = (off + n + 255) & ~(size_t)255; return p; };
  int*   cnt    = (int*)  A((size_t)N_NODES*4);
  int*   rowptr = (int*)  A((size_t)(N_NODES+1)*4);
  int*   fill   = (int*)  A((size_t)N_NODES*4);
  int*   s_src  = (int*)  A((size_t)N_EDGES*4);
  float* s_w    = (float*)A((size_t)N_EDGES*4);
  float* g_e    = (float*)A((size_t)N_EDGES*4);
  float* dinv   = (float*)A((size_t)N_NODES*4);
  u32*   hb     = (u32*)  A((size_t)N_NODES*17*4);
  float* xp1    = (float*)A((size_t)N_NODES*36*4);
  u32*   xlb    = (u32*)  A((size_t)N_NODES*68*4);
  float* xr     = (float*)A((size_t)N_NODES*132*4);
  float* xp2    = (float*)A((size_t)N_NODES*132*4);
  int*   gstart = (int*)  A(64*4);
  int*   gend   = (int*)  A(64*4);
  float* pooledT= (float*)A(132*64*4);
  float* pp     = (float*)A((size_t)64*16*132*4);
  float* h1T    = (float*)A(1024*64*4);
  float* S1     = (float*)A((size_t)64*1280*4);
  float* S2     = (float*)A((size_t)64*16640*4);
  float* ysum   = (float*)A((size_t)64*3872*4);
  int*   sci1   = (int*)  A((size_t)64*3000*4);
  int*   off1   = (int*)  A((size_t)64*8*4);
  int*   sci2   = (int*)  A((size_t)64*3000*4);
  int*   off2   = (int*)  A((size_t)64*66*4);
  (void)ws_size; (void)in_sizes; (void)n_in; (void)out_size;

  // protein GNN pipeline
  k_init   <<<196, 256, 0, stream>>>(cnt, fill, gstart, gend);
  k_hist   <<<3125, 256, 0, stream>>>(eidx, cnt);
  k_scan   <<<1, 1024, 0, stream>>>(cnt, rowptr);
  k_scatter<<<3125, 256, 0, stream>>>(eidx, pro_w, rowptr, fill, s_src, s_w);
  k_deg    <<<196, 256, 0, stream>>>(rowptr, s_w, dinv);
  k_enorm  <<<3125, 256, 0, stream>>>(s_src, s_w, dinv, g_e);
  k_h      <<<196, 256, 0, stream>>>(pro_x, gcnw, hb);
  k_gcn    <<<12500, 256, 0, stream>>>(hb, rowptr, s_src, g_e, dinv, gcnb, bnm, bnv, bnw, bnb, xp1);
  k_gatlin <<<782, 256, 0, stream>>>(xp1, gwl, gwr, xlb, xr);
  k_gat    <<<N_NODES, 128, 0, stream>>>(rowptr, s_src, xlb, xr, gatt, gatb, xp2);
  k_bounds <<<196, 256, 0, stream>>>(batch, gstart, gend);
  k_poolp  <<<dim3(64,16), 128, 0, stream>>>(xp2, gstart, gend, pp);
  k_poolr  <<<64, 256, 0, stream>>>(pp, gstart, gend, pooledT);
  k_fc1    <<<256, 256, 0, stream>>>(pooledT, f1w, f1b, h1T);
  k_fc2    <<<128, 256, 0, stream>>>(h1T, f2w, f2b_, out);

  // RNA branches: bucket-sort + register gather
  k_bucket <<<64, 256, 0, stream>>>(g_rna, 3000, 5, sci1, off1);
  k_bucket <<<64, 256, 0, stream>>>(l_rna, 2998, 65, sci2, off2);
  k_sgather<<<dim3(64,5), 256, 0, stream>>>(sci1, off1, c1w, 5, 24000, 40, S1);
  k_sgather<<<dim3(64,8), 256, 0, stream>>>(sci2, off2, c2w, 65, 23984, 520, S2);
  k_y1  <<<dim3(64,32), 128, 0, stream>>>(S1, emb1, c1b, ysum);
  k_y2  <<<dim3(64,32), 128, 0, stream>>>(S2, emb2, c2b, ysum);
  k_fcxr<<<dim3(64,4), 256, 0, stream>>>(ysum, fcxw, fcxb, out);
}

// Round 11
// 632.378 us; speedup vs baseline: 1.7888x; 1.0454x over previous
//
#include <hip/hip_runtime.h>

#define N_NODES 50000
#define N_EDGES 800000
#define LRELU_SLOPE 0.2f
#define BN_EPS 1e-5f

typedef unsigned int u32;

__device__ __forceinline__ float lrelu(float x){ return fmaxf(x,0.f) + LRELU_SLOPE*fminf(x,0.f); }
__device__ __forceinline__ float bflo(u32 u){ return __uint_as_float(u<<16); }
__device__ __forceinline__ float bfhi(u32 u){ return __uint_as_float(u & 0xffff0000u); }
__device__ __forceinline__ u32 packbf(float a, float b){
  u32 ua = __float_as_uint(a); ua = (ua + 0x7fffu + ((ua>>16)&1u)) >> 16;
  u32 ub = __float_as_uint(b); ub = (ub + 0x7fffu + ((ub>>16)&1u)) >> 16;
  return ua | (ub<<16);
}

// ---------------- CSR build ----------------
// cnt/fill/deg zeroed by hipMemsetAsync in kernel_launch.
__global__ __launch_bounds__(256) void k_hist(const int* __restrict__ eidx, const float* __restrict__ pw,
                                              int* __restrict__ cnt, float* __restrict__ deg){
  int e = blockIdx.x*256 + threadIdx.x;
  if(e < N_EDGES){
    int d = eidx[N_EDGES + e];
    atomicAdd(&cnt[d], 1);
    unsafeAtomicAdd(&deg[d], pw[e]);
  }
}

// 3-phase parallel exclusive scan of cnt -> rowptr
__global__ __launch_bounds__(256) void k_scan1(const int* __restrict__ cnt, int* __restrict__ rowptr,
                                               int* __restrict__ bsum){
  __shared__ int sc[256];
  int b = blockIdx.x, t = threadIdx.x;
  int i = b*256 + t;
  int v = (i < N_NODES) ? cnt[i] : 0;
  sc[t] = v;
  __syncthreads();
  for(int off=1; off<256; off<<=1){
    int x = (t>=off)? sc[t-off] : 0;
    __syncthreads();
    sc[t] += x;
    __syncthreads();
  }
  if(i < N_NODES) rowptr[i] = sc[t] - v;   // exclusive within block
  if(t == 255) bsum[b] = sc[255];
}

__global__ __launch_bounds__(256) void k_scan2(const int* __restrict__ bsum, int* __restrict__ bbase,
                                               int* __restrict__ rowptr, int* __restrict__ gstart,
                                               int* __restrict__ gend){
  __shared__ int sc[256];
  int t = threadIdx.x;
  int v = (t < 196) ? bsum[t] : 0;
  sc[t] = v;
  __syncthreads();
  for(int off=1; off<256; off<<=1){
    int x = (t>=off)? sc[t-off] : 0;
    __syncthreads();
    sc[t] += x;
    __syncthreads();
  }
  if(t < 196) bbase[t] = sc[t] - v;
  if(t == 255) rowptr[N_NODES] = sc[255];
  if(t < 64){ gstart[t] = N_NODES; gend[t] = 0; }
}

__global__ __launch_bounds__(256) void k_scan3(int* __restrict__ rowptr, const int* __restrict__ bbase){
  int b = blockIdx.x, t = threadIdx.x;
  int i = b*256 + t;
  if(i < N_NODES) rowptr[i] += bbase[b];
}

// paired (src, w) 8-byte scatter: halves scattered-line touches vs two 4B arrays
__global__ __launch_bounds__(256) void k_scatter(const int* __restrict__ eidx, const float* __restrict__ pw,
                                                 const int* __restrict__ rowptr, int* __restrict__ fill,
                                                 uint2* __restrict__ s_srcw){
  int e = blockIdx.x*256 + threadIdx.x;
  if(e < N_EDGES){
    int d = eidx[N_EDGES + e];
    int pos = rowptr[d] + atomicAdd(&fill[d], 1);
    uint2 pr; pr.x = (u32)eidx[e]; pr.y = __float_as_uint(pw[e]);
    s_srcw[pos] = pr;
  }
}

// ---------------- GCN ----------------
__global__ __launch_bounds__(256) void k_enorm(const uint2* __restrict__ s_srcw, const float* __restrict__ deg,
                                               float* __restrict__ g_e){
  int j = blockIdx.x*256 + threadIdx.x;
  if(j < N_EDGES){
    uint2 pr = s_srcw[j];
    float w = __uint_as_float(pr.y);
    g_e[j] = rsqrtf(deg[pr.x] + 1.f) * w;
  }
}

// h = pro_x @ gcn_w.T, packed bf16 pairs: 17 dwords/node
__global__ __launch_bounds__(256) void k_h(const float* __restrict__ px, const float* __restrict__ gw,
                                           u32* __restrict__ hb){
  int n = blockIdx.x*256 + threadIdx.x;
  if(n >= N_NODES) return;
  float x[33];
  #pragma unroll
  for(int k=0;k<33;k++) x[k] = px[n*33+k];
  float a[33];
  for(int c=0;c<33;c++){
    float s = 0.f;
    #pragma unroll
    for(int k=0;k<33;k++) s = fmaf(x[k], gw[c*33+k], s);
    a[c] = s;
  }
  #pragma unroll
  for(int d=0;d<16;d++) hb[(size_t)n*17 + d] = packbf(a[2*d], a[2*d+1]);
  hb[(size_t)n*17 + 16] = packbf(a[32], 0.f);
}

// wave per node, 4 groups x 16 lanes, 4 edges/iter; bf16 h gather; fused bias+relu+BN.
__global__ __launch_bounds__(256) void k_gcn(const u32* __restrict__ hb, const int* __restrict__ rowptr,
                                             const uint2* __restrict__ s_srcw, const float* __restrict__ g_e,
                                             const float* __restrict__ deg,
                                             const float* __restrict__ gcnb, const float* __restrict__ bnm,
                                             const float* __restrict__ bnv, const float* __restrict__ bnw,
                                             const float* __restrict__ bnb, float* __restrict__ xp1){
  int wave = threadIdx.x >> 6;
  int lane = threadIdx.x & 63;
  int n = blockIdx.x*4 + wave;
  if(n >= N_NODES) return;
  int l = lane & 15, g = lane >> 4;
  bool t0 = (l == 0);
  float dn = rsqrtf(deg[n] + 1.f);
  const u32* srow = hb + (size_t)n*17;
  u32 us  = srow[l];
  u32 ust = t0 ? srow[16] : 0u;
  float acc0, acc1, acct;
  if(g == 0){ acc0 = dn*bflo(us); acc1 = dn*bfhi(us); acct = dn*bflo(ust); }
  else      { acc0 = 0.f; acc1 = 0.f; acct = 0.f; }
  int rb = rowptr[n], re = rowptr[n+1];
  int j = rb;
  for(; j+4 <= re; j += 4){
    int e = j + g;
    float ge = g_e[e];
    int s = (int)s_srcw[e].x;
    const u32* r = hb + (size_t)s*17;
    u32 u  = r[l];
    u32 ut = t0 ? r[16] : 0u;
    acc0 = fmaf(ge, bflo(u),  acc0);
    acc1 = fmaf(ge, bfhi(u),  acc1);
    acct = fmaf(ge, bflo(ut), acct);
  }
  int rem = re - j;
  if(rem > 0){
    bool val = (g < rem);
    int e = val ? (j + g) : j;
    float ge = val ? g_e[e] : 0.f;
    int s = (int)s_srcw[e].x;
    const u32* r = hb + (size_t)s*17;
    u32 u  = r[l];
    u32 ut = t0 ? r[16] : 0u;
    acc0 = fmaf(ge, bflo(u),  acc0);
    acc1 = fmaf(ge, bfhi(u),  acc1);
    acct = fmaf(ge, bflo(ut), acct);
  }
  #pragma unroll
  for(int m=16;m<=32;m<<=1){
    acc0 += __shfl_xor(acc0, m, 64);
    acc1 += __shfl_xor(acc1, m, 64);
    acct += __shfl_xor(acct, m, 64);
  }
  if(g == 0){
    int c0 = 2*l, c1 = 2*l+1;
    float v0 = fmaxf(dn*acc0 + gcnb[c0], 0.f);
    float v1 = fmaxf(dn*acc1 + gcnb[c1], 0.f);
    float i0 = bnw[c0] / sqrtf(bnv[c0] + BN_EPS);
    float i1 = bnw[c1] / sqrtf(bnv[c1] + BN_EPS);
    float2 o;
    o.x = v0*i0 + (bnb[c0] - bnm[c0]*i0);
    o.y = v1*i1 + (bnb[c1] - bnm[c1]*i1);
    ((float2*)(xp1 + (size_t)n*36))[l] = o;
    if(t0){
      float vt = fmaxf(dn*acct + gcnb[32], 0.f);
      float it = bnw[32] / sqrtf(bnv[32] + BN_EPS);
      float2 ot; ot.x = vt*it + (bnb[32] - bnm[32]*it); ot.y = 0.f;
      ((float2*)(xp1 + (size_t)n*36))[16] = ot;
      float2 z; z.x = 0.f; z.y = 0.f;
      ((float2*)(xp1 + (size_t)n*36))[17] = z;
    }
  }
}

// ---------------- GATv2 ----------------
__global__ __launch_bounds__(256) void k_gatlin(const float* __restrict__ xp1, const float* __restrict__ wl,
                                                const float* __restrict__ wr, u32* __restrict__ xlb,
                                                float* __restrict__ xr){
  __shared__ float sx[64*36];
  __shared__ float swl[132*33];
  __shared__ float swr[132*33];
  int t = threadIdx.x;
  int n0 = blockIdx.x*64;
  int nn = N_NODES - n0; if(nn > 64) nn = 64;
  for(int i=t;i<4356;i+=256){ swl[i] = wl[i]; swr[i] = wr[i]; }
  int xcnt = nn*36;
  for(int i=t;i<xcnt;i+=256) sx[i] = xp1[(size_t)n0*36 + i];
  __syncthreads();
  int total = nn*66;
  for(int p=t; p<total; p+=256){
    int n = p/66, d = p - n*66;
    int j0 = 2*d;
    const float* xv  = sx + n*36;
    const float* wl0 = swl + j0*33;
    const float* wl1 = wl0 + 33;
    const float* wr0 = swr + j0*33;
    const float* wr1 = wr0 + 33;
    float al0=0.f, al1=0.f, ar0=0.f, ar1=0.f;
    #pragma unroll
    for(int k=0;k<33;k++){
      float x = xv[k];
      al0 = fmaf(x, wl0[k], al0);
      al1 = fmaf(x, wl1[k], al1);
      ar0 = fmaf(x, wr0[k], ar0);
      ar1 = fmaf(x, wr1[k], ar1);
    }
    size_t nidx = (size_t)(n0 + n);
    int head = (d >= 33) ? 1 : 0;
    int dd = d - 33*head;
    xlb[nidx*68 + head*34 + dd] = packbf(al0, al1);
    float2 xv2; xv2.x = ar0; xv2.y = ar1;
    ((float2*)xr)[nidx*66 + d] = xv2;
  }
}

// block/node, 2 head-waves; wave = 4 x 16-lane groups; 2x unrolled -> 8 edges in flight.
__global__ __launch_bounds__(128) void k_gat(const int* __restrict__ rowptr, const u32* __restrict__ srcx,
                                             const u32* __restrict__ xlb, const float* __restrict__ xr,
                                             const float* __restrict__ att, const float* __restrict__ gatb,
                                             float* __restrict__ xp2){
  int n = blockIdx.x;
  int h = threadIdx.x >> 6;
  int lane = threadIdx.x & 63;
  int l = lane & 15, g = lane >> 4;
  int base = h*66, dbase = h*34;
  bool t0 = (l == 0);
  size_t nrow = (size_t)n*132;
  const float2* xr2 = (const float2*)(xr + nrow + base);
  float2 xra = xr2[2*l], xrb = xr2[2*l+1];
  float2 xrt = t0 ? xr2[32] : make_float2(0.f,0.f);
  const float2* att2 = (const float2*)(att + base);
  float2 ata = att2[2*l], atb = att2[2*l+1];
  float2 att_t = att2[32];
  const u32* srow = xlb + (size_t)n*68 + dbase;
  uint2 su = ((const uint2*)srow)[l];
  u32 ust = t0 ? srow[32] : 0u;
  float s0 = bflo(su.x), s1 = bfhi(su.x), s2 = bflo(su.y), s3 = bfhi(su.y);
  float st0 = bflo(ust), st1 = bfhi(ust);
  float p = lrelu(s0+xra.x)*ata.x + lrelu(s1+xra.y)*ata.y
          + lrelu(s2+xrb.x)*atb.x + lrelu(s3+xrb.y)*atb.y
          + lrelu(st0+xrt.x)*att_t.x + lrelu(st1+xrt.y)*att_t.y;
  #pragma unroll
  for(int m=1;m<=8;m<<=1) p += __shfl_xor(p, m, 64);
  float e_self = p;
  float a0_, a1_, a2_, a3_, at0, at1, asum;
  if(g == 0){ a0_=s0; a1_=s1; a2_=s2; a3_=s3; at0=st0; at1=st1; asum=1.f; }
  else      { a0_=0.f; a1_=0.f; a2_=0.f; a3_=0.f; at0=0.f; at1=0.f; asum=0.f; }
  int rb = rowptr[n], re = rowptr[n+1];
  int j = rb;
  for(; j+8 <= re; j += 8){
    int sA = (int)srcx[2*(j + g)];
    int sB = (int)srcx[2*(j + 4 + g)];
    const u32* rA = xlb + (size_t)sA*68 + dbase;
    const u32* rB = xlb + (size_t)sB*68 + dbase;
    uint2 uA = ((const uint2*)rA)[l];
    uint2 uB = ((const uint2*)rB)[l];
    u32 utA = t0 ? rA[32] : 0u;
    u32 utB = t0 ? rB[32] : 0u;
    float vA0=bflo(uA.x), vA1=bfhi(uA.x), vA2=bflo(uA.y), vA3=bfhi(uA.y);
    float vB0=bflo(uB.x), vB1=bfhi(uB.x), vB2=bflo(uB.y), vB3=bfhi(uB.y);
    float wA0=bflo(utA), wA1=bfhi(utA);
    float wB0=bflo(utB), wB1=bfhi(utB);
    float pA = lrelu(vA0+xra.x)*ata.x + lrelu(vA1+xra.y)*ata.y
             + lrelu(vA2+xrb.x)*atb.x + lrelu(vA3+xrb.y)*atb.y
             + lrelu(wA0+xrt.x)*att_t.x + lrelu(wA1+xrt.y)*att_t.y;
    float pB = lrelu(vB0+xra.x)*ata.x + lrelu(vB1+xra.y)*ata.y
             + lrelu(vB2+xrb.x)*atb.x + lrelu(vB3+xrb.y)*atb.y
             + lrelu(wB0+xrt.x)*att_t.x + lrelu(wB1+xrt.y)*att_t.y;
    #pragma unroll
    for(int m=1;m<=8;m<<=1){
      pA += __shfl_xor(pA, m, 64);
      pB += __shfl_xor(pB, m, 64);
    }
    float aA = __expf(pA - e_self);
    float aB = __expf(pB - e_self);
    a0_ = fmaf(aA, vA0, fmaf(aB, vB0, a0_));
    a1_ = fmaf(aA, vA1, fmaf(aB, vB1, a1_));
    a2_ = fmaf(aA, vA2, fmaf(aB, vB2, a2_));
    a3_ = fmaf(aA, vA3, fmaf(aB, vB3, a3_));
    at0 = fmaf(aA, wA0, fmaf(aB, wB0, at0));
    at1 = fmaf(aA, wA1, fmaf(aB, wB1, at1));
    asum += aA + aB;
  }
  if(j+4 <= re){
    int s = (int)srcx[2*(j + g)];
    const u32* r = xlb + (size_t)s*68 + dbase;
    uint2 uu = ((const uint2*)r)[l];
    u32 ut = t0 ? r[32] : 0u;
    float v0=bflo(uu.x), v1=bfhi(uu.x), v2=bflo(uu.y), v3=bfhi(uu.y);
    float w0=bflo(ut), w1=bfhi(ut);
    float pp = lrelu(v0+xra.x)*ata.x + lrelu(v1+xra.y)*ata.y
             + lrelu(v2+xrb.x)*atb.x + lrelu(v3+xrb.y)*atb.y
             + lrelu(w0+xrt.x)*att_t.x + lrelu(w1+xrt.y)*att_t.y;
    #pragma unroll
    for(int m=1;m<=8;m<<=1) pp += __shfl_xor(pp, m, 64);
    float a = __expf(pp - e_self);
    a0_ = fmaf(a, v0, a0_); a1_ = fmaf(a, v1, a1_);
    a2_ = fmaf(a, v2, a2_); a3_ = fmaf(a, v3, a3_);
    at0 = fmaf(a, w0, at0); at1 = fmaf(a, w1, at1);
    asum += a;
    j += 4;
  }
  int rem = re - j;
  if(rem > 0){
    bool val = (g < rem);
    int s = val ? (int)srcx[2*(j + g)] : n;
    const u32* r = xlb + (size_t)s*68 + dbase;
    uint2 uu = ((const uint2*)r)[l];
    u32 ut = t0 ? r[32] : 0u;
    float v0=bflo(uu.x), v1=bfhi(uu.x), v2=bflo(uu.y), v3=bfhi(uu.y);
    float w0=bflo(ut), w1=bfhi(ut);
    float pp = lrelu(v0+xra.x)*ata.x + lrelu(v1+xra.y)*ata.y
             + lrelu(v2+xrb.x)*atb.x + lrelu(v3+xrb.y)*atb.y
             + lrelu(w0+xrt.x)*att_t.x + lrelu(w1+xrt.y)*att_t.y;
    #pragma unroll
    for(int m=1;m<=8;m<<=1) pp += __shfl_xor(pp, m, 64);
    float a = val ? __expf(pp - e_self) : 0.f;
    a0_ = fmaf(a, v0, a0_); a1_ = fmaf(a, v1, a1_);
    a2_ = fmaf(a, v2, a2_); a3_ = fmaf(a, v3, a3_);
    at0 = fmaf(a, w0, at0); at1 = fmaf(a, w1, at1);
    asum += a;
  }
  #pragma unroll
  for(int m=16;m<=32;m<<=1){
    a0_ += __shfl_xor(a0_, m, 64);
    a1_ += __shfl_xor(a1_, m, 64);
    a2_ += __shfl_xor(a2_, m, 64);
    a3_ += __shfl_xor(a3_, m, 64);
    at0 += __shfl_xor(at0, m, 64);
    at1 += __shfl_xor(at1, m, 64);
    asum += __shfl_xor(asum, m, 64);
  }
  float inv = 1.f/asum;
  if(g == 0){
    const float2* gb2 = (const float2*)(gatb + base);
    float2 ga = gb2[2*l], gb = gb2[2*l+1];
    float2* o2 = (float2*)(xp2 + nrow + base);
    float2 oa, ob;
    oa.x = fmaxf(a0_*inv + ga.x, 0.f); oa.y = fmaxf(a1_*inv + ga.y, 0.f);
    ob.x = fmaxf(a2_*inv + gb.x, 0.f); ob.y = fmaxf(a3_*inv + gb.y, 0.f);
    o2[2*l] = oa; o2[2*l+1] = ob;
    if(t0){
      float2 gt = gb2[32];
      float2 ot;
      ot.x = fmaxf(at0*inv + gt.x, 0.f); ot.y = fmaxf(at1*inv + gt.y, 0.f);
      o2[32] = ot;
    }
  }
}

// ---------------- pooling + MLP head ----------------
__global__ __launch_bounds__(256) void k_bounds(const int* __restrict__ batch, int* __restrict__ gstart,
                                                int* __restrict__ gend){
  int n = blockIdx.x*256 + threadIdx.x;
  if(n >= N_NODES) return;
  int b = batch[n];
  if(n == 0) gstart[b] = 0;
  else {
    int p = batch[n-1];
    if(p != b){ gstart[b] = n; gend[p] = n; }
  }
  if(n == N_NODES-1) gend[b] = N_NODES;
}

__global__ __launch_bounds__(128) void k_poolp(const float* __restrict__ xp2, const int* __restrict__ gstart,
                                               const int* __restrict__ gend, float* __restrict__ pp){
  int g = blockIdx.x, seg = blockIdx.y, t = threadIdx.x;
  int s = gstart[g], e = gend[g];
  int len = e - s; if(len < 0) len = 0;
  int ns = s + (int)(((long long)len*seg)>>4);
  int ne = s + (int)(((long long)len*(seg+1))>>4);
  float a0 = 0.f, a1 = 0.f;
  for(int n=ns;n<ne;n++){
    a0 += xp2[(size_t)n*132 + t];
    if(t < 4) a1 += xp2[(size_t)n*132 + 128 + t];
  }
  float* o = pp + (size_t)(g*16 + seg)*132;
  o[t] = a0;
  if(t < 4) o[128 + t] = a1;
}

// fused poolr + fc1: block per graph; pooled vector in LDS, then 1024-dim fc.
__global__ __launch_bounds__(256) void k_pfc1(const float* __restrict__ pp, const int* __restrict__ gstart,
                                              const int* __restrict__ gend, const float* __restrict__ w,
                                              const float* __restrict__ b, float* __restrict__ h1T){
  __shared__ float pooled[132];
  int g = blockIdx.x, t = threadIdx.x;
  if(t < 132){
    float s = 0.f;
    #pragma unroll
    for(int k=0;k<16;k++) s += pp[(size_t)(g*16 + k)*132 + t];
    int c = gend[g] - gstart[g]; if(c < 1) c = 1;
    pooled[t] = s/(float)c;
  }
  __syncthreads();
  #pragma unroll
  for(int r=0;r<4;r++){
    int o = r*256 + t;
    const float* wr = w + o*132;
    float acc = b[o];
    for(int k=0;k<132;k++) acc = fmaf(pooled[k], wr[k], acc);
    h1T[o*64+g] = fmaxf(acc, 0.f);
  }
}

// block per output o (128 blocks); 256 threads = 4 k-slices x 64 graphs; LDS reduce.
__global__ __launch_bounds__(256) void k_fc2(const float* __restrict__ h1T, const float* __restrict__ w,
                                             const float* __restrict__ b, float* __restrict__ out){
  __shared__ float part[256];
  int o = blockIdx.x, t = threadIdx.x;
  int s = t >> 6, g = t & 63;
  const float* wr = w + o*1024 + s*256;
  const float* hp = h1T + (size_t)(s*256)*64 + g;
  float acc = 0.f;
  for(int k=0;k<256;k++) acc = fmaf(hp[k*64], wr[k], acc);
  part[t] = acc;
  __syncthreads();
  if(s == 0){
    float r = b[o] + part[g] + part[64+g] + part[128+g] + part[192+g];
    out[8192 + g*128 + o] = r;
  }
}

// ---------------- RNA branches ----------------
__global__ __launch_bounds__(256) void k_bucket(const int* __restrict__ g, int L, int V,
                                                int* __restrict__ sci, int* __restrict__ off){
  __shared__ int gl[3000];
  __shared__ int hist[65];
  __shared__ int base[66];
  int b = blockIdx.x, t = threadIdx.x;
  if(t < V) hist[t] = 0;
  for(int i=t;i<L;i+=256) gl[i] = g[b*L + i];
  __syncthreads();
  for(int i=t;i<L;i+=256) atomicAdd(&hist[gl[i]], 1);
  __syncthreads();
  if(t == 0){
    int run = 0;
    for(int v=0;v<V;v++){ base[v] = run; run += hist[v]; }
    base[V] = run;
  }
  __syncthreads();
  if(t <= V) off[b*(V+1) + t] = base[t];
  if(t < V) hist[t] = 0;
  __syncthreads();
  for(int i=t;i<L;i+=256){
    int v = gl[i];
    int p = base[v] + atomicAdd(&hist[v], 1);
    sci[b*3000 + p] = i*8;
  }
}

__global__ __launch_bounds__(256) void k_sgather(const int* __restrict__ sci, const int* __restrict__ off,
                                                 const float* __restrict__ w, int V, int wstride,
                                                 int sstride, float* __restrict__ S){
  __shared__ int loff[66];
  __shared__ int lci[3000];
  int b = blockIdx.x, q = blockIdx.y, t = threadIdx.x;
  int nsplit = gridDim.y;
  if(t <= V) loff[t] = off[b*(V+1) + t];
  __syncthreads();
  int vs = (V*q)/nsplit, ve = (V*(q+1))/nsplit;
  int p0 = loff[vs], p1 = loff[ve];
  for(int i=p0+t;i<p1;i+=256) lci[i-p0] = sci[b*3000 + i];
  __syncthreads();
  int co = t >> 3, kk = t & 7;
  const float* wrow = w + co*wstride + kk;
  float* Srow = S + (size_t)b*32*sstride + co*sstride + kk;
  for(int v=vs;v<ve;v++){
    int j = loff[v] - p0, je = loff[v+1] - p0;
    float a0=0.f,a1=0.f,a2=0.f,a3=0.f,a4=0.f,a5=0.f,a6=0.f,a7=0.f;
    for(; j+8 <= je; j += 8){
      a0 += wrow[lci[j]];
      a1 += wrow[lci[j+1]];
      a2 += wrow[lci[j+2]];
      a3 += wrow[lci[j+3]];
      a4 += wrow[lci[j+4]];
      a5 += wrow[lci[j+5]];
      a6 += wrow[lci[j+6]];
      a7 += wrow[lci[j+7]];
    }
    for(; j<je; j++) a0 += wrow[lci[j]];
    Srow[v*8] = ((a0+a1)+(a2+a3)) + ((a4+a5)+(a6+a7));
  }
}

// fused y1+y2: ysum[b][co*121+l] = 0.5*(conv1+b1) + 0.5*(conv2+b2)
__global__ __launch_bounds__(128) void k_y(const float* __restrict__ S1, const float* __restrict__ S2,
                                           const float* __restrict__ emb1, const float* __restrict__ emb2,
                                           const float* __restrict__ c1b, const float* __restrict__ c2b,
                                           float* __restrict__ ysum){
  int b = blockIdx.x, co = blockIdx.y, t = threadIdx.x;
  __shared__ float em1[640];
  __shared__ float em2[8320];
  for(int i=t;i<640;i+=128) em1[i] = emb1[i];
  for(int i=t;i<8320;i+=128) em2[i] = emb2[i];
  __syncthreads();
  if(t < 121){
    const float* Sa = S1 + b*1280 + co*40;
    float acc1 = c1b[co];
    #pragma unroll
    for(int v=0;v<5;v++)
      #pragma unroll
      for(int k=0;k<8;k++) acc1 = fmaf(Sa[v*8+k], em1[v*128 + t + k], acc1);
    const float* Sb = S2 + (size_t)b*16640 + co*520;
    float acc2 = c2b[co];
    for(int v=0;v<65;v++){
      #pragma unroll
      for(int k=0;k<8;k++) acc2 = fmaf(Sb[v*8+k], em2[v*128 + t + k], acc2);
    }
    ysum[b*3872 + co*121 + t] = 0.5f*(acc1 + acc2);
  }
}

__global__ __launch_bounds__(256) void k_fcxr(const float* __restrict__ ysum, const float* __restrict__ fcw,
                                              const float* __restrict__ fcb, float* __restrict__ out){
  __shared__ float part[256];
  int b = blockIdx.x, q = blockIdx.y, t = threadIdx.x;
  int ol = t >> 3;
  int o  = q*32 + ol;
  int slice = t & 7;
  const float4* ys = (const float4*)(ysum + b*3872) + slice*121;
  const float4* wr = (const float4*)(fcw + (size_t)o*3872) + slice*121;
  float acc = 0.f;
  for(int k=0;k<121;k++){
    float4 y = ys[k], w4 = wr[k];
    acc += y.x*w4.x + y.y*w4.y + y.z*w4.z + y.w*w4.w;
  }
  part[t] = acc;
  __syncthreads();
  if(slice == 0){
    float s = fcb[o];
    #pragma unroll
    for(int i=0;i<8;i++) s += part[ol*8 + i];
    out[b*128 + o] = s;
  }
}

extern "C" void kernel_launch(void* const* d_in, const int* in_sizes, int n_in,
                              void* d_out, int out_size, void* d_ws, size_t ws_size,
                              hipStream_t stream){
  const int*   g_rna = (const int*)  d_in[0];
  const int*   l_rna = (const int*)  d_in[1];
  const float* pro_x = (const float*)d_in[2];
  const int*   eidx  = (const int*)  d_in[3];
  const float* pro_w = (const float*)d_in[4];
  const int*   batch = (const int*)  d_in[5];
  const float* emb1  = (const float*)d_in[6];
  const float* emb2  = (const float*)d_in[7];
  const float* c1w   = (const float*)d_in[8];
  const float* c1b   = (const float*)d_in[9];
  const float* c2w   = (const float*)d_in[10];
  const float* c2b   = (const float*)d_in[11];
  const float* fcxw  = (const float*)d_in[12];
  const float* fcxb  = (const float*)d_in[13];
  const float* gcnw  = (const float*)d_in[14];
  const float* gcnb  = (const float*)d_in[15];
  const float* bnm   = (const float*)d_in[16];
  const float* bnv   = (const float*)d_in[17];
  const float* bnw   = (const float*)d_in[18];
  const float* bnb   = (const float*)d_in[19];
  const float* gwl   = (const float*)d_in[20];
  const float* gwr   = (const float*)d_in[21];
  const float* gatt  = (const float*)d_in[22];
  const float* gatb  = (const float*)d_in[23];
  const float* f1w   = (const float*)d_in[24];
  const float* f1b   = (const float*)d_in[25];
  const float* f2w   = (const float*)d_in[26];
  const float* f2b_  = (const float*)d_in[27];
  float* out = (float*)d_out;

  char* ws = (char*)d_ws;
  size_t off = 0;
  auto A = [&](size_t n)->char*{ char* p = ws + off; off = (off + n + 255) & ~(size_t)255; return p; };
  // cnt, fill, deg contiguous -> single memset
  int*   cnt    = (int*)  A((size_t)N_NODES*4);
  int*   fill   = (int*)  A((size_t)N_NODES*4);
  float* deg    = (float*)A((size_t)N_NODES*4);
  size_t zero_bytes = off;  // covers cnt+fill+deg (incl. padding)
  int*   rowptr = (int*)  A((size_t)(N_NODES+1)*4);
  int*   bsum   = (int*)  A(196*4);
  int*   bbase  = (int*)  A(196*4);
  uint2* s_srcw = (uint2*)A((size_t)N_EDGES*8);
  float* g_e    = (float*)A((size_t)N_EDGES*4);
  u32*   hb     = (u32*)  A((size_t)N_NODES*17*4);
  float* xp1    = (float*)A((size_t)N_NODES*36*4);
  u32*   xlb    = (u32*)  A((size_t)N_NODES*68*4);
  float* xr     = (float*)A((size_t)N_NODES*132*4);
  float* xp2    = (float*)A((size_t)N_NODES*132*4);
  int*   gstart = (int*)  A(64*4);
  int*   gend   = (int*)  A(64*4);
  float* pp     = (float*)A((size_t)64*16*132*4);
  float* h1T    = (float*)A(1024*64*4);
  float* S1     = (float*)A((size_t)64*1280*4);
  float* S2     = (float*)A((size_t)64*16640*4);
  float* ysum   = (float*)A((size_t)64*3872*4);
  int*   sci1   = (int*)  A((size_t)64*3000*4);
  int*   off1   = (int*)  A((size_t)64*8*4);
  int*   sci2   = (int*)  A((size_t)64*3000*4);
  int*   off2   = (int*)  A((size_t)64*66*4);
  (void)ws_size; (void)in_sizes; (void)n_in; (void)out_size;

  hipMemsetAsync(ws, 0, zero_bytes, stream);

  // protein GNN pipeline
  k_hist   <<<3125, 256, 0, stream>>>(eidx, pro_w, cnt, deg);
  k_scan1  <<<196, 256, 0, stream>>>(cnt, rowptr, bsum);
  k_scan2  <<<1, 256, 0, stream>>>(bsum, bbase, rowptr, gstart, gend);
  k_scan3  <<<196, 256, 0, stream>>>(rowptr, bbase);
  k_scatter<<<3125, 256, 0, stream>>>(eidx, pro_w, rowptr, fill, s_srcw);
  k_enorm  <<<3125, 256, 0, stream>>>(s_srcw, deg, g_e);
  k_h      <<<196, 256, 0, stream>>>(pro_x, gcnw, hb);
  k_gcn    <<<12500, 256, 0, stream>>>(hb, rowptr, s_srcw, g_e, deg, gcnb, bnm, bnv, bnw, bnb, xp1);
  k_gatlin <<<782, 256, 0, stream>>>(xp1, gwl, gwr, xlb, xr);
  k_gat    <<<N_NODES, 128, 0, stream>>>(rowptr, (const u32*)s_srcw, xlb, xr, gatt, gatb, xp2);
  k_bounds <<<196, 256, 0, stream>>>(batch, gstart, gend);
  k_poolp  <<<dim3(64,16), 128, 0, stream>>>(xp2, gstart, gend, pp);
  k_pfc1   <<<64, 256, 0, stream>>>(pp, gstart, gend, f1w, f1b, h1T);
  k_fc2    <<<128, 256, 0, stream>>>(h1T, f2w, f2b_, out);

  // RNA branches
  k_bucket <<<64, 256, 0, stream>>>(g_rna, 3000, 5, sci1, off1);
  k_bucket <<<64, 256, 0, stream>>>(l_rna, 2998, 65, sci2, off2);
  k_sgather<<<dim3(64,5), 256, 0, stream>>>(sci1, off1, c1w, 5, 24000, 40, S1);
  k_sgather<<<dim3(64,8), 256, 0, stream>>>(sci2, off2, c2w, 65, 23984, 520, S2);
  k_y      <<<dim3(64,32), 128, 0, stream>>>(S1, S2, emb1, emb2, c1b, c2b, ysum);
  k_fcxr   <<<dim3(64,4), 256, 0, stream>>>(ysum, fcxw, fcxb, out);
}

// Round 13
// 618.577 us; speedup vs baseline: 1.8287x; 1.0223x over previous
//
#include <hip/hip_runtime.h>

#define N_NODES 50000
#define N_EDGES 800000
#define LRELU_SLOPE 0.2f
#define BN_EPS 1e-5f

typedef unsigned int u32;

__device__ __forceinline__ float lrelu(float x){ return fmaxf(x,0.f) + LRELU_SLOPE*fminf(x,0.f); }
__device__ __forceinline__ float bflo(u32 u){ return __uint_as_float(u<<16); }
__device__ __forceinline__ float bfhi(u32 u){ return __uint_as_float(u & 0xffff0000u); }
__device__ __forceinline__ u32 packbf(float a, float b){
  u32 ua = __float_as_uint(a); ua = (ua + 0x7fffu + ((ua>>16)&1u)) >> 16;
  u32 ub = __float_as_uint(b); ub = (ub + 0x7fffu + ((ub>>16)&1u)) >> 16;
  return ua | (ub<<16);
}

// ---------------- CSR build ----------------
// cnt/fill/deg zeroed by hipMemsetAsync in kernel_launch.
__global__ __launch_bounds__(256) void k_hist(const int* __restrict__ eidx, const float* __restrict__ pw,
                                              int* __restrict__ cnt, float* __restrict__ deg){
  int e = blockIdx.x*256 + threadIdx.x;
  if(e < N_EDGES){
    int d = eidx[N_EDGES + e];
    atomicAdd(&cnt[d], 1);
    unsafeAtomicAdd(&deg[d], pw[e]);
  }
}

// 3-phase parallel exclusive scan of cnt -> rowptr
__global__ __launch_bounds__(256) void k_scan1(const int* __restrict__ cnt, int* __restrict__ rowptr,
                                               int* __restrict__ bsum){
  __shared__ int sc[256];
  int b = blockIdx.x, t = threadIdx.x;
  int i = b*256 + t;
  int v = (i < N_NODES) ? cnt[i] : 0;
  sc[t] = v;
  __syncthreads();
  for(int off=1; off<256; off<<=1){
    int x = (t>=off)? sc[t-off] : 0;
    __syncthreads();
    sc[t] += x;
    __syncthreads();
  }
  if(i < N_NODES) rowptr[i] = sc[t] - v;   // exclusive within block
  if(t == 255) bsum[b] = sc[255];
}

__global__ __launch_bounds__(256) void k_scan2(const int* __restrict__ bsum, int* __restrict__ bbase,
                                               int* __restrict__ rowptr, int* __restrict__ gstart,
                                               int* __restrict__ gend){
  __shared__ int sc[256];
  int t = threadIdx.x;
  int v = (t < 196) ? bsum[t] : 0;
  sc[t] = v;
  __syncthreads();
  for(int off=1; off<256; off<<=1){
    int x = (t>=off)? sc[t-off] : 0;
    __syncthreads();
    sc[t] += x;
    __syncthreads();
  }
  if(t < 196) bbase[t] = sc[t] - v;
  if(t == 255) rowptr[N_NODES] = sc[255];
  if(t < 64){ gstart[t] = N_NODES; gend[t] = 0; }
}

__global__ __launch_bounds__(256) void k_scan3(int* __restrict__ rowptr, const int* __restrict__ bbase){
  int b = blockIdx.x, t = threadIdx.x;
  int i = b*256 + t;
  if(i < N_NODES) rowptr[i] += bbase[b];
}

// paired (src, w) 8-byte scatter
__global__ __launch_bounds__(256) void k_scatter(const int* __restrict__ eidx, const float* __restrict__ pw,
                                                 const int* __restrict__ rowptr, int* __restrict__ fill,
                                                 uint2* __restrict__ s_srcw){
  int e = blockIdx.x*256 + threadIdx.x;
  if(e < N_EDGES){
    int d = eidx[N_EDGES + e];
    int pos = rowptr[d] + atomicAdd(&fill[d], 1);
    uint2 pr; pr.x = (u32)eidx[e]; pr.y = __float_as_uint(pw[e]);
    s_srcw[pos] = pr;
  }
}

// ---------------- GCN ----------------
__global__ __launch_bounds__(256) void k_enorm(const uint2* __restrict__ s_srcw, const float* __restrict__ deg,
                                               float* __restrict__ g_e){
  int j = blockIdx.x*256 + threadIdx.x;
  if(j < N_EDGES){
    uint2 pr = s_srcw[j];
    float w = __uint_as_float(pr.y);
    g_e[j] = rsqrtf(deg[pr.x] + 1.f) * w;
  }
}

// h = pro_x @ gcn_w.T, packed bf16 pairs: 17 dwords/node
__global__ __launch_bounds__(256) void k_h(const float* __restrict__ px, const float* __restrict__ gw,
                                           u32* __restrict__ hb){
  int n = blockIdx.x*256 + threadIdx.x;
  if(n >= N_NODES) return;
  float x[33];
  #pragma unroll
  for(int k=0;k<33;k++) x[k] = px[n*33+k];
  float a[33];
  for(int c=0;c<33;c++){
    float s = 0.f;
    #pragma unroll
    for(int k=0;k<33;k++) s = fmaf(x[k], gw[c*33+k], s);
    a[c] = s;
  }
  #pragma unroll
  for(int d=0;d<16;d++) hb[(size_t)n*17 + d] = packbf(a[2*d], a[2*d+1]);
  hb[(size_t)n*17 + 16] = packbf(a[32], 0.f);
}

// wave per node, 4 groups x 16 lanes, 4 edges/iter; bf16 h gather; fused bias+relu+BN.
__global__ __launch_bounds__(256) void k_gcn(const u32* __restrict__ hb, const int* __restrict__ rowptr,
                                             const uint2* __restrict__ s_srcw, const float* __restrict__ g_e,
                                             const float* __restrict__ deg,
                                             const float* __restrict__ gcnb, const float* __restrict__ bnm,
                                             const float* __restrict__ bnv, const float* __restrict__ bnw,
                                             const float* __restrict__ bnb, float* __restrict__ xp1){
  int wave = threadIdx.x >> 6;
  int lane = threadIdx.x & 63;
  int n = blockIdx.x*4 + wave;
  if(n >= N_NODES) return;
  int l = lane & 15, g = lane >> 4;
  bool t0 = (l == 0);
  float dn = rsqrtf(deg[n] + 1.f);
  const u32* srow = hb + (size_t)n*17;
  u32 us  = srow[l];
  u32 ust = t0 ? srow[16] : 0u;
  float acc0, acc1, acct;
  if(g == 0){ acc0 = dn*bflo(us); acc1 = dn*bfhi(us); acct = dn*bflo(ust); }
  else      { acc0 = 0.f; acc1 = 0.f; acct = 0.f; }
  int rb = rowptr[n], re = rowptr[n+1];
  int j = rb;
  for(; j+4 <= re; j += 4){
    int e = j + g;
    float ge = g_e[e];
    int s = (int)s_srcw[e].x;
    const u32* r = hb + (size_t)s*17;
    u32 u  = r[l];
    u32 ut = t0 ? r[16] : 0u;
    acc0 = fmaf(ge, bflo(u),  acc0);
    acc1 = fmaf(ge, bfhi(u),  acc1);
    acct = fmaf(ge, bflo(ut), acct);
  }
  int rem = re - j;
  if(rem > 0){
    bool val = (g < rem);
    int e = val ? (j + g) : j;
    float ge = val ? g_e[e] : 0.f;
    int s = (int)s_srcw[e].x;
    const u32* r = hb + (size_t)s*17;
    u32 u  = r[l];
    u32 ut = t0 ? r[16] : 0u;
    acc0 = fmaf(ge, bflo(u),  acc0);
    acc1 = fmaf(ge, bfhi(u),  acc1);
    acct = fmaf(ge, bflo(ut), acct);
  }
  #pragma unroll
  for(int m=16;m<=32;m<<=1){
    acc0 += __shfl_xor(acc0, m, 64);
    acc1 += __shfl_xor(acc1, m, 64);
    acct += __shfl_xor(acct, m, 64);
  }
  if(g == 0){
    int c0 = 2*l, c1 = 2*l+1;
    float v0 = fmaxf(dn*acc0 + gcnb[c0], 0.f);
    float v1 = fmaxf(dn*acc1 + gcnb[c1], 0.f);
    float i0 = bnw[c0] / sqrtf(bnv[c0] + BN_EPS);
    float i1 = bnw[c1] / sqrtf(bnv[c1] + BN_EPS);
    float2 o;
    o.x = v0*i0 + (bnb[c0] - bnm[c0]*i0);
    o.y = v1*i1 + (bnb[c1] - bnm[c1]*i1);
    ((float2*)(xp1 + (size_t)n*36))[l] = o;
    if(t0){
      float vt = fmaxf(dn*acct + gcnb[32], 0.f);
      float it = bnw[32] / sqrtf(bnv[32] + BN_EPS);
      float2 ot; ot.x = vt*it + (bnb[32] - bnm[32]*it); ot.y = 0.f;
      ((float2*)(xp1 + (size_t)n*36))[16] = ot;
      float2 z; z.x = 0.f; z.y = 0.f;
      ((float2*)(xp1 + (size_t)n*36))[17] = z;
    }
  }
}

// ---------------- GATv2 ----------------
// Thread computes column pair (2d, 2d+1) from even/odd-split LDS weight copies:
// read addr d*33+k in each array -> bank (d+k)%32, consecutive lanes consecutive
// banks, conflict-free. No cross-lane ops; pair packed locally.
__global__ __launch_bounds__(256) void k_gatlin(const float* __restrict__ xp1, const float* __restrict__ wl,
                                                const float* __restrict__ wr, u32* __restrict__ xlb,
                                                float* __restrict__ xr){
  __shared__ float sx[64*36];     // 9 KB
  __shared__ float swle[66*33];   // even columns of wl
  __shared__ float swlo[66*33];   // odd columns of wl
  __shared__ float swre[66*33];
  __shared__ float swro[66*33];
  int t = threadIdx.x;
  int n0 = blockIdx.x*64;
  int nn = N_NODES - n0; if(nn > 64) nn = 64;
  for(int i=t;i<2178;i+=256){
    int d = i/33, k = i - d*33;
    int gb = d*66 + k;            // column 2d starts at 66d
    swle[i] = wl[gb];
    swlo[i] = wl[gb+33];
    swre[i] = wr[gb];
    swro[i] = wr[gb+33];
  }
  int xcnt = nn*36;
  for(int i=t;i<xcnt;i+=256) sx[i] = xp1[(size_t)n0*36 + i];
  __syncthreads();
  int total = nn*66;
  for(int p=t; p<total; p+=256){
    int n = p/66, d = p - n*66;
    const float* xv  = sx + n*36;
    const float* wle = swle + d*33;
    const float* wlo = swlo + d*33;
    const float* wre = swre + d*33;
    const float* wro = swro + d*33;
    float al0=0.f, al1=0.f, ar0=0.f, ar1=0.f;
    #pragma unroll
    for(int k=0;k<33;k++){
      float x = xv[k];
      al0 = fmaf(x, wle[k], al0);
      al1 = fmaf(x, wlo[k], al1);
      ar0 = fmaf(x, wre[k], ar0);
      ar1 = fmaf(x, wro[k], ar1);
    }
    size_t nidx = (size_t)(n0 + n);
    int head = (d >= 33) ? 1 : 0;
    int dd = d - 33*head;
    xlb[nidx*68 + head*34 + dd] = packbf(al0, al1);
    float2 xv2; xv2.x = ar0; xv2.y = ar1;
    ((float2*)xr)[nidx*66 + d] = xv2;
  }
}

// block/node, 2 head-waves; wave = 4 x 16-lane groups; 2x unrolled -> 8 edges in flight.
__global__ __launch_bounds__(128) void k_gat(const int* __restrict__ rowptr, const u32* __restrict__ srcx,
                                             const u32* __restrict__ xlb, const float* __restrict__ xr,
                                             const float* __restrict__ att, const float* __restrict__ gatb,
                                             float* __restrict__ xp2){
  int n = blockIdx.x;
  int h = threadIdx.x >> 6;
  int lane = threadIdx.x & 63;
  int l = lane & 15, g = lane >> 4;
  int base = h*66, dbase = h*34;
  bool t0 = (l == 0);
  size_t nrow = (size_t)n*132;
  const float2* xr2 = (const float2*)(xr + nrow + base);
  float2 xra = xr2[2*l], xrb = xr2[2*l+1];
  float2 xrt = t0 ? xr2[32] : make_float2(0.f,0.f);
  const float2* att2 = (const float2*)(att + base);
  float2 ata = att2[2*l], atb = att2[2*l+1];
  float2 att_t = att2[32];
  const u32* srow = xlb + (size_t)n*68 + dbase;
  uint2 su = ((const uint2*)srow)[l];
  u32 ust = t0 ? srow[32] : 0u;
  float s0 = bflo(su.x), s1 = bfhi(su.x), s2 = bflo(su.y), s3 = bfhi(su.y);
  float st0 = bflo(ust), st1 = bfhi(ust);
  float p = lrelu(s0+xra.x)*ata.x + lrelu(s1+xra.y)*ata.y
          + lrelu(s2+xrb.x)*atb.x + lrelu(s3+xrb.y)*atb.y
          + lrelu(st0+xrt.x)*att_t.x + lrelu(st1+xrt.y)*att_t.y;
  #pragma unroll
  for(int m=1;m<=8;m<<=1) p += __shfl_xor(p, m, 64);
  float e_self = p;
  float a0_, a1_, a2_, a3_, at0, at1, asum;
  if(g == 0){ a0_=s0; a1_=s1; a2_=s2; a3_=s3; at0=st0; at1=st1; asum=1.f; }
  else      { a0_=0.f; a1_=0.f; a2_=0.f; a3_=0.f; at0=0.f; at1=0.f; asum=0.f; }
  int rb = rowptr[n], re = rowptr[n+1];
  int j = rb;
  for(; j+8 <= re; j += 8){
    int sA = (int)srcx[2*(j + g)];
    int sB = (int)srcx[2*(j + 4 + g)];
    const u32* rA = xlb + (size_t)sA*68 + dbase;
    const u32* rB = xlb + (size_t)sB*68 + dbase;
    uint2 uA = ((const uint2*)rA)[l];
    uint2 uB = ((const uint2*)rB)[l];
    u32 utA = t0 ? rA[32] : 0u;
    u32 utB = t0 ? rB[32] : 0u;
    float vA0=bflo(uA.x), vA1=bfhi(uA.x), vA2=bflo(uA.y), vA3=bfhi(uA.y);
    float vB0=bflo(uB.x), vB1=bfhi(uB.x), vB2=bflo(uB.y), vB3=bfhi(uB.y);
    float wA0=bflo(utA), wA1=bfhi(utA);
    float wB0=bflo(utB), wB1=bfhi(utB);
    float pA = lrelu(vA0+xra.x)*ata.x + lrelu(vA1+xra.y)*ata.y
             + lrelu(vA2+xrb.x)*atb.x + lrelu(vA3+xrb.y)*atb.y
             + lrelu(wA0+xrt.x)*att_t.x + lrelu(wA1+xrt.y)*att_t.y;
    float pB = lrelu(vB0+xra.x)*ata.x + lrelu(vB1+xra.y)*ata.y
             + lrelu(vB2+xrb.x)*atb.x + lrelu(vB3+xrb.y)*atb.y
             + lrelu(wB0+xrt.x)*att_t.x + lrelu(wB1+xrt.y)*att_t.y;
    #pragma unroll
    for(int m=1;m<=8;m<<=1){
      pA += __shfl_xor(pA, m, 64);
      pB += __shfl_xor(pB, m, 64);
    }
    float aA = __expf(pA - e_self);
    float aB = __expf(pB - e_self);
    a0_ = fmaf(aA, vA0, fmaf(aB, vB0, a0_));
    a1_ = fmaf(aA, vA1, fmaf(aB, vB1, a1_));
    a2_ = fmaf(aA, vA2, fmaf(aB, vB2, a2_));
    a3_ = fmaf(aA, vA3, fmaf(aB, vB3, a3_));
    at0 = fmaf(aA, wA0, fmaf(aB, wB0, at0));
    at1 = fmaf(aA, wA1, fmaf(aB, wB1, at1));
    asum += aA + aB;
  }
  if(j+4 <= re){
    int s = (int)srcx[2*(j + g)];
    const u32* r = xlb + (size_t)s*68 + dbase;
    uint2 uu = ((const uint2*)r)[l];
    u32 ut = t0 ? r[32] : 0u;
    float v0=bflo(uu.x), v1=bfhi(uu.x), v2=bflo(uu.y), v3=bfhi(uu.y);
    float w0=bflo(ut), w1=bfhi(ut);
    float pp = lrelu(v0+xra.x)*ata.x + lrelu(v1+xra.y)*ata.y
             + lrelu(v2+xrb.x)*atb.x + lrelu(v3+xrb.y)*atb.y
             + lrelu(w0+xrt.x)*att_t.x + lrelu(w1+xrt.y)*att_t.y;
    #pragma unroll
    for(int m=1;m<=8;m<<=1) pp += __shfl_xor(pp, m, 64);
    float a = __expf(pp - e_self);
    a0_ = fmaf(a, v0, a0_); a1_ = fmaf(a, v1, a1_);
    a2_ = fmaf(a, v2, a2_); a3_ = fmaf(a, v3, a3_);
    at0 = fmaf(a, w0, at0); at1 = fmaf(a, w1, at1);
    asum += a;
    j += 4;
  }
  int rem = re - j;
  if(rem > 0){
    bool val = (g < rem);
    int s = val ? (int)srcx[2*(j + g)] : n;
    const u32* r = xlb + (size_t)s*68 + dbase;
    uint2 uu = ((const uint2*)r)[l];
    u32 ut = t0 ? r[32] : 0u;
    float v0=bflo(uu.x), v1=bfhi(uu.x), v2=bflo(uu.y), v3=bfhi(uu.y);
    float w0=bflo(ut), w1=bfhi(ut);
    float pp = lrelu(v0+xra.x)*ata.x + lrelu(v1+xra.y)*ata.y
             + lrelu(v2+xrb.x)*atb.x + lrelu(v3+xrb.y)*atb.y
             + lrelu(w0+xrt.x)*att_t.x + lrelu(w1+xrt.y)*att_t.y;
    #pragma unroll
    for(int m=1;m<=8;m<<=1) pp += __shfl_xor(pp, m, 64);
    float a = val ? __expf(pp - e_self) : 0.f;
    a0_ = fmaf(a, v0, a0_); a1_ = fmaf(a, v1, a1_);
    a2_ = fmaf(a, v2, a2_); a3_ = fmaf(a, v3, a3_);
    at0 = fmaf(a, w0, at0); at1 = fmaf(a, w1, at1);
    asum += a;
  }
  #pragma unroll
  for(int m=16;m<=32;m<<=1){
    a0_ += __shfl_xor(a0_, m, 64);
    a1_ += __shfl_xor(a1_, m, 64);
    a2_ += __shfl_xor(a2_, m, 64);
    a3_ += __shfl_xor(a3_, m, 64);
    at0 += __shfl_xor(at0, m, 64);
    at1 += __shfl_xor(at1, m, 64);
    asum += __shfl_xor(asum, m, 64);
  }
  float inv = 1.f/asum;
  if(g == 0){
    const float2* gb2 = (const float2*)(gatb + base);
    float2 ga = gb2[2*l], gb = gb2[2*l+1];
    float2* o2 = (float2*)(xp2 + nrow + base);
    float2 oa, ob;
    oa.x = fmaxf(a0_*inv + ga.x, 0.f); oa.y = fmaxf(a1_*inv + ga.y, 0.f);
    ob.x = fmaxf(a2_*inv + gb.x, 0.f); ob.y = fmaxf(a3_*inv + gb.y, 0.f);
    o2[2*l] = oa; o2[2*l+1] = ob;
    if(t0){
      float2 gt = gb2[32];
      float2 ot;
      ot.x = fmaxf(at0*inv + gt.x, 0.f); ot.y = fmaxf(at1*inv + gt.y, 0.f);
      o2[32] = ot;
    }
  }
}

// ---------------- pooling + MLP head ----------------
__global__ __launch_bounds__(256) void k_bounds(const int* __restrict__ batch, int* __restrict__ gstart,
                                                int* __restrict__ gend){
  int n = blockIdx.x*256 + threadIdx.x;
  if(n >= N_NODES) return;
  int b = batch[n];
  if(n == 0) gstart[b] = 0;
  else {
    int p = batch[n-1];
    if(p != b){ gstart[b] = n; gend[p] = n; }
  }
  if(n == N_NODES-1) gend[b] = N_NODES;
}

__global__ __launch_bounds__(128) void k_poolp(const float* __restrict__ xp2, const int* __restrict__ gstart,
                                               const int* __restrict__ gend, float* __restrict__ pp){
  int g = blockIdx.x, seg = blockIdx.y, t = threadIdx.x;
  int s = gstart[g], e = gend[g];
  int len = e - s; if(len < 0) len = 0;
  int ns = s + (int)(((long long)len*seg)>>4);
  int ne = s + (int)(((long long)len*(seg+1))>>4);
  float a0 = 0.f, a1 = 0.f;
  for(int n=ns;n<ne;n++){
    a0 += xp2[(size_t)n*132 + t];
    if(t < 4) a1 += xp2[(size_t)n*132 + 128 + t];
  }
  float* o = pp + (size_t)(g*16 + seg)*132;
  o[t] = a0;
  if(t < 4) o[128 + t] = a1;
}

// fused poolr + fc1: block per graph; pooled vector in LDS, then 1024-dim fc.
__global__ __launch_bounds__(256) void k_pfc1(const float* __restrict__ pp, const int* __restrict__ gstart,
                                              const int* __restrict__ gend, const float* __restrict__ w,
                                              const float* __restrict__ b, float* __restrict__ h1T){
  __shared__ float pooled[132];
  int g = blockIdx.x, t = threadIdx.x;
  if(t < 132){
    float s = 0.f;
    #pragma unroll
    for(int k=0;k<16;k++) s += pp[(size_t)(g*16 + k)*132 + t];
    int c = gend[g] - gstart[g]; if(c < 1) c = 1;
    pooled[t] = s/(float)c;
  }
  __syncthreads();
  #pragma unroll
  for(int r=0;r<4;r++){
    int o = r*256 + t;
    const float* wr = w + o*132;
    float acc = b[o];
    for(int k=0;k<132;k++) acc = fmaf(pooled[k], wr[k], acc);
    h1T[o*64+g] = fmaxf(acc, 0.f);
  }
}

// block per output o (128 blocks); 256 threads = 4 k-slices x 64 graphs; LDS reduce.
__global__ __launch_bounds__(256) void k_fc2(const float* __restrict__ h1T, const float* __restrict__ w,
                                             const float* __restrict__ b, float* __restrict__ out){
  __shared__ float part[256];
  int o = blockIdx.x, t = threadIdx.x;
  int s = t >> 6, g = t & 63;
  const float* wr = w + o*1024 + s*256;
  const float* hp = h1T + (size_t)(s*256)*64 + g;
  float acc = 0.f;
  for(int k=0;k<256;k++) acc = fmaf(hp[k*64], wr[k], acc);
  part[t] = acc;
  __syncthreads();
  if(s == 0){
    float r = b[o] + part[g] + part[64+g] + part[128+g] + part[192+g];
    out[8192 + g*128 + o] = r;
  }
}

// ---------------- RNA branches ----------------
__global__ __launch_bounds__(256) void k_bucket(const int* __restrict__ g, int L, int V,
                                                int* __restrict__ sci, int* __restrict__ off){
  __shared__ int gl[3000];
  __shared__ int hist[65];
  __shared__ int base[66];
  int b = blockIdx.x, t = threadIdx.x;
  if(t < V) hist[t] = 0;
  for(int i=t;i<L;i+=256) gl[i] = g[b*L + i];
  __syncthreads();
  for(int i=t;i<L;i+=256) atomicAdd(&hist[gl[i]], 1);
  __syncthreads();
  if(t == 0){
    int run = 0;
    for(int v=0;v<V;v++){ base[v] = run; run += hist[v]; }
    base[V] = run;
  }
  __syncthreads();
  if(t <= V) off[b*(V+1) + t] = base[t];
  if(t < V) hist[t] = 0;
  __syncthreads();
  for(int i=t;i<L;i+=256){
    int v = gl[i];
    int p = base[v] + atomicAdd(&hist[v], 1);
    sci[b*3000 + p] = i*8;
  }
}

__global__ __launch_bounds__(256) void k_sgather(const int* __restrict__ sci, const int* __restrict__ off,
                                                 const float* __restrict__ w, int V, int wstride,
                                                 int sstride, float* __restrict__ S){
  __shared__ int loff[66];
  __shared__ int lci[3000];
  int b = blockIdx.x, q = blockIdx.y, t = threadIdx.x;
  int nsplit = gridDim.y;
  if(t <= V) loff[t] = off[b*(V+1) + t];
  __syncthreads();
  int vs = (V*q)/nsplit, ve = (V*(q+1))/nsplit;
  int p0 = loff[vs], p1 = loff[ve];
  for(int i=p0+t;i<p1;i+=256) lci[i-p0] = sci[b*3000 + i];
  __syncthreads();
  int co = t >> 3, kk = t & 7;
  const float* wrow = w + co*wstride + kk;
  float* Srow = S + (size_t)b*32*sstride + co*sstride + kk;
  for(int v=vs;v<ve;v++){
    int j = loff[v] - p0, je = loff[v+1] - p0;
    float a0=0.f,a1=0.f,a2=0.f,a3=0.f,a4=0.f,a5=0.f,a6=0.f,a7=0.f;
    for(; j+8 <= je; j += 8){
      a0 += wrow[lci[j]];
      a1 += wrow[lci[j+1]];
      a2 += wrow[lci[j+2]];
      a3 += wrow[lci[j+3]];
      a4 += wrow[lci[j+4]];
      a5 += wrow[lci[j+5]];
      a6 += wrow[lci[j+6]];
      a7 += wrow[lci[j+7]];
    }
    for(; j<je; j++) a0 += wrow[lci[j]];
    Srow[v*8] = ((a0+a1)+(a2+a3)) + ((a4+a5)+(a6+a7));
  }
}

// fused y1+y2: ysum[b][co*121+l] = 0.5*(conv1+b1) + 0.5*(conv2+b2)
__global__ __launch_bounds__(128) void k_y(const float* __restrict__ S1, const float* __restrict__ S2,
                                           const float* __restrict__ emb1, const float* __restrict__ emb2,
                                           const float* __restrict__ c1b, const float* __restrict__ c2b,
                                           float* __restrict__ ysum){
  int b = blockIdx.x, co = blockIdx.y, t = threadIdx.x;
  __shared__ float em1[640];
  __shared__ float em2[8320];
  for(int i=t;i<640;i+=128) em1[i] = emb1[i];
  for(int i=t;i<8320;i+=128) em2[i] = emb2[i];
  __syncthreads();
  if(t < 121){
    const float* Sa = S1 + b*1280 + co*40;
    float acc1 = c1b[co];
    #pragma unroll
    for(int v=0;v<5;v++)
      #pragma unroll
      for(int k=0;k<8;k++) acc1 = fmaf(Sa[v*8+k], em1[v*128 + t + k], acc1);
    const float* Sb = S2 + (size_t)b*16640 + co*520;
    float acc2 = c2b[co];
    for(int v=0;v<65;v++){
      #pragma unroll
      for(int k=0;k<8;k++) acc2 = fmaf(Sb[v*8+k], em2[v*128 + t + k], acc2);
    }
    ysum[b*3872 + co*121 + t] = 0.5f*(acc1 + acc2);
  }
}

__global__ __launch_bounds__(256) void k_fcxr(const float* __restrict__ ysum, const float* __restrict__ fcw,
                                              const float* __restrict__ fcb, float* __restrict__ out){
  __shared__ float part[256];
  int b = blockIdx.x, q = blockIdx.y, t = threadIdx.x;
  int ol = t >> 3;
  int o  = q*32 + ol;
  int slice = t & 7;
  const float4* ys = (const float4*)(ysum + b*3872) + slice*121;
  const float4* wr = (const float4*)(fcw + (size_t)o*3872) + slice*121;
  float acc = 0.f;
  for(int k=0;k<121;k++){
    float4 y = ys[k], w4 = wr[k];
    acc += y.x*w4.x + y.y*w4.y + y.z*w4.z + y.w*w4.w;
  }
  part[t] = acc;
  __syncthreads();
  if(slice == 0){
    float s = fcb[o];
    #pragma unroll
    for(int i=0;i<8;i++) s += part[ol*8 + i];
    out[b*128 + o] = s;
  }
}

extern "C" void kernel_launch(void* const* d_in, const int* in_sizes, int n_in,
                              void* d_out, int out_size, void* d_ws, size_t ws_size,
                              hipStream_t stream){
  const int*   g_rna = (const int*)  d_in[0];
  const int*   l_rna = (const int*)  d_in[1];
  const float* pro_x = (const float*)d_in[2];
  const int*   eidx  = (const int*)  d_in[3];
  const float* pro_w = (const float*)d_in[4];
  const int*   batch = (const int*)  d_in[5];
  const float* emb1  = (const float*)d_in[6];
  const float* emb2  = (const float*)d_in[7];
  const float* c1w   = (const float*)d_in[8];
  const float* c1b   = (const float*)d_in[9];
  const float* c2w   = (const float*)d_in[10];
  const float* c2b   = (const float*)d_in[11];
  const float* fcxw  = (const float*)d_in[12];
  const float* fcxb  = (const float*)d_in[13];
  const float* gcnw  = (const float*)d_in[14];
  const float* gcnb  = (const float*)d_in[15];
  const float* bnm   = (const float*)d_in[16];
  const float* bnv   = (const float*)d_in[17];
  const float* bnw   = (const float*)d_in[18];
  const float* bnb   = (const float*)d_in[19];
  const float* gwl   = (const float*)d_in[20];
  const float* gwr   = (const float*)d_in[21];
  const float* gatt  = (const float*)d_in[22];
  const float* gatb  = (const float*)d_in[23];
  const float* f1w   = (const float*)d_in[24];
  const float* f1b   = (const float*)d_in[25];
  const float* f2w   = (const float*)d_in[26];
  const float* f2b_  = (const float*)d_in[27];
  float* out = (float*)d_out;

  char* ws = (char*)d_ws;
  size_t off = 0;
  auto A = [&](size_t n)->char*{ char* p = ws + off; off = (off + n + 255) & ~(size_t)255; return p; };
  int*   cnt    = (int*)  A((size_t)N_NODES*4);
  int*   fill   = (int*)  A((size_t)N_NODES*4);
  float* deg    = (float*)A((size_t)N_NODES*4);
  size_t zero_bytes = off;
  int*   rowptr = (int*)  A((size_t)(N_NODES+1)*4);
  int*   bsum   = (int*)  A(196*4);
  int*   bbase  = (int*)  A(196*4);
  uint2* s_srcw = (uint2*)A((size_t)N_EDGES*8);
  float* g_e    = (float*)A((size_t)N_EDGES*4);
  u32*   hb     = (u32*)  A((size_t)N_NODES*17*4);
  float* xp1    = (float*)A((size_t)N_NODES*36*4);
  u32*   xlb    = (u32*)  A((size_t)N_NODES*68*4);
  float* xr     = (float*)A((size_t)N_NODES*132*4);
  float* xp2    = (float*)A((size_t)N_NODES*132*4);
  int*   gstart = (int*)  A(64*4);
  int*   gend   = (int*)  A(64*4);
  float* pp     = (float*)A((size_t)64*16*132*4);
  float* h1T    = (float*)A(1024*64*4);
  float* S1     = (float*)A((size_t)64*1280*4);
  float* S2     = (float*)A((size_t)64*16640*4);
  float* ysum   = (float*)A((size_t)64*3872*4);
  int*   sci1   = (int*)  A((size_t)64*3000*4);
  int*   off1   = (int*)  A((size_t)64*8*4);
  int*   sci2   = (int*)  A((size_t)64*3000*4);
  int*   off2   = (int*)  A((size_t)64*66*4);
  (void)ws_size; (void)in_sizes; (void)n_in; (void)out_size;

  hipMemsetAsync(ws, 0, zero_bytes, stream);

  // protein GNN pipeline
  k_hist   <<<3125, 256, 0, stream>>>(eidx, pro_w, cnt, deg);
  k_scan1  <<<196, 256, 0, stream>>>(cnt, rowptr, bsum);
  k_scan2  <<<1, 256, 0, stream>>>(bsum, bbase, rowptr, gstart, gend);
  k_scan3  <<<196, 256, 0, stream>>>(rowptr, bbase);
  k_scatter<<<3125, 256, 0, stream>>>(eidx, pro_w, rowptr, fill, s_srcw);
  k_enorm  <<<3125, 256, 0, stream>>>(s_srcw, deg, g_e);
  k_h      <<<196, 256, 0, stream>>>(pro_x, gcnw, hb);
  k_gcn    <<<12500, 256, 0, stream>>>(hb, rowptr, s_srcw, g_e, deg, gcnb, bnm, bnv, bnw, bnb, xp1);
  k_gatlin <<<782, 256, 0, stream>>>(xp1, gwl, gwr, xlb, xr);
  k_gat    <<<N_NODES, 128, 0, stream>>>(rowptr, (const u32*)s_srcw, xlb, xr, gatt, gatb, xp2);
  k_bounds <<<196, 256, 0, stream>>>(batch, gstart, gend);
  k_poolp  <<<dim3(64,16), 128, 0, stream>>>(xp2, gstart, gend, pp);
  k_pfc1   <<<64, 256, 0, stream>>>(pp, gstart, gend, f1w, f1b, h1T);
  k_fc2    <<<128, 256, 0, stream>>>(h1T, f2w, f2b_, out);

  // RNA branches
  k_bucket <<<64, 256, 0, stream>>>(g_rna, 3000, 5, sci1, off1);
  k_bucket <<<64, 256, 0, stream>>>(l_rna, 2998, 65, sci2, off2);
  k_sgather<<<dim3(64,5), 256, 0, stream>>>(sci1, off1, c1w, 5, 24000, 40, S1);
  k_sgather<<<dim3(64,8), 256, 0, stream>>>(sci2, off2, c2w, 65, 23984, 520, S2);
  k_y      <<<dim3(64,32), 128, 0, stream>>>(S1, S2, emb1, emb2, c1b, c2b, ysum);
  k_fcxr   <<<dim3(64,4), 256, 0, stream>>>(ysum, fcxw, fcxb, out);
}

// Round 14
// 617.060 us; speedup vs baseline: 1.8332x; 1.0025x over previous
//
#include <hip/hip_runtime.h>

#define N_NODES 50000
#define N_EDGES 800000
#define LRELU_SLOPE 0.2f
#define BN_EPS 1e-5f

typedef unsigned int u32;

__device__ __forceinline__ float lrelu(float x){ return fmaxf(x,0.f) + LRELU_SLOPE*fminf(x,0.f); }
__device__ __forceinline__ float bflo(u32 u){ return __uint_as_float(u<<16); }
__device__ __forceinline__ float bfhi(u32 u){ return __uint_as_float(u & 0xffff0000u); }
__device__ __forceinline__ u32 packbf(float a, float b){
  u32 ua = __float_as_uint(a); ua = (ua + 0x7fffu + ((ua>>16)&1u)) >> 16;
  u32 ub = __float_as_uint(b); ub = (ub + 0x7fffu + ((ub>>16)&1u)) >> 16;
  return ua | (ub<<16);
}

// ---------------- CSR build ----------------
// cnt/fill/deg zeroed by hipMemsetAsync in kernel_launch.
__global__ __launch_bounds__(256) void k_hist(const int* __restrict__ eidx, const float* __restrict__ pw,
                                              int* __restrict__ cnt, float* __restrict__ deg){
  int e = blockIdx.x*256 + threadIdx.x;
  if(e < N_EDGES){
    int d = eidx[N_EDGES + e];
    atomicAdd(&cnt[d], 1);
    unsafeAtomicAdd(&deg[d], pw[e]);
  }
}

// 3-phase parallel exclusive scan of cnt -> rowptr
__global__ __launch_bounds__(256) void k_scan1(const int* __restrict__ cnt, int* __restrict__ rowptr,
                                               int* __restrict__ bsum){
  __shared__ int sc[256];
  int b = blockIdx.x, t = threadIdx.x;
  int i = b*256 + t;
  int v = (i < N_NODES) ? cnt[i] : 0;
  sc[t] = v;
  __syncthreads();
  for(int off=1; off<256; off<<=1){
    int x = (t>=off)? sc[t-off] : 0;
    __syncthreads();
    sc[t] += x;
    __syncthreads();
  }
  if(i < N_NODES) rowptr[i] = sc[t] - v;   // exclusive within block
  if(t == 255) bsum[b] = sc[255];
}

__global__ __launch_bounds__(256) void k_scan2(const int* __restrict__ bsum, int* __restrict__ bbase,
                                               int* __restrict__ rowptr, int* __restrict__ gstart,
                                               int* __restrict__ gend){
  __shared__ int sc[256];
  int t = threadIdx.x;
  int v = (t < 196) ? bsum[t] : 0;
  sc[t] = v;
  __syncthreads();
  for(int off=1; off<256; off<<=1){
    int x = (t>=off)? sc[t-off] : 0;
    __syncthreads();
    sc[t] += x;
    __syncthreads();
  }
  if(t < 196) bbase[t] = sc[t] - v;
  if(t == 255) rowptr[N_NODES] = sc[255];
  if(t < 64){ gstart[t] = N_NODES; gend[t] = 0; }
}

__global__ __launch_bounds__(256) void k_scan3(int* __restrict__ rowptr, const int* __restrict__ bbase){
  int b = blockIdx.x, t = threadIdx.x;
  int i = b*256 + t;
  if(i < N_NODES) rowptr[i] += bbase[b];
}

// scatter stores (src, ge) where ge = rsqrt(deg[src]+1)*w  -> k_enorm eliminated
__global__ __launch_bounds__(256) void k_scatter(const int* __restrict__ eidx, const float* __restrict__ pw,
                                                 const int* __restrict__ rowptr, int* __restrict__ fill,
                                                 const float* __restrict__ deg, uint2* __restrict__ s_srcw){
  int e = blockIdx.x*256 + threadIdx.x;
  if(e < N_EDGES){
    int d = eidx[N_EDGES + e];
    int s = eidx[e];
    float ge = rsqrtf(deg[s] + 1.f) * pw[e];
    int pos = rowptr[d] + atomicAdd(&fill[d], 1);
    uint2 pr; pr.x = (u32)s; pr.y = __float_as_uint(ge);
    s_srcw[pos] = pr;
  }
}

// ---------------- GCN ----------------
// h = pro_x @ gcn_w.T, packed bf16 pairs: 17 dwords/node
__global__ __launch_bounds__(256) void k_h(const float* __restrict__ px, const float* __restrict__ gw,
                                           u32* __restrict__ hb){
  int n = blockIdx.x*256 + threadIdx.x;
  if(n >= N_NODES) return;
  float x[33];
  #pragma unroll
  for(int k=0;k<33;k++) x[k] = px[n*33+k];
  float a[33];
  for(int c=0;c<33;c++){
    float s = 0.f;
    #pragma unroll
    for(int k=0;k<33;k++) s = fmaf(x[k], gw[c*33+k], s);
    a[c] = s;
  }
  #pragma unroll
  for(int d=0;d<16;d++) hb[(size_t)n*17 + d] = packbf(a[2*d], a[2*d+1]);
  hb[(size_t)n*17 + 16] = packbf(a[32], 0.f);
}

// wave per node, 4 groups x 16 lanes; 2x unrolled -> 8 edges in flight; ge from s_srcw.y.
__global__ __launch_bounds__(256) void k_gcn(const u32* __restrict__ hb, const int* __restrict__ rowptr,
                                             const uint2* __restrict__ s_srcw,
                                             const float* __restrict__ deg,
                                             const float* __restrict__ gcnb, const float* __restrict__ bnm,
                                             const float* __restrict__ bnv, const float* __restrict__ bnw,
                                             const float* __restrict__ bnb, float* __restrict__ xp1){
  int wave = threadIdx.x >> 6;
  int lane = threadIdx.x & 63;
  int n = blockIdx.x*4 + wave;
  if(n >= N_NODES) return;
  int l = lane & 15, g = lane >> 4;
  bool t0 = (l == 0);
  float dn = rsqrtf(deg[n] + 1.f);
  const u32* srow = hb + (size_t)n*17;
  u32 us  = srow[l];
  u32 ust = t0 ? srow[16] : 0u;
  float acc0, acc1, acct;
  if(g == 0){ acc0 = dn*bflo(us); acc1 = dn*bfhi(us); acct = dn*bflo(ust); }
  else      { acc0 = 0.f; acc1 = 0.f; acct = 0.f; }
  int rb = rowptr[n], re = rowptr[n+1];
  int j = rb;
  for(; j+8 <= re; j += 8){
    uint2 prA = s_srcw[j + g];
    uint2 prB = s_srcw[j + 4 + g];
    float geA = __uint_as_float(prA.y);
    float geB = __uint_as_float(prB.y);
    const u32* rA = hb + (size_t)prA.x*17;
    const u32* rB = hb + (size_t)prB.x*17;
    u32 uA  = rA[l], uB = rB[l];
    u32 utA = t0 ? rA[16] : 0u;
    u32 utB = t0 ? rB[16] : 0u;
    acc0 = fmaf(geA, bflo(uA),  fmaf(geB, bflo(uB),  acc0));
    acc1 = fmaf(geA, bfhi(uA),  fmaf(geB, bfhi(uB),  acc1));
    acct = fmaf(geA, bflo(utA), fmaf(geB, bflo(utB), acct));
  }
  if(j+4 <= re){
    uint2 pr = s_srcw[j + g];
    float ge = __uint_as_float(pr.y);
    const u32* r = hb + (size_t)pr.x*17;
    u32 u  = r[l];
    u32 ut = t0 ? r[16] : 0u;
    acc0 = fmaf(ge, bflo(u),  acc0);
    acc1 = fmaf(ge, bfhi(u),  acc1);
    acct = fmaf(ge, bflo(ut), acct);
    j += 4;
  }
  int rem = re - j;
  if(rem > 0){
    bool val = (g < rem);
    uint2 pr = s_srcw[val ? (j + g) : j];
    float ge = val ? __uint_as_float(pr.y) : 0.f;
    const u32* r = hb + (size_t)pr.x*17;
    u32 u  = r[l];
    u32 ut = t0 ? r[16] : 0u;
    acc0 = fmaf(ge, bflo(u),  acc0);
    acc1 = fmaf(ge, bfhi(u),  acc1);
    acct = fmaf(ge, bflo(ut), acct);
  }
  #pragma unroll
  for(int m=16;m<=32;m<<=1){
    acc0 += __shfl_xor(acc0, m, 64);
    acc1 += __shfl_xor(acc1, m, 64);
    acct += __shfl_xor(acct, m, 64);
  }
  if(g == 0){
    int c0 = 2*l, c1 = 2*l+1;
    float v0 = fmaxf(dn*acc0 + gcnb[c0], 0.f);
    float v1 = fmaxf(dn*acc1 + gcnb[c1], 0.f);
    float i0 = bnw[c0] / sqrtf(bnv[c0] + BN_EPS);
    float i1 = bnw[c1] / sqrtf(bnv[c1] + BN_EPS);
    float2 o;
    o.x = v0*i0 + (bnb[c0] - bnm[c0]*i0);
    o.y = v1*i1 + (bnb[c1] - bnm[c1]*i1);
    ((float2*)(xp1 + (size_t)n*36))[l] = o;
    if(t0){
      float vt = fmaxf(dn*acct + gcnb[32], 0.f);
      float it = bnw[32] / sqrtf(bnv[32] + BN_EPS);
      float2 ot; ot.x = vt*it + (bnb[32] - bnm[32]*it); ot.y = 0.f;
      ((float2*)(xp1 + (size_t)n*36))[16] = ot;
      float2 z; z.x = 0.f; z.y = 0.f;
      ((float2*)(xp1 + (size_t)n*36))[17] = z;
    }
  }
}

// ---------------- GATv2 ----------------
// Thread computes column pair (2d, 2d+1) from even/odd-split LDS weight copies (conflict-free).
__global__ __launch_bounds__(256) void k_gatlin(const float* __restrict__ xp1, const float* __restrict__ wl,
                                                const float* __restrict__ wr, u32* __restrict__ xlb,
                                                float* __restrict__ xr){
  __shared__ float sx[64*36];
  __shared__ float swle[66*33];
  __shared__ float swlo[66*33];
  __shared__ float swre[66*33];
  __shared__ float swro[66*33];
  int t = threadIdx.x;
  int n0 = blockIdx.x*64;
  int nn = N_NODES - n0; if(nn > 64) nn = 64;
  for(int i=t;i<2178;i+=256){
    int d = i/33, k = i - d*33;
    int gb = d*66 + k;
    swle[i] = wl[gb];
    swlo[i] = wl[gb+33];
    swre[i] = wr[gb];
    swro[i] = wr[gb+33];
  }
  int xcnt = nn*36;
  for(int i=t;i<xcnt;i+=256) sx[i] = xp1[(size_t)n0*36 + i];
  __syncthreads();
  int total = nn*66;
  for(int p=t; p<total; p+=256){
    int n = p/66, d = p - n*66;
    const float* xv  = sx + n*36;
    const float* wle = swle + d*33;
    const float* wlo = swlo + d*33;
    const float* wre = swre + d*33;
    const float* wro = swro + d*33;
    float al0=0.f, al1=0.f, ar0=0.f, ar1=0.f;
    #pragma unroll
    for(int k=0;k<33;k++){
      float x = xv[k];
      al0 = fmaf(x, wle[k], al0);
      al1 = fmaf(x, wlo[k], al1);
      ar0 = fmaf(x, wre[k], ar0);
      ar1 = fmaf(x, wro[k], ar1);
    }
    size_t nidx = (size_t)(n0 + n);
    int head = (d >= 33) ? 1 : 0;
    int dd = d - 33*head;
    xlb[nidx*68 + head*34 + dd] = packbf(al0, al1);
    float2 xv2; xv2.x = ar0; xv2.y = ar1;
    ((float2*)xr)[nidx*66 + d] = xv2;
  }
}

// block/node, 2 head-waves; wave = 4 x 16-lane groups; 2x unrolled -> 8 edges in flight.
__global__ __launch_bounds__(128) void k_gat(const int* __restrict__ rowptr, const u32* __restrict__ srcx,
                                             const u32* __restrict__ xlb, const float* __restrict__ xr,
                                             const float* __restrict__ att, const float* __restrict__ gatb,
                                             float* __restrict__ xp2){
  int n = blockIdx.x;
  int h = threadIdx.x >> 6;
  int lane = threadIdx.x & 63;
  int l = lane & 15, g = lane >> 4;
  int base = h*66, dbase = h*34;
  bool t0 = (l == 0);
  size_t nrow = (size_t)n*132;
  const float2* xr2 = (const float2*)(xr + nrow + base);
  float2 xra = xr2[2*l], xrb = xr2[2*l+1];
  float2 xrt = t0 ? xr2[32] : make_float2(0.f,0.f);
  const float2* att2 = (const float2*)(att + base);
  float2 ata = att2[2*l], atb = att2[2*l+1];
  float2 att_t = att2[32];
  const u32* srow = xlb + (size_t)n*68 + dbase;
  uint2 su = ((const uint2*)srow)[l];
  u32 ust = t0 ? srow[32] : 0u;
  float s0 = bflo(su.x), s1 = bfhi(su.x), s2 = bflo(su.y), s3 = bfhi(su.y);
  float st0 = bflo(ust), st1 = bfhi(ust);
  float p = lrelu(s0+xra.x)*ata.x + lrelu(s1+xra.y)*ata.y
          + lrelu(s2+xrb.x)*atb.x + lrelu(s3+xrb.y)*atb.y
          + lrelu(st0+xrt.x)*att_t.x + lrelu(st1+xrt.y)*att_t.y;
  #pragma unroll
  for(int m=1;m<=8;m<<=1) p += __shfl_xor(p, m, 64);
  float e_self = p;
  float a0_, a1_, a2_, a3_, at0, at1, asum;
  if(g == 0){ a0_=s0; a1_=s1; a2_=s2; a3_=s3; at0=st0; at1=st1; asum=1.f; }
  else      { a0_=0.f; a1_=0.f; a2_=0.f; a3_=0.f; at0=0.f; at1=0.f; asum=0.f; }
  int rb = rowptr[n], re = rowptr[n+1];
  int j = rb;
  for(; j+8 <= re; j += 8){
    int sA = (int)srcx[2*(j + g)];
    int sB = (int)srcx[2*(j + 4 + g)];
    const u32* rA = xlb + (size_t)sA*68 + dbase;
    const u32* rB = xlb + (size_t)sB*68 + dbase;
    uint2 uA = ((const uint2*)rA)[l];
    uint2 uB = ((const uint2*)rB)[l];
    u32 utA = t0 ? rA[32] : 0u;
    u32 utB = t0 ? rB[32] : 0u;
    float vA0=bflo(uA.x), vA1=bfhi(uA.x), vA2=bflo(uA.y), vA3=bfhi(uA.y);
    float vB0=bflo(uB.x), vB1=bfhi(uB.x), vB2=bflo(uB.y), vB3=bfhi(uB.y);
    float wA0=bflo(utA), wA1=bfhi(utA);
    float wB0=bflo(utB), wB1=bfhi(utB);
    float pA = lrelu(vA0+xra.x)*ata.x + lrelu(vA1+xra.y)*ata.y
             + lrelu(vA2+xrb.x)*atb.x + lrelu(vA3+xrb.y)*atb.y
             + lrelu(wA0+xrt.x)*att_t.x + lrelu(wA1+xrt.y)*att_t.y;
    float pB = lrelu(vB0+xra.x)*ata.x + lrelu(vB1+xra.y)*ata.y
             + lrelu(vB2+xrb.x)*atb.x + lrelu(vB3+xrb.y)*atb.y
             + lrelu(wB0+xrt.x)*att_t.x + lrelu(wB1+xrt.y)*att_t.y;
    #pragma unroll
    for(int m=1;m<=8;m<<=1){
      pA += __shfl_xor(pA, m, 64);
      pB += __shfl_xor(pB, m, 64);
    }
    float aA = __expf(pA - e_self);
    float aB = __expf(pB - e_self);
    a0_ = fmaf(aA, vA0, fmaf(aB, vB0, a0_));
    a1_ = fmaf(aA, vA1, fmaf(aB, vB1, a1_));
    a2_ = fmaf(aA, vA2, fmaf(aB, vB2, a2_));
    a3_ = fmaf(aA, vA3, fmaf(aB, vB3, a3_));
    at0 = fmaf(aA, wA0, fmaf(aB, wB0, at0));
    at1 = fmaf(aA, wA1, fmaf(aB, wB1, at1));
    asum += aA + aB;
  }
  if(j+4 <= re){
    int s = (int)srcx[2*(j + g)];
    const u32* r = xlb + (size_t)s*68 + dbase;
    uint2 uu = ((const uint2*)r)[l];
    u32 ut = t0 ? r[32] : 0u;
    float v0=bflo(uu.x), v1=bfhi(uu.x), v2=bflo(uu.y), v3=bfhi(uu.y);
    float w0=bflo(ut), w1=bfhi(ut);
    float pp = lrelu(v0+xra.x)*ata.x + lrelu(v1+xra.y)*ata.y
             + lrelu(v2+xrb.x)*atb.x + lrelu(v3+xrb.y)*atb.y
             + lrelu(w0+xrt.x)*att_t.x + lrelu(w1+xrt.y)*att_t.y;
    #pragma unroll
    for(int m=1;m<=8;m<<=1) pp += __shfl_xor(pp, m, 64);
    float a = __expf(pp - e_self);
    a0_ = fmaf(a, v0, a0_); a1_ = fmaf(a, v1, a1_);
    a2_ = fmaf(a, v2, a2_); a3_ = fmaf(a, v3, a3_);
    at0 = fmaf(a, w0, at0); at1 = fmaf(a, w1, at1);
    asum += a;
    j += 4;
  }
  int rem = re - j;
  if(rem > 0){
    bool val = (g < rem);
    int s = val ? (int)srcx[2*(j + g)] : n;
    const u32* r = xlb + (size_t)s*68 + dbase;
    uint2 uu = ((const uint2*)r)[l];
    u32 ut = t0 ? r[32] : 0u;
    float v0=bflo(uu.x), v1=bfhi(uu.x), v2=bflo(uu.y), v3=bfhi(uu.y);
    float w0=bflo(ut), w1=bfhi(ut);
    float pp = lrelu(v0+xra.x)*ata.x + lrelu(v1+xra.y)*ata.y
             + lrelu(v2+xrb.x)*atb.x + lrelu(v3+xrb.y)*atb.y
             + lrelu(w0+xrt.x)*att_t.x + lrelu(w1+xrt.y)*att_t.y;
    #pragma unroll
    for(int m=1;m<=8;m<<=1) pp += __shfl_xor(pp, m, 64);
    float a = val ? __expf(pp - e_self) : 0.f;
    a0_ = fmaf(a, v0, a0_); a1_ = fmaf(a, v1, a1_);
    a2_ = fmaf(a, v2, a2_); a3_ = fmaf(a, v3, a3_);
    at0 = fmaf(a, w0, at0); at1 = fmaf(a, w1, at1);
    asum += a;
  }
  #pragma unroll
  for(int m=16;m<=32;m<<=1){
    a0_ += __shfl_xor(a0_, m, 64);
    a1_ += __shfl_xor(a1_, m, 64);
    a2_ += __shfl_xor(a2_, m, 64);
    a3_ += __shfl_xor(a3_, m, 64);
    at0 += __shfl_xor(at0, m, 64);
    at1 += __shfl_xor(at1, m, 64);
    asum += __shfl_xor(asum, m, 64);
  }
  float inv = 1.f/asum;
  if(g == 0){
    const float2* gb2 = (const float2*)(gatb + base);
    float2 ga = gb2[2*l], gb = gb2[2*l+1];
    float2* o2 = (float2*)(xp2 + nrow + base);
    float2 oa, ob;
    oa.x = fmaxf(a0_*inv + ga.x, 0.f); oa.y = fmaxf(a1_*inv + ga.y, 0.f);
    ob.x = fmaxf(a2_*inv + gb.x, 0.f); ob.y = fmaxf(a3_*inv + gb.y, 0.f);
    o2[2*l] = oa; o2[2*l+1] = ob;
    if(t0){
      float2 gt = gb2[32];
      float2 ot;
      ot.x = fmaxf(at0*inv + gt.x, 0.f); ot.y = fmaxf(at1*inv + gt.y, 0.f);
      o2[32] = ot;
    }
  }
}

// ---------------- pooling + MLP head ----------------
__global__ __launch_bounds__(256) void k_bounds(const int* __restrict__ batch, int* __restrict__ gstart,
                                                int* __restrict__ gend){
  int n = blockIdx.x*256 + threadIdx.x;
  if(n >= N_NODES) return;
  int b = batch[n];
  if(n == 0) gstart[b] = 0;
  else {
    int p = batch[n-1];
    if(p != b){ gstart[b] = n; gend[p] = n; }
  }
  if(n == N_NODES-1) gend[b] = N_NODES;
}

__global__ __launch_bounds__(128) void k_poolp(const float* __restrict__ xp2, const int* __restrict__ gstart,
                                               const int* __restrict__ gend, float* __restrict__ pp){
  int g = blockIdx.x, seg = blockIdx.y, t = threadIdx.x;
  int s = gstart[g], e = gend[g];
  int len = e - s; if(len < 0) len = 0;
  int ns = s + (int)(((long long)len*seg)>>4);
  int ne = s + (int)(((long long)len*(seg+1))>>4);
  float a0 = 0.f, a1 = 0.f;
  for(int n=ns;n<ne;n++){
    a0 += xp2[(size_t)n*132 + t];
    if(t < 4) a1 += xp2[(size_t)n*132 + 128 + t];
  }
  float* o = pp + (size_t)(g*16 + seg)*132;
  o[t] = a0;
  if(t < 4) o[128 + t] = a1;
}

// fused poolr + fc1
__global__ __launch_bounds__(256) void k_pfc1(const float* __restrict__ pp, const int* __restrict__ gstart,
                                              const int* __restrict__ gend, const float* __restrict__ w,
                                              const float* __restrict__ b, float* __restrict__ h1T){
  __shared__ float pooled[132];
  int g = blockIdx.x, t = threadIdx.x;
  if(t < 132){
    float s = 0.f;
    #pragma unroll
    for(int k=0;k<16;k++) s += pp[(size_t)(g*16 + k)*132 + t];
    int c = gend[g] - gstart[g]; if(c < 1) c = 1;
    pooled[t] = s/(float)c;
  }
  __syncthreads();
  #pragma unroll
  for(int r=0;r<4;r++){
    int o = r*256 + t;
    const float* wr = w + o*132;
    float acc = b[o];
    for(int k=0;k<132;k++) acc = fmaf(pooled[k], wr[k], acc);
    h1T[o*64+g] = fmaxf(acc, 0.f);
  }
}

__global__ __launch_bounds__(256) void k_fc2(const float* __restrict__ h1T, const float* __restrict__ w,
                                             const float* __restrict__ b, float* __restrict__ out){
  __shared__ float part[256];
  int o = blockIdx.x, t = threadIdx.x;
  int s = t >> 6, g = t & 63;
  const float* wr = w + o*1024 + s*256;
  const float* hp = h1T + (size_t)(s*256)*64 + g;
  float acc = 0.f;
  for(int k=0;k<256;k++) acc = fmaf(hp[k*64], wr[k], acc);
  part[t] = acc;
  __syncthreads();
  if(s == 0){
    float r = b[o] + part[g] + part[64+g] + part[128+g] + part[192+g];
    out[8192 + g*128 + o] = r;
  }
}

// ---------------- RNA branches ----------------
__global__ __launch_bounds__(256) void k_bucket(const int* __restrict__ g, int L, int V,
                                                int* __restrict__ sci, int* __restrict__ off){
  __shared__ int gl[3000];
  __shared__ int hist[65];
  __shared__ int base[66];
  int b = blockIdx.x, t = threadIdx.x;
  if(t < V) hist[t] = 0;
  for(int i=t;i<L;i+=256) gl[i] = g[b*L + i];
  __syncthreads();
  for(int i=t;i<L;i+=256) atomicAdd(&hist[gl[i]], 1);
  __syncthreads();
  if(t == 0){
    int run = 0;
    for(int v=0;v<V;v++){ base[v] = run; run += hist[v]; }
    base[V] = run;
  }
  __syncthreads();
  if(t <= V) off[b*(V+1) + t] = base[t];
  if(t < V) hist[t] = 0;
  __syncthreads();
  for(int i=t;i<L;i+=256){
    int v = gl[i];
    int p = base[v] + atomicAdd(&hist[v], 1);
    sci[b*3000 + p] = i*8;
  }
}

__global__ __launch_bounds__(256) void k_sgather(const int* __restrict__ sci, const int* __restrict__ off,
                                                 const float* __restrict__ w, int V, int wstride,
                                                 int sstride, float* __restrict__ S){
  __shared__ int loff[66];
  __shared__ int lci[3000];
  int b = blockIdx.x, q = blockIdx.y, t = threadIdx.x;
  int nsplit = gridDim.y;
  if(t <= V) loff[t] = off[b*(V+1) + t];
  __syncthreads();
  int vs = (V*q)/nsplit, ve = (V*(q+1))/nsplit;
  if(vs == ve) return;
  int p0 = loff[vs], p1 = loff[ve];
  for(int i=p0+t;i<p1;i+=256) lci[i-p0] = sci[b*3000 + i];
  __syncthreads();
  int co = t >> 3, kk = t & 7;
  const float* wrow = w + co*wstride + kk;
  float* Srow = S + (size_t)b*32*sstride + co*sstride + kk;
  for(int v=vs;v<ve;v++){
    int j = loff[v] - p0, je = loff[v+1] - p0;
    float a0=0.f,a1=0.f,a2=0.f,a3=0.f,a4=0.f,a5=0.f,a6=0.f,a7=0.f;
    for(; j+8 <= je; j += 8){
      a0 += wrow[lci[j]];
      a1 += wrow[lci[j+1]];
      a2 += wrow[lci[j+2]];
      a3 += wrow[lci[j+3]];
      a4 += wrow[lci[j+4]];
      a5 += wrow[lci[j+5]];
      a6 += wrow[lci[j+6]];
      a7 += wrow[lci[j+7]];
    }
    for(; j<je; j++) a0 += wrow[lci[j]];
    Srow[v*8] = ((a0+a1)+(a2+a3)) + ((a4+a5)+(a6+a7));
  }
}

// fused y1+y2
__global__ __launch_bounds__(128) void k_y(const float* __restrict__ S1, const float* __restrict__ S2,
                                           const float* __restrict__ emb1, const float* __restrict__ emb2,
                                           const float* __restrict__ c1b, const float* __restrict__ c2b,
                                           float* __restrict__ ysum){
  int b = blockIdx.x, co = blockIdx.y, t = threadIdx.x;
  __shared__ float em1[640];
  __shared__ float em2[8320];
  for(int i=t;i<640;i+=128) em1[i] = emb1[i];
  for(int i=t;i<8320;i+=128) em2[i] = emb2[i];
  __syncthreads();
  if(t < 121){
    const float* Sa = S1 + b*1280 + co*40;
    float acc1 = c1b[co];
    #pragma unroll
    for(int v=0;v<5;v++)
      #pragma unroll
      for(int k=0;k<8;k++) acc1 = fmaf(Sa[v*8+k], em1[v*128 + t + k], acc1);
    const float* Sb = S2 + (size_t)b*16640 + co*520;
    float acc2 = c2b[co];
    for(int v=0;v<65;v++){
      #pragma unroll
      for(int k=0;k<8;k++) acc2 = fmaf(Sb[v*8+k], em2[v*128 + t + k], acc2);
    }
    ysum[b*3872 + co*121 + t] = 0.5f*(acc1 + acc2);
  }
}

__global__ __launch_bounds__(256) void k_fcxr(const float* __restrict__ ysum, const float* __restrict__ fcw,
                                              const float* __restrict__ fcb, float* __restrict__ out){
  __shared__ float part[256];
  int b = blockIdx.x, q = blockIdx.y, t = threadIdx.x;
  int ol = t >> 3;
  int o  = q*32 + ol;
  int slice = t & 7;
  const float4* ys = (const float4*)(ysum + b*3872) + slice*121;
  const float4* wr = (const float4*)(fcw + (size_t)o*3872) + slice*121;
  float acc = 0.f;
  for(int k=0;k<121;k++){
    float4 y = ys[k], w4 = wr[k];
    acc += y.x*w4.x + y.y*w4.y + y.z*w4.z + y.w*w4.w;
  }
  part[t] = acc;
  __syncthreads();
  if(slice == 0){
    float s = fcb[o];
    #pragma unroll
    for(int i=0;i<8;i++) s += part[ol*8 + i];
    out[b*128 + o] = s;
  }
}

extern "C" void kernel_launch(void* const* d_in, const int* in_sizes, int n_in,
                              void* d_out, int out_size, void* d_ws, size_t ws_size,
                              hipStream_t stream){
  const int*   g_rna = (const int*)  d_in[0];
  const int*   l_rna = (const int*)  d_in[1];
  const float* pro_x = (const float*)d_in[2];
  const int*   eidx  = (const int*)  d_in[3];
  const float* pro_w = (const float*)d_in[4];
  const int*   batch = (const int*)  d_in[5];
  const float* emb1  = (const float*)d_in[6];
  const float* emb2  = (const float*)d_in[7];
  const float* c1w   = (const float*)d_in[8];
  const float* c1b   = (const float*)d_in[9];
  const float* c2w   = (const float*)d_in[10];
  const float* c2b   = (const float*)d_in[11];
  const float* fcxw  = (const float*)d_in[12];
  const float* fcxb  = (const float*)d_in[13];
  const float* gcnw  = (const float*)d_in[14];
  const float* gcnb  = (const float*)d_in[15];
  const float* bnm   = (const float*)d_in[16];
  const float* bnv   = (const float*)d_in[17];
  const float* bnw   = (const float*)d_in[18];
  const float* bnb   = (const float*)d_in[19];
  const float* gwl   = (const float*)d_in[20];
  const float* gwr   = (const float*)d_in[21];
  const float* gatt  = (const float*)d_in[22];
  const float* gatb  = (const float*)d_in[23];
  const float* f1w   = (const float*)d_in[24];
  const float* f1b   = (const float*)d_in[25];
  const float* f2w   = (const float*)d_in[26];
  const float* f2b_  = (const float*)d_in[27];
  float* out = (float*)d_out;

  char* ws = (char*)d_ws;
  size_t off = 0;
  auto A = [&](size_t n)->char*{ char* p = ws + off; off = (off + n + 255) & ~(size_t)255; return p; };
  int*   cnt    = (int*)  A((size_t)N_NODES*4);
  int*   fill   = (int*)  A((size_t)N_NODES*4);
  float* deg    = (float*)A((size_t)N_NODES*4);
  size_t zero_bytes = off;
  int*   rowptr = (int*)  A((size_t)(N_NODES+1)*4);
  int*   bsum   = (int*)  A(196*4);
  int*   bbase  = (int*)  A(196*4);
  uint2* s_srcw = (uint2*)A((size_t)N_EDGES*8);
  u32*   hb     = (u32*)  A((size_t)N_NODES*17*4);
  float* xp1    = (float*)A((size_t)N_NODES*36*4);
  u32*   xlb    = (u32*)  A((size_t)N_NODES*68*4);
  float* xr     = (float*)A((size_t)N_NODES*132*4);
  float* xp2    = (float*)A((size_t)N_NODES*132*4);
  int*   gstart = (int*)  A(64*4);
  int*   gend   = (int*)  A(64*4);
  float* pp     = (float*)A((size_t)64*16*132*4);
  float* h1T    = (float*)A(1024*64*4);
  float* S1     = (float*)A((size_t)64*1280*4);
  float* S2     = (float*)A((size_t)64*16640*4);
  float* ysum   = (float*)A((size_t)64*3872*4);
  int*   sci1   = (int*)  A((size_t)64*3000*4);
  int*   off1   = (int*)  A((size_t)64*8*4);
  int*   sci2   = (int*)  A((size_t)64*3000*4);
  int*   off2   = (int*)  A((size_t)64*66*4);
  (void)ws_size; (void)in_sizes; (void)n_in; (void)out_size;

  hipMemsetAsync(ws, 0, zero_bytes, stream);

  // protein GNN pipeline
  k_hist   <<<3125, 256, 0, stream>>>(eidx, pro_w, cnt, deg);
  k_scan1  <<<196, 256, 0, stream>>>(cnt, rowptr, bsum);
  k_scan2  <<<1, 256, 0, stream>>>(bsum, bbase, rowptr, gstart, gend);
  k_scan3  <<<196, 256, 0, stream>>>(rowptr, bbase);
  k_scatter<<<3125, 256, 0, stream>>>(eidx, pro_w, rowptr, fill, deg, s_srcw);
  k_h      <<<196, 256, 0, stream>>>(pro_x, gcnw, hb);
  k_gcn    <<<12500, 256, 0, stream>>>(hb, rowptr, s_srcw, deg, gcnb, bnm, bnv, bnw, bnb, xp1);
  k_gatlin <<<782, 256, 0, stream>>>(xp1, gwl, gwr, xlb, xr);
  k_gat    <<<N_NODES, 128, 0, stream>>>(rowptr, (const u32*)s_srcw, xlb, xr, gatt, gatb, xp2);
  k_bounds <<<196, 256, 0, stream>>>(batch, gstart, gend);
  k_poolp  <<<dim3(64,16), 128, 0, stream>>>(xp2, gstart, gend, pp);
  k_pfc1   <<<64, 256, 0, stream>>>(pp, gstart, gend, f1w, f1b, h1T);
  k_fc2    <<<128, 256, 0, stream>>>(h1T, f2w, f2b_, out);

  // RNA branches
  k_bucket <<<64, 256, 0, stream>>>(g_rna, 3000, 5, sci1, off1);
  k_bucket <<<64, 256, 0, stream>>>(l_rna, 2998, 65, sci2, off2);
  k_sgather<<<dim3(64,5), 256, 0, stream>>>(sci1, off1, c1w, 5, 24000, 40, S1);
  k_sgather<<<dim3(64,32), 256, 0, stream>>>(sci2, off2, c2w, 65, 23984, 520, S2);
  k_y      <<<dim3(64,32), 128, 0, stream>>>(S1, S2, emb1, emb2, c1b, c2b, ysum);
  k_fcxr   <<<dim3(64,4), 256, 0, stream>>>(ysum, fcxw, fcxb, out);
}

// Round 15
// 588.177 us; speedup vs baseline: 1.9232x; 1.0491x over previous
//
#include <hip/hip_runtime.h>

#define N_NODES 50000
#define N_EDGES 800000
#define LRELU_SLOPE 0.2f
#define BN_EPS 1e-5f

typedef unsigned int u32;

__device__ __forceinline__ float lrelu(float x){ return fmaxf(x,0.f) + LRELU_SLOPE*fminf(x,0.f); }
__device__ __forceinline__ float bflo(u32 u){ return __uint_as_float(u<<16); }
__device__ __forceinline__ float bfhi(u32 u){ return __uint_as_float(u & 0xffff0000u); }
__device__ __forceinline__ u32 packbf(float a, float b){
  u32 ua = __float_as_uint(a); ua = (ua + 0x7fffu + ((ua>>16)&1u)) >> 16;
  u32 ub = __float_as_uint(b); ub = (ub + 0x7fffu + ((ub>>16)&1u)) >> 16;
  return ua | (ub<<16);
}

// ---------------- CSR build ----------------
// cnt/fill/deg zeroed by hipMemsetAsync in kernel_launch.
__global__ __launch_bounds__(256) void k_hist(const int* __restrict__ eidx, const float* __restrict__ pw,
                                              int* __restrict__ cnt, float* __restrict__ deg){
  int e = blockIdx.x*256 + threadIdx.x;
  if(e < N_EDGES){
    int d = eidx[N_EDGES + e];
    atomicAdd(&cnt[d], 1);
    unsafeAtomicAdd(&deg[d], pw[e]);
  }
}

// 3-phase parallel exclusive scan of cnt -> rowptr
__global__ __launch_bounds__(256) void k_scan1(const int* __restrict__ cnt, int* __restrict__ rowptr,
                                               int* __restrict__ bsum){
  __shared__ int sc[256];
  int b = blockIdx.x, t = threadIdx.x;
  int i = b*256 + t;
  int v = (i < N_NODES) ? cnt[i] : 0;
  sc[t] = v;
  __syncthreads();
  for(int off=1; off<256; off<<=1){
    int x = (t>=off)? sc[t-off] : 0;
    __syncthreads();
    sc[t] += x;
    __syncthreads();
  }
  if(i < N_NODES) rowptr[i] = sc[t] - v;   // exclusive within block
  if(t == 255) bsum[b] = sc[255];
}

__global__ __launch_bounds__(256) void k_scan2(const int* __restrict__ bsum, int* __restrict__ bbase,
                                               int* __restrict__ rowptr, int* __restrict__ gstart,
                                               int* __restrict__ gend){
  __shared__ int sc[256];
  int t = threadIdx.x;
  int v = (t < 196) ? bsum[t] : 0;
  sc[t] = v;
  __syncthreads();
  for(int off=1; off<256; off<<=1){
    int x = (t>=off)? sc[t-off] : 0;
    __syncthreads();
    sc[t] += x;
    __syncthreads();
  }
  if(t < 196) bbase[t] = sc[t] - v;
  if(t == 255) rowptr[N_NODES] = sc[255];
  if(t < 64){ gstart[t] = N_NODES; gend[t] = 0; }
}

__global__ __launch_bounds__(256) void k_scan3(int* __restrict__ rowptr, const int* __restrict__ bbase){
  int b = blockIdx.x, t = threadIdx.x;
  int i = b*256 + t;
  if(i < N_NODES) rowptr[i] += bbase[b];
}

// scatter stores (src, ge) where ge = rsqrt(deg[src]+1)*w
__global__ __launch_bounds__(256) void k_scatter(const int* __restrict__ eidx, const float* __restrict__ pw,
                                                 const int* __restrict__ rowptr, int* __restrict__ fill,
                                                 const float* __restrict__ deg, uint2* __restrict__ s_srcw){
  int e = blockIdx.x*256 + threadIdx.x;
  if(e < N_EDGES){
    int d = eidx[N_EDGES + e];
    int s = eidx[e];
    float ge = rsqrtf(deg[s] + 1.f) * pw[e];
    int pos = rowptr[d] + atomicAdd(&fill[d], 1);
    uint2 pr; pr.x = (u32)s; pr.y = __float_as_uint(ge);
    s_srcw[pos] = pr;
  }
}

// ---------------- GCN ----------------
// h = pro_x @ gcn_w.T, packed bf16 pairs: 17 dwords/node
__global__ __launch_bounds__(256) void k_h(const float* __restrict__ px, const float* __restrict__ gw,
                                           u32* __restrict__ hb){
  int n = blockIdx.x*256 + threadIdx.x;
  if(n >= N_NODES) return;
  float x[33];
  #pragma unroll
  for(int k=0;k<33;k++) x[k] = px[n*33+k];
  float a[33];
  for(int c=0;c<33;c++){
    float s = 0.f;
    #pragma unroll
    for(int k=0;k<33;k++) s = fmaf(x[k], gw[c*33+k], s);
    a[c] = s;
  }
  #pragma unroll
  for(int d=0;d<16;d++) hb[(size_t)n*17 + d] = packbf(a[2*d], a[2*d+1]);
  hb[(size_t)n*17 + 16] = packbf(a[32], 0.f);
}

// wave per node, 4 groups x 16 lanes; 2x unrolled -> 8 edges in flight; ge from s_srcw.y.
__global__ __launch_bounds__(256) void k_gcn(const u32* __restrict__ hb, const int* __restrict__ rowptr,
                                             const uint2* __restrict__ s_srcw,
                                             const float* __restrict__ deg,
                                             const float* __restrict__ gcnb, const float* __restrict__ bnm,
                                             const float* __restrict__ bnv, const float* __restrict__ bnw,
                                             const float* __restrict__ bnb, float* __restrict__ xp1){
  int wave = threadIdx.x >> 6;
  int lane = threadIdx.x & 63;
  int n = blockIdx.x*4 + wave;
  if(n >= N_NODES) return;
  int l = lane & 15, g = lane >> 4;
  bool t0 = (l == 0);
  float dn = rsqrtf(deg[n] + 1.f);
  const u32* srow = hb + (size_t)n*17;
  u32 us  = srow[l];
  u32 ust = t0 ? srow[16] : 0u;
  float acc0, acc1, acct;
  if(g == 0){ acc0 = dn*bflo(us); acc1 = dn*bfhi(us); acct = dn*bflo(ust); }
  else      { acc0 = 0.f; acc1 = 0.f; acct = 0.f; }
  int rb = rowptr[n], re = rowptr[n+1];
  int j = rb;
  for(; j+8 <= re; j += 8){
    uint2 prA = s_srcw[j + g];
    uint2 prB = s_srcw[j + 4 + g];
    float geA = __uint_as_float(prA.y);
    float geB = __uint_as_float(prB.y);
    const u32* rA = hb + (size_t)prA.x*17;
    const u32* rB = hb + (size_t)prB.x*17;
    u32 uA  = rA[l], uB = rB[l];
    u32 utA = t0 ? rA[16] : 0u;
    u32 utB = t0 ? rB[16] : 0u;
    acc0 = fmaf(geA, bflo(uA),  fmaf(geB, bflo(uB),  acc0));
    acc1 = fmaf(geA, bfhi(uA),  fmaf(geB, bfhi(uB),  acc1));
    acct = fmaf(geA, bflo(utA), fmaf(geB, bflo(utB), acct));
  }
  if(j+4 <= re){
    uint2 pr = s_srcw[j + g];
    float ge = __uint_as_float(pr.y);
    const u32* r = hb + (size_t)pr.x*17;
    u32 u  = r[l];
    u32 ut = t0 ? r[16] : 0u;
    acc0 = fmaf(ge, bflo(u),  acc0);
    acc1 = fmaf(ge, bfhi(u),  acc1);
    acct = fmaf(ge, bflo(ut), acct);
    j += 4;
  }
  int rem = re - j;
  if(rem > 0){
    bool val = (g < rem);
    uint2 pr = s_srcw[val ? (j + g) : j];
    float ge = val ? __uint_as_float(pr.y) : 0.f;
    const u32* r = hb + (size_t)pr.x*17;
    u32 u  = r[l];
    u32 ut = t0 ? r[16] : 0u;
    acc0 = fmaf(ge, bflo(u),  acc0);
    acc1 = fmaf(ge, bfhi(u),  acc1);
    acct = fmaf(ge, bflo(ut), acct);
  }
  #pragma unroll
  for(int m=16;m<=32;m<<=1){
    acc0 += __shfl_xor(acc0, m, 64);
    acc1 += __shfl_xor(acc1, m, 64);
    acct += __shfl_xor(acct, m, 64);
  }
  if(g == 0){
    int c0 = 2*l, c1 = 2*l+1;
    float v0 = fmaxf(dn*acc0 + gcnb[c0], 0.f);
    float v1 = fmaxf(dn*acc1 + gcnb[c1], 0.f);
    float i0 = bnw[c0] / sqrtf(bnv[c0] + BN_EPS);
    float i1 = bnw[c1] / sqrtf(bnv[c1] + BN_EPS);
    float2 o;
    o.x = v0*i0 + (bnb[c0] - bnm[c0]*i0);
    o.y = v1*i1 + (bnb[c1] - bnm[c1]*i1);
    ((float2*)(xp1 + (size_t)n*36))[l] = o;
    if(t0){
      float vt = fmaxf(dn*acct + gcnb[32], 0.f);
      float it = bnw[32] / sqrtf(bnv[32] + BN_EPS);
      float2 ot; ot.x = vt*it + (bnb[32] - bnm[32]*it); ot.y = 0.f;
      ((float2*)(xp1 + (size_t)n*36))[16] = ot;
      float2 z; z.x = 0.f; z.y = 0.f;
      ((float2*)(xp1 + (size_t)n*36))[17] = z;
    }
  }
}

// ---------------- GATv2 ----------------
// Register-tiled GEMM: thread = (pair p<66, node-group ng<4 of 16 nodes).
// Per k: 4 weight LDS reads + 16 sx reads (wave-broadcast) feed 64 FMAs
// -> 0.31 LDS reads/fma (was 1.25). 64 accumulators/thread.
__global__ __launch_bounds__(320) void k_gatlin(const float* __restrict__ xp1, const float* __restrict__ wl,
                                                const float* __restrict__ wr, u32* __restrict__ xlb,
                                                float* __restrict__ xr){
  __shared__ float sx[64*36];     // 9.2 KB
  __shared__ float swle[66*33];   // even cols of wl
  __shared__ float swlo[66*33];   // odd cols of wl
  __shared__ float swre[66*33];
  __shared__ float swro[66*33];
  int t = threadIdx.x;
  int n0 = blockIdx.x*64;
  int nn = N_NODES - n0; if(nn > 64) nn = 64;
  for(int i=t;i<2178;i+=320){
    int d = i/33, k = i - d*33;
    int gb = d*66 + k;            // column 2d of [132][33] row-major
    swle[i] = wl[gb];
    swlo[i] = wl[gb+33];
    swre[i] = wr[gb];
    swro[i] = wr[gb+33];
  }
  int xcnt = nn*36;
  for(int i=t;i<xcnt;i+=320) sx[i] = xp1[(size_t)n0*36 + i];
  __syncthreads();
  if(t >= 264) return;
  int ng = t/66, p = t - ng*66;
  int nbase = ng*16;
  float al0[16], al1[16], ar0[16], ar1[16];
  #pragma unroll
  for(int i=0;i<16;i++){ al0[i]=0.f; al1[i]=0.f; ar0[i]=0.f; ar1[i]=0.f; }
  const float* wle = swle + p*33;
  const float* wlo = swlo + p*33;
  const float* wre = swre + p*33;
  const float* wro = swro + p*33;
  for(int k=0;k<33;k++){
    float w0 = wle[k], w1 = wlo[k], w2 = wre[k], w3 = wro[k];
    const float* xcol = sx + nbase*36 + k;
    #pragma unroll
    for(int i=0;i<16;i++){
      float x = xcol[i*36];
      al0[i] = fmaf(x, w0, al0[i]);
      al1[i] = fmaf(x, w1, al1[i]);
      ar0[i] = fmaf(x, w2, ar0[i]);
      ar1[i] = fmaf(x, w3, ar1[i]);
    }
  }
  int head = (p >= 33) ? 1 : 0;
  int dd = p - 33*head;
  #pragma unroll
  for(int i=0;i<16;i++){
    int n = nbase + i;
    if(n < nn){
      size_t nidx = (size_t)(n0 + n);
      xlb[nidx*68 + head*34 + dd] = packbf(al0[i], al1[i]);
      float2 v; v.x = ar0[i]; v.y = ar1[i];
      ((float2*)xr)[nidx*66 + p] = v;
    }
  }
}

// block/node, 2 head-waves; wave = 4 x 16-lane groups; 2x unrolled -> 8 edges in flight.
__global__ __launch_bounds__(128) void k_gat(const int* __restrict__ rowptr, const u32* __restrict__ srcx,
                                             const u32* __restrict__ xlb, const float* __restrict__ xr,
                                             const float* __restrict__ att, const float* __restrict__ gatb,
                                             float* __restrict__ xp2){
  int n = blockIdx.x;
  int h = threadIdx.x >> 6;
  int lane = threadIdx.x & 63;
  int l = lane & 15, g = lane >> 4;
  int base = h*66, dbase = h*34;
  bool t0 = (l == 0);
  size_t nrow = (size_t)n*132;
  const float2* xr2 = (const float2*)(xr + nrow + base);
  float2 xra = xr2[2*l], xrb = xr2[2*l+1];
  float2 xrt = t0 ? xr2[32] : make_float2(0.f,0.f);
  const float2* att2 = (const float2*)(att + base);
  float2 ata = att2[2*l], atb = att2[2*l+1];
  float2 att_t = att2[32];
  const u32* srow = xlb + (size_t)n*68 + dbase;
  uint2 su = ((const uint2*)srow)[l];
  u32 ust = t0 ? srow[32] : 0u;
  float s0 = bflo(su.x), s1 = bfhi(su.x), s2 = bflo(su.y), s3 = bfhi(su.y);
  float st0 = bflo(ust), st1 = bfhi(ust);
  float p = lrelu(s0+xra.x)*ata.x + lrelu(s1+xra.y)*ata.y
          + lrelu(s2+xrb.x)*atb.x + lrelu(s3+xrb.y)*atb.y
          + lrelu(st0+xrt.x)*att_t.x + lrelu(st1+xrt.y)*att_t.y;
  #pragma unroll
  for(int m=1;m<=8;m<<=1) p += __shfl_xor(p, m, 64);
  float e_self = p;
  float a0_, a1_, a2_, a3_, at0, at1, asum;
  if(g == 0){ a0_=s0; a1_=s1; a2_=s2; a3_=s3; at0=st0; at1=st1; asum=1.f; }
  else      { a0_=0.f; a1_=0.f; a2_=0.f; a3_=0.f; at0=0.f; at1=0.f; asum=0.f; }
  int rb = rowptr[n], re = rowptr[n+1];
  int j = rb;
  for(; j+8 <= re; j += 8){
    int sA = (int)srcx[2*(j + g)];
    int sB = (int)srcx[2*(j + 4 + g)];
    const u32* rA = xlb + (size_t)sA*68 + dbase;
    const u32* rB = xlb + (size_t)sB*68 + dbase;
    uint2 uA = ((const uint2*)rA)[l];
    uint2 uB = ((const uint2*)rB)[l];
    u32 utA = t0 ? rA[32] : 0u;
    u32 utB = t0 ? rB[32] : 0u;
    float vA0=bflo(uA.x), vA1=bfhi(uA.x), vA2=bflo(uA.y), vA3=bfhi(uA.y);
    float vB0=bflo(uB.x), vB1=bfhi(uB.x), vB2=bflo(uB.y), vB3=bfhi(uB.y);
    float wA0=bflo(utA), wA1=bfhi(utA);
    float wB0=bflo(utB), wB1=bfhi(utB);
    float pA = lrelu(vA0+xra.x)*ata.x + lrelu(vA1+xra.y)*ata.y
             + lrelu(vA2+xrb.x)*atb.x + lrelu(vA3+xrb.y)*atb.y
             + lrelu(wA0+xrt.x)*att_t.x + lrelu(wA1+xrt.y)*att_t.y;
    float pB = lrelu(vB0+xra.x)*ata.x + lrelu(vB1+xra.y)*ata.y
             + lrelu(vB2+xrb.x)*atb.x + lrelu(vB3+xrb.y)*atb.y
             + lrelu(wB0+xrt.x)*att_t.x + lrelu(wB1+xrt.y)*att_t.y;
    #pragma unroll
    for(int m=1;m<=8;m<<=1){
      pA += __shfl_xor(pA, m, 64);
      pB += __shfl_xor(pB, m, 64);
    }
    float aA = __expf(pA - e_self);
    float aB = __expf(pB - e_self);
    a0_ = fmaf(aA, vA0, fmaf(aB, vB0, a0_));
    a1_ = fmaf(aA, vA1, fmaf(aB, vB1, a1_));
    a2_ = fmaf(aA, vA2, fmaf(aB, vB2, a2_));
    a3_ = fmaf(aA, vA3, fmaf(aB, vB3, a3_));
    at0 = fmaf(aA, wA0, fmaf(aB, wB0, at0));
    at1 = fmaf(aA, wA1, fmaf(aB, wB1, at1));
    asum += aA + aB;
  }
  if(j+4 <= re){
    int s = (int)srcx[2*(j + g)];
    const u32* r = xlb + (size_t)s*68 + dbase;
    uint2 uu = ((const uint2*)r)[l];
    u32 ut = t0 ? r[32] : 0u;
    float v0=bflo(uu.x), v1=bfhi(uu.x), v2=bflo(uu.y), v3=bfhi(uu.y);
    float w0=bflo(ut), w1=bfhi(ut);
    float pp = lrelu(v0+xra.x)*ata.x + lrelu(v1+xra.y)*ata.y
             + lrelu(v2+xrb.x)*atb.x + lrelu(v3+xrb.y)*atb.y
             + lrelu(w0+xrt.x)*att_t.x + lrelu(w1+xrt.y)*att_t.y;
    #pragma unroll
    for(int m=1;m<=8;m<<=1) pp += __shfl_xor(pp, m, 64);
    float a = __expf(pp - e_self);
    a0_ = fmaf(a, v0, a0_); a1_ = fmaf(a, v1, a1_);
    a2_ = fmaf(a, v2, a2_); a3_ = fmaf(a, v3, a3_);
    at0 = fmaf(a, w0, at0); at1 = fmaf(a, w1, at1);
    asum += a;
    j += 4;
  }
  int rem = re - j;
  if(rem > 0){
    bool val = (g < rem);
    int s = val ? (int)srcx[2*(j + g)] : n;
    const u32* r = xlb + (size_t)s*68 + dbase;
    uint2 uu = ((const uint2*)r)[l];
    u32 ut = t0 ? r[32] : 0u;
    float v0=bflo(uu.x), v1=bfhi(uu.x), v2=bflo(uu.y), v3=bfhi(uu.y);
    float w0=bflo(ut), w1=bfhi(ut);
    float pp = lrelu(v0+xra.x)*ata.x + lrelu(v1+xra.y)*ata.y
             + lrelu(v2+xrb.x)*atb.x + lrelu(v3+xrb.y)*atb.y
             + lrelu(w0+xrt.x)*att_t.x + lrelu(w1+xrt.y)*att_t.y;
    #pragma unroll
    for(int m=1;m<=8;m<<=1) pp += __shfl_xor(pp, m, 64);
    float a = val ? __expf(pp - e_self) : 0.f;
    a0_ = fmaf(a, v0, a0_); a1_ = fmaf(a, v1, a1_);
    a2_ = fmaf(a, v2, a2_); a3_ = fmaf(a, v3, a3_);
    at0 = fmaf(a, w0, at0); at1 = fmaf(a, w1, at1);
    asum += a;
  }
  #pragma unroll
  for(int m=16;m<=32;m<<=1){
    a0_ += __shfl_xor(a0_, m, 64);
    a1_ += __shfl_xor(a1_, m, 64);
    a2_ += __shfl_xor(a2_, m, 64);
    a3_ += __shfl_xor(a3_, m, 64);
    at0 += __shfl_xor(at0, m, 64);
    at1 += __shfl_xor(at1, m, 64);
    asum += __shfl_xor(asum, m, 64);
  }
  float inv = 1.f/asum;
  if(g == 0){
    const float2* gb2 = (const float2*)(gatb + base);
    float2 ga = gb2[2*l], gb = gb2[2*l+1];
    float2* o2 = (float2*)(xp2 + nrow + base);
    float2 oa, ob;
    oa.x = fmaxf(a0_*inv + ga.x, 0.f); oa.y = fmaxf(a1_*inv + ga.y, 0.f);
    ob.x = fmaxf(a2_*inv + gb.x, 0.f); ob.y = fmaxf(a3_*inv + gb.y, 0.f);
    o2[2*l] = oa; o2[2*l+1] = ob;
    if(t0){
      float2 gt = gb2[32];
      float2 ot;
      ot.x = fmaxf(at0*inv + gt.x, 0.f); ot.y = fmaxf(at1*inv + gt.y, 0.f);
      o2[32] = ot;
    }
  }
}

// ---------------- pooling + MLP head ----------------
__global__ __launch_bounds__(256) void k_bounds(const int* __restrict__ batch, int* __restrict__ gstart,
                                                int* __restrict__ gend){
  int n = blockIdx.x*256 + threadIdx.x;
  if(n >= N_NODES) return;
  int b = batch[n];
  if(n == 0) gstart[b] = 0;
  else {
    int p = batch[n-1];
    if(p != b){ gstart[b] = n; gend[p] = n; }
  }
  if(n == N_NODES-1) gend[b] = N_NODES;
}

__global__ __launch_bounds__(128) void k_poolp(const float* __restrict__ xp2, const int* __restrict__ gstart,
                                               const int* __restrict__ gend, float* __restrict__ pp){
  int g = blockIdx.x, seg = blockIdx.y, t = threadIdx.x;
  int s = gstart[g], e = gend[g];
  int len = e - s; if(len < 0) len = 0;
  int ns = s + (int)(((long long)len*seg)>>4);
  int ne = s + (int)(((long long)len*(seg+1))>>4);
  float a0 = 0.f, a1 = 0.f;
  for(int n=ns;n<ne;n++){
    a0 += xp2[(size_t)n*132 + t];
    if(t < 4) a1 += xp2[(size_t)n*132 + 128 + t];
  }
  float* o = pp + (size_t)(g*16 + seg)*132;
  o[t] = a0;
  if(t < 4) o[128 + t] = a1;
}

// fused poolr + fc1
__global__ __launch_bounds__(256) void k_pfc1(const float* __restrict__ pp, const int* __restrict__ gstart,
                                              const int* __restrict__ gend, const float* __restrict__ w,
                                              const float* __restrict__ b, float* __restrict__ h1T){
  __shared__ float pooled[132];
  int g = blockIdx.x, t = threadIdx.x;
  if(t < 132){
    float s = 0.f;
    #pragma unroll
    for(int k=0;k<16;k++) s += pp[(size_t)(g*16 + k)*132 + t];
    int c = gend[g] - gstart[g]; if(c < 1) c = 1;
    pooled[t] = s/(float)c;
  }
  __syncthreads();
  #pragma unroll
  for(int r=0;r<4;r++){
    int o = r*256 + t;
    const float* wr = w + o*132;
    float acc = b[o];
    for(int k=0;k<132;k++) acc = fmaf(pooled[k], wr[k], acc);
    h1T[o*64+g] = fmaxf(acc, 0.f);
  }
}

__global__ __launch_bounds__(256) void k_fc2(const float* __restrict__ h1T, const float* __restrict__ w,
                                             const float* __restrict__ b, float* __restrict__ out){
  __shared__ float part[256];
  int o = blockIdx.x, t = threadIdx.x;
  int s = t >> 6, g = t & 63;
  const float* wr = w + o*1024 + s*256;
  const float* hp = h1T + (size_t)(s*256)*64 + g;
  float acc = 0.f;
  for(int k=0;k<256;k++) acc = fmaf(hp[k*64], wr[k], acc);
  part[t] = acc;
  __syncthreads();
  if(s == 0){
    float r = b[o] + part[g] + part[64+g] + part[128+g] + part[192+g];
    out[8192 + g*128 + o] = r;
  }
}

// ---------------- RNA branches ----------------
__global__ __launch_bounds__(256) void k_bucket(const int* __restrict__ g, int L, int V,
                                                int* __restrict__ sci, int* __restrict__ off){
  __shared__ int gl[3000];
  __shared__ int hist[65];
  __shared__ int base[66];
  int b = blockIdx.x, t = threadIdx.x;
  if(t < V) hist[t] = 0;
  for(int i=t;i<L;i+=256) gl[i] = g[b*L + i];
  __syncthreads();
  for(int i=t;i<L;i+=256) atomicAdd(&hist[gl[i]], 1);
  __syncthreads();
  if(t == 0){
    int run = 0;
    for(int v=0;v<V;v++){ base[v] = run; run += hist[v]; }
    base[V] = run;
  }
  __syncthreads();
  if(t <= V) off[b*(V+1) + t] = base[t];
  if(t < V) hist[t] = 0;
  __syncthreads();
  for(int i=t;i<L;i+=256){
    int v = gl[i];
    int p = base[v] + atomicAdd(&hist[v], 1);
    sci[b*3000 + p] = i*8;
  }
}

__global__ __launch_bounds__(256) void k_sgather(const int* __restrict__ sci, const int* __restrict__ off,
                                                 const float* __restrict__ w, int V, int wstride,
                                                 int sstride, float* __restrict__ S){
  __shared__ int loff[66];
  __shared__ int lci[3000];
  int b = blockIdx.x, q = blockIdx.y, t = threadIdx.x;
  int nsplit = gridDim.y;
  if(t <= V) loff[t] = off[b*(V+1) + t];
  __syncthreads();
  int vs = (V*q)/nsplit, ve = (V*(q+1))/nsplit;
  if(vs == ve) return;
  int p0 = loff[vs], p1 = loff[ve];
  for(int i=p0+t;i<p1;i+=256) lci[i-p0] = sci[b*3000 + i];
  __syncthreads();
  int co = t >> 3, kk = t & 7;
  const float* wrow = w + co*wstride + kk;
  float* Srow = S + (size_t)b*32*sstride + co*sstride + kk;
  for(int v=vs;v<ve;v++){
    int j = loff[v] - p0, je = loff[v+1] - p0;
    float a0=0.f,a1=0.f,a2=0.f,a3=0.f,a4=0.f,a5=0.f,a6=0.f,a7=0.f;
    for(; j+8 <= je; j += 8){
      a0 += wrow[lci[j]];
      a1 += wrow[lci[j+1]];
      a2 += wrow[lci[j+2]];
      a3 += wrow[lci[j+3]];
      a4 += wrow[lci[j+4]];
      a5 += wrow[lci[j+5]];
      a6 += wrow[lci[j+6]];
      a7 += wrow[lci[j+7]];
    }
    for(; j<je; j++) a0 += wrow[lci[j]];
    Srow[v*8] = ((a0+a1)+(a2+a3)) + ((a4+a5)+(a6+a7));
  }
}

// fused y1+y2
__global__ __launch_bounds__(128) void k_y(const float* __restrict__ S1, const float* __restrict__ S2,
                                           const float* __restrict__ emb1, const float* __restrict__ emb2,
                                           const float* __restrict__ c1b, const float* __restrict__ c2b,
                                           float* __restrict__ ysum){
  int b = blockIdx.x, co = blockIdx.y, t = threadIdx.x;
  __shared__ float em1[640];
  __shared__ float em2[8320];
  for(int i=t;i<640;i+=128) em1[i] = emb1[i];
  for(int i=t;i<8320;i+=128) em2[i] = emb2[i];
  __syncthreads();
  if(t < 121){
    const float* Sa = S1 + b*1280 + co*40;
    float acc1 = c1b[co];
    #pragma unroll
    for(int v=0;v<5;v++)
      #pragma unroll
      for(int k=0;k<8;k++) acc1 = fmaf(Sa[v*8+k], em1[v*128 + t + k], acc1);
    const float* Sb = S2 + (size_t)b*16640 + co*520;
    float acc2 = c2b[co];
    for(int v=0;v<65;v++){
      #pragma unroll
      for(int k=0;k<8;k++) acc2 = fmaf(Sb[v*8+k], em2[v*128 + t + k], acc2);
    }
    ysum[b*3872 + co*121 + t] = 0.5f*(acc1 + acc2);
  }
}

__global__ __launch_bounds__(256) void k_fcxr(const float* __restrict__ ysum, const float* __restrict__ fcw,
                                              const float* __restrict__ fcb, float* __restrict__ out){
  __shared__ float part[256];
  int b = blockIdx.x, q = blockIdx.y, t = threadIdx.x;
  int ol = t >> 3;
  int o  = q*32 + ol;
  int slice = t & 7;
  const float4* ys = (const float4*)(ysum + b*3872) + slice*121;
  const float4* wr = (const float4*)(fcw + (size_t)o*3872) + slice*121;
  float acc = 0.f;
  for(int k=0;k<121;k++){
    float4 y = ys[k], w4 = wr[k];
    acc += y.x*w4.x + y.y*w4.y + y.z*w4.z + y.w*w4.w;
  }
  part[t] = acc;
  __syncthreads();
  if(slice == 0){
    float s = fcb[o];
    #pragma unroll
    for(int i=0;i<8;i++) s += part[ol*8 + i];
    out[b*128 + o] = s;
  }
}

extern "C" void kernel_launch(void* const* d_in, const int* in_sizes, int n_in,
                              void* d_out, int out_size, void* d_ws, size_t ws_size,
                              hipStream_t stream){
  const int*   g_rna = (const int*)  d_in[0];
  const int*   l_rna = (const int*)  d_in[1];
  const float* pro_x = (const float*)d_in[2];
  const int*   eidx  = (const int*)  d_in[3];
  const float* pro_w = (const float*)d_in[4];
  const int*   batch = (const int*)  d_in[5];
  const float* emb1  = (const float*)d_in[6];
  const float* emb2  = (const float*)d_in[7];
  const float* c1w   = (const float*)d_in[8];
  const float* c1b   = (const float*)d_in[9];
  const float* c2w   = (const float*)d_in[10];
  const float* c2b   = (const float*)d_in[11];
  const float* fcxw  = (const float*)d_in[12];
  const float* fcxb  = (const float*)d_in[13];
  const float* gcnw  = (const float*)d_in[14];
  const float* gcnb  = (const float*)d_in[15];
  const float* bnm   = (const float*)d_in[16];
  const float* bnv   = (const float*)d_in[17];
  const float* bnw   = (const float*)d_in[18];
  const float* bnb   = (const float*)d_in[19];
  const float* gwl   = (const float*)d_in[20];
  const float* gwr   = (const float*)d_in[21];
  const float* gatt  = (const float*)d_in[22];
  const float* gatb  = (const float*)d_in[23];
  const float* f1w   = (const float*)d_in[24];
  const float* f1b   = (const float*)d_in[25];
  const float* f2w   = (const float*)d_in[26];
  const float* f2b_  = (const float*)d_in[27];
  float* out = (float*)d_out;

  char* ws = (char*)d_ws;
  size_t off = 0;
  auto A = [&](size_t n)->char*{ char* p = ws + off; off = (off + n + 255) & ~(size_t)255; return p; };
  int*   cnt    = (int*)  A((size_t)N_NODES*4);
  int*   fill   = (int*)  A((size_t)N_NODES*4);
  float* deg    = (float*)A((size_t)N_NODES*4);
  size_t zero_bytes = off;
  int*   rowptr = (int*)  A((size_t)(N_NODES+1)*4);
  int*   bsum   = (int*)  A(196*4);
  int*   bbase  = (int*)  A(196*4);
  uint2* s_srcw = (uint2*)A((size_t)N_EDGES*8);
  u32*   hb     = (u32*)  A((size_t)N_NODES*17*4);
  float* xp1    = (float*)A((size_t)N_NODES*36*4);
  u32*   xlb    = (u32*)  A((size_t)N_NODES*68*4);
  float* xr     = (float*)A((size_t)N_NODES*132*4);
  float* xp2    = (float*)A((size_t)N_NODES*132*4);
  int*   gstart = (int*)  A(64*4);
  int*   gend   = (int*)  A(64*4);
  float* pp     = (float*)A((size_t)64*16*132*4);
  float* h1T    = (float*)A(1024*64*4);
  float* S1     = (float*)A((size_t)64*1280*4);
  float* S2     = (float*)A((size_t)64*16640*4);
  float* ysum   = (float*)A((size_t)64*3872*4);
  int*   sci1   = (int*)  A((size_t)64*3000*4);
  int*   off1   = (int*)  A((size_t)64*8*4);
  int*   sci2   = (int*)  A((size_t)64*3000*4);
  int*   off2   = (int*)  A((size_t)64*66*4);
  (void)ws_size; (void)in_sizes; (void)n_in; (void)out_size;

  hipMemsetAsync(ws, 0, zero_bytes, stream);

  // protein GNN pipeline
  k_hist   <<<3125, 256, 0, stream>>>(eidx, pro_w, cnt, deg);
  k_scan1  <<<196, 256, 0, stream>>>(cnt, rowptr, bsum);
  k_scan2  <<<1, 256, 0, stream>>>(bsum, bbase, rowptr, gstart, gend);
  k_scan3  <<<196, 256, 0, stream>>>(rowptr, bbase);
  k_scatter<<<3125, 256, 0, stream>>>(eidx, pro_w, rowptr, fill, deg, s_srcw);
  k_h      <<<196, 256, 0, stream>>>(pro_x, gcnw, hb);
  k_gcn    <<<12500, 256, 0, stream>>>(hb, rowptr, s_srcw, deg, gcnb, bnm, bnv, bnw, bnb, xp1);
  k_gatlin <<<782, 320, 0, stream>>>(xp1, gwl, gwr, xlb, xr);
  k_gat    <<<N_NODES, 128, 0, stream>>>(rowptr, (const u32*)s_srcw, xlb, xr, gatt, gatb, xp2);
  k_bounds <<<196, 256, 0, stream>>>(batch, gstart, gend);
  k_poolp  <<<dim3(64,16), 128, 0, stream>>>(xp2, gstart, gend, pp);
  k_pfc1   <<<64, 256, 0, stream>>>(pp, gstart, gend, f1w, f1b, h1T);
  k_fc2    <<<128, 256, 0, stream>>>(h1T, f2w, f2b_, out);

  // RNA branches
  k_bucket <<<64, 256, 0, stream>>>(g_rna, 3000, 5, sci1, off1);
  k_bucket <<<64, 256, 0, stream>>>(l_rna, 2998, 65, sci2, off2);
  k_sgather<<<dim3(64,5), 256, 0, stream>>>(sci1, off1, c1w, 5, 24000, 40, S1);
  k_sgather<<<dim3(64,32), 256, 0, stream>>>(sci2, off2, c2w, 65, 23984, 520, S2);
  k_y      <<<dim3(64,32), 128, 0, stream>>>(S1, S2, emb1, emb2, c1b, c2b, ysum);
  k_fcxr   <<<dim3(64,4), 256, 0, stream>>>(ysum, fcxw, fcxb, out);
}